// Round 6
// baseline (281.323 us; speedup 1.0000x reference)
//
#include <hip/hip_runtime.h>
#include <hip/hip_bf16.h>
#include <math.h>

#define NEG_SLOPE 0.2f
#define EPSBN 1e-5f

typedef __attribute__((ext_vector_type(8))) short bf16x8;
typedef __attribute__((ext_vector_type(4))) float f32x4;

__device__ __forceinline__ float bfu2f(unsigned u_lo16) { return __uint_as_float(u_lo16 << 16); }
__device__ __forceinline__ unsigned short f2bf(float f) {
    return __bfloat16_as_ushort(__float2bfloat16(f));
}
__device__ __forceinline__ void splitf(float v, unsigned short &h, unsigned short &l) {
    __hip_bfloat16 hb = __float2bfloat16(v);
    float r = v - __bfloat162float(hb);
    h = __bfloat16_as_ushort(hb);
    l = __bfloat16_as_ushort(__float2bfloat16(r));
}

// ---------------- split kernels --------------------------------------------
__global__ void split_x4(const float* __restrict__ X, unsigned short* __restrict__ Xh,
                         unsigned short* __restrict__ Xl, int total4)
{
    int i = blockIdx.x * blockDim.x + threadIdx.x;
    if (i >= total4) return;
    float4 v = *(const float4*)(X + (size_t)i * 4);
    unsigned short h[4], l[4];
    splitf(v.x, h[0], l[0]); splitf(v.y, h[1], l[1]);
    splitf(v.z, h[2], l[2]); splitf(v.w, h[3], l[3]);
    *(uint2*)(Xh + (size_t)i * 4) = *(uint2*)h;
    *(uint2*)(Xl + (size_t)i * 4) = *(uint2*)l;
}

// both weights -> transposed split planes [N,K]
__global__ void split_w_both(const float* __restrict__ W1, const float* __restrict__ W2,
                             unsigned short* __restrict__ w1th, unsigned short* __restrict__ w1tl,
                             unsigned short* __restrict__ w2th, unsigned short* __restrict__ w2tl)
{
    int idx = blockIdx.x * blockDim.x + threadIdx.x;
    if (idx < 32768) {                      // W1 [128,256] -> [256,128]
        int nn = idx >> 7, k = idx & 127;
        unsigned short h, l; splitf(W1[(size_t)k * 256 + nn], h, l);
        w1th[idx] = h; w1tl[idx] = l;
    } else if (idx < 65536) {               // W2 [256,128] -> [128,256]
        int j = idx - 32768;
        int nn = j >> 8, k = j & 255;
        unsigned short h, l; splitf(W2[(size_t)k * 128 + nn], h, l);
        w2th[j] = h; w2tl[j] = l;
    }
}

// ---------------- MFMA GEMM + fused attention coefficients ------------------
__global__ __launch_bounds__(256) void gemm_bf16_split_attn(
    const unsigned short* __restrict__ Ah, const unsigned short* __restrict__ Al,
    const unsigned short* __restrict__ Bth, const unsigned short* __restrict__ Btl,
    unsigned short* __restrict__ Cb,
    const float* __restrict__ aSrc, const float* __restrict__ aDst,
    float* __restrict__ asrcOut, float* __restrict__ adstOut,
    int M, int N, int K, int heads)
{
    __shared__ unsigned short smem[4][128][32];  // Ah,Al,Bh,Bl tiles: 32 KiB
    const int tid = threadIdx.x;
    const int lane = tid & 63;
    const int wave = tid >> 6;
    const int fr = lane & 15, g = lane >> 4;
    const int wr = (wave >> 1) * 64, wc = (wave & 1) * 64;
    const int rowBase = blockIdx.x * 128, colBase = blockIdx.y * 128;

    f32x4 acc[4][4] = {};

    for (int kk = 0; kk < K; kk += 32) {
#pragma unroll
        for (int i = 0; i < 2; ++i) {
            int idx = tid + 256 * i;
            int r = idx >> 2, c = (idx & 3) * 8;
            int grow = rowBase + r;
            uint4 va_h, va_l;
            if (grow < M) {
                va_h = *(const uint4*)(Ah + (size_t)grow * K + kk + c);
                va_l = *(const uint4*)(Al + (size_t)grow * K + kk + c);
            } else {
                va_h = make_uint4(0, 0, 0, 0); va_l = make_uint4(0, 0, 0, 0);
            }
            *(uint4*)&smem[0][r][c] = va_h;
            *(uint4*)&smem[1][r][c] = va_l;
            int gcol = colBase + r;
            *(uint4*)&smem[2][r][c] = *(const uint4*)(Bth + (size_t)gcol * K + kk + c);
            *(uint4*)&smem[3][r][c] = *(const uint4*)(Btl + (size_t)gcol * K + kk + c);
        }
        __syncthreads();

        bf16x8 ah[4], al[4], bh[4], bl[4];
#pragma unroll
        for (int m = 0; m < 4; ++m) {
            ah[m] = *(const bf16x8*)&smem[0][wr + m * 16 + fr][g * 8];
            al[m] = *(const bf16x8*)&smem[1][wr + m * 16 + fr][g * 8];
        }
#pragma unroll
        for (int n = 0; n < 4; ++n) {
            bh[n] = *(const bf16x8*)&smem[2][wc + n * 16 + fr][g * 8];
            bl[n] = *(const bf16x8*)&smem[3][wc + n * 16 + fr][g * 8];
        }
#pragma unroll
        for (int m = 0; m < 4; ++m)
#pragma unroll
            for (int n = 0; n < 4; ++n) {
                acc[m][n] = __builtin_amdgcn_mfma_f32_16x16x32_bf16(ah[m], bh[n], acc[m][n], 0, 0, 0);
                acc[m][n] = __builtin_amdgcn_mfma_f32_16x16x32_bf16(ah[m], bl[n], acc[m][n], 0, 0, 0);
                acc[m][n] = __builtin_amdgcn_mfma_f32_16x16x32_bf16(al[m], bh[n], acc[m][n], 0, 0, 0);
            }
        __syncthreads();
    }

    // ---- fused attention coefficient partials (f32 accuracy)
    {
        const int head = colBase >> 7;
        float avs[4], avd[4];
#pragma unroll
        for (int n = 0; n < 4; ++n) {
            int col = colBase + wc + n * 16 + fr;
            avs[n] = aSrc[col]; avd[n] = aDst[col];
        }
#pragma unroll
        for (int m = 0; m < 4; ++m) {
            float ps[4], pd[4];
#pragma unroll
            for (int j = 0; j < 4; ++j) {
                ps[j] = acc[m][0][j] * avs[0] + acc[m][1][j] * avs[1]
                      + acc[m][2][j] * avs[2] + acc[m][3][j] * avs[3];
                pd[j] = acc[m][0][j] * avd[0] + acc[m][1][j] * avd[1]
                      + acc[m][2][j] * avd[2] + acc[m][3][j] * avd[3];
            }
#pragma unroll
            for (int off = 8; off; off >>= 1)
#pragma unroll
                for (int j = 0; j < 4; ++j) {
                    ps[j] += __shfl_xor(ps[j], off);
                    pd[j] += __shfl_xor(pd[j], off);
                }
            if (fr == 0) {
#pragma unroll
                for (int j = 0; j < 4; ++j) {
                    int grow = rowBase + wr + m * 16 + g * 4 + j;
                    if (grow < M) {
                        atomicAdd(asrcOut + (size_t)grow * heads + head, ps[j]);
                        atomicAdd(adstOut + (size_t)grow * heads + head, pd[j]);
                    }
                }
            }
        }
    }

    // ---- epilogue: LDS transpose, coalesced bf16 stores
    float* Cs = (float*)&smem[0][0][0];
    const int rl_w = (wr >> 6) * 16;
#pragma unroll
    for (int m = 0; m < 4; ++m) {
        __syncthreads();
#pragma unroll
        for (int n = 0; n < 4; ++n)
#pragma unroll
            for (int j = 0; j < 4; ++j)
                Cs[(rl_w + g * 4 + j) * 132 + wc + n * 16 + fr] = acc[m][n][j];
        __syncthreads();
        int rl = tid >> 3, c16 = (tid & 7) * 16;
        int grow = rowBase + (rl >> 4) * 64 + m * 16 + (rl & 15);
        if (grow < M) {
            unsigned short tmp[16];
#pragma unroll
            for (int i = 0; i < 16; ++i) tmp[i] = f2bf(Cs[rl * 132 + c16 + i]);
            *(uint4*)(Cb + (size_t)grow * N + colBase + c16)     = *(uint4*)&tmp[0];
            *(uint4*)(Cb + (size_t)grow * N + colBase + c16 + 8) = *(uint4*)&tmp[8];
        }
    }
}

// ---------------- CSR build -------------------------------------------------
__global__ void count_edges(const int* __restrict__ ei, int E, int Nn,
                            int* __restrict__ counts, int* __restrict__ erank)
{
    int e = blockIdx.x * blockDim.x + threadIdx.x;
    int E2 = E + Nn;
    if (e >= E2) return;
    int dst = (e < E) ? ei[E + e] : (e - E);
    erank[e] = atomicAdd(&counts[dst], 1);
}

__global__ __launch_bounds__(256) void scan_block(
    const int* __restrict__ counts, int* __restrict__ offs, int* __restrict__ bsum, int Nn)
{
    __shared__ int s[256];
    int i = blockIdx.x * 256 + threadIdx.x;
    int v = (i < Nn) ? counts[i] : 0;
    s[threadIdx.x] = v;
    __syncthreads();
    for (int off = 1; off < 256; off <<= 1) {
        int t = (threadIdx.x >= off) ? s[threadIdx.x - off] : 0;
        __syncthreads();
        s[threadIdx.x] += t;
        __syncthreads();
    }
    if (i < Nn) offs[i] = s[threadIdx.x] - v;
    if (threadIdx.x == 255) bsum[blockIdx.x] = s[255];
}

__global__ __launch_bounds__(256) void scan_tops(int* __restrict__ bsum, int* __restrict__ boff, int nb)
{
    __shared__ int s[256];
    int v = (threadIdx.x < nb) ? bsum[threadIdx.x] : 0;
    s[threadIdx.x] = v;
    __syncthreads();
    for (int off = 1; off < 256; off <<= 1) {
        int t = (threadIdx.x >= off) ? s[threadIdx.x - off] : 0;
        __syncthreads();
        s[threadIdx.x] += t;
        __syncthreads();
    }
    if (threadIdx.x < nb) boff[threadIdx.x] = s[threadIdx.x] - v;
}

__global__ void add_offsets(int* __restrict__ offs, const int* __restrict__ boff, int Nn, int E2)
{
    int i = blockIdx.x * blockDim.x + threadIdx.x;
    if (i < Nn) offs[i] += boff[i >> 8];
    if (i == 0) offs[Nn] = E2;
}

// atomic-free scatter using precomputed rank
__global__ void fill_edges(const int* __restrict__ ei, int E, int Nn,
                           const int* __restrict__ offs, const int* __restrict__ erank,
                           int* __restrict__ esrc)
{
    int e = blockIdx.x * blockDim.x + threadIdx.x;
    int E2 = E + Nn;
    if (e >= E2) return;
    int src, dst;
    if (e < E) { src = ei[e]; dst = ei[E + e]; }
    else       { src = e - E; dst = e - E; }
    esrc[offs[dst] + erank[e]] = src;
}

// ---------------- unpack-FMA of one gathered uint4 (8 bf16 ch) --------------
__device__ __forceinline__ void fma8(float wA, uint4 hv, float acc[8])
{
    acc[0] = fmaf(wA, bfu2f(hv.x & 0xffff), acc[0]);
    acc[1] = fmaf(wA, __uint_as_float(hv.x & 0xffff0000u), acc[1]);
    acc[2] = fmaf(wA, bfu2f(hv.y & 0xffff), acc[2]);
    acc[3] = fmaf(wA, __uint_as_float(hv.y & 0xffff0000u), acc[3]);
    acc[4] = fmaf(wA, bfu2f(hv.z & 0xffff), acc[4]);
    acc[5] = fmaf(wA, __uint_as_float(hv.z & 0xffff0000u), acc[5]);
    acc[6] = fmaf(wA, bfu2f(hv.w & 0xffff), acc[6]);
    acc[7] = fmaf(wA, __uint_as_float(hv.w & 0xffff0000u), acc[7]);
}

// 4-deep unrolled gather: 2 heads, 8 edges/iter (sub in {0,1}), row 512 B
__device__ __forceinline__ void gather2h(
    int sj, float w0, float w1, int nc, int sub, int head,
    const char* __restrict__ hb_c, float acc[8])
{
    int t = 0;
    for (; t + 8 <= nc; t += 8) {
        int e0 = t + sub;
        int sA0 = __shfl(sj, e0),     sA1 = __shfl(sj, e0 + 2);
        int sA2 = __shfl(sj, e0 + 4), sA3 = __shfl(sj, e0 + 6);
        float a0 = __shfl(w0, e0),     a1 = __shfl(w0, e0 + 2);
        float a2 = __shfl(w0, e0 + 4), a3 = __shfl(w0, e0 + 6);
        float b0 = __shfl(w1, e0),     b1 = __shfl(w1, e0 + 2);
        float b2 = __shfl(w1, e0 + 4), b3 = __shfl(w1, e0 + 6);
        uint4 h0 = *(const uint4*)(hb_c + sA0 * 512);
        uint4 h1 = *(const uint4*)(hb_c + sA1 * 512);
        uint4 h2 = *(const uint4*)(hb_c + sA2 * 512);
        uint4 h3 = *(const uint4*)(hb_c + sA3 * 512);
        fma8(head ? b0 : a0, h0, acc);
        fma8(head ? b1 : a1, h1, acc);
        fma8(head ? b2 : a2, h2, acc);
        fma8(head ? b3 : a3, h3, acc);
    }
    for (; t < nc; t += 2) {
        int e = t + sub;
        int sA = __shfl(sj, e);
        float a = __shfl(w0, e), b = __shfl(w1, e);
        uint4 hv = *(const uint4*)(hb_c + sA * 512);
        fma8(head ? b : a, hv, acc);
    }
}

// 4-deep unrolled gather: 1 head, 16 edges/iter (sub in {0..3}), row 256 B
__device__ __forceinline__ void gather1h(
    int sj, float w, int nc, int sub,
    const char* __restrict__ hb_c, float acc[8])
{
    int t = 0;
    for (; t + 16 <= nc; t += 16) {
        int e0 = t + sub;
        int sA0 = __shfl(sj, e0),     sA1 = __shfl(sj, e0 + 4);
        int sA2 = __shfl(sj, e0 + 8), sA3 = __shfl(sj, e0 + 12);
        float w0 = __shfl(w, e0),     w1 = __shfl(w, e0 + 4);
        float w2 = __shfl(w, e0 + 8), w3 = __shfl(w, e0 + 12);
        uint4 h0 = *(const uint4*)(hb_c + sA0 * 256);
        uint4 h1 = *(const uint4*)(hb_c + sA1 * 256);
        uint4 h2 = *(const uint4*)(hb_c + sA2 * 256);
        uint4 h3 = *(const uint4*)(hb_c + sA3 * 256);
        fma8(w0, h0, acc);
        fma8(w1, h1, acc);
        fma8(w2, h2, acc);
        fma8(w3, h3, acc);
    }
    for (; t < nc; t += 4) {
        int e = t + sub;
        int sA = __shfl(sj, e);
        float wA = __shfl(w, e);
        uint4 hv = *(const uint4*)(hb_c + sA * 256);
        fma8(wA, hv, acc);
    }
}

// ---------------- SpMM layer 1 (all 256 ch) + fused softmax ------------------
__global__ __launch_bounds__(256) void spmm1(
    const unsigned short* __restrict__ h1b, const float* __restrict__ asrc,
    const float* __restrict__ adst, const int* __restrict__ offs,
    const int* __restrict__ esrc,
    const float* __restrict__ b1, const float* __restrict__ gamma,
    const float* __restrict__ beta, const float* __restrict__ rm,
    const float* __restrict__ rv, unsigned short* __restrict__ x2h,
    unsigned short* __restrict__ x2l, int Nn)
{
    int d = (int)((blockIdx.x * blockDim.x + threadIdx.x) >> 6);
    int lane = threadIdx.x & 63;
    if (d >= Nn) return;
    int beg = offs[d], end = offs[d + 1];
    int deg = end - beg;
    float ad0 = adst[d * 2], ad1 = adst[d * 2 + 1];
    const int sub = lane >> 5;            // edge subslot 0..1
    const int cgrp = lane & 31;           // channel group 0..31
    const int head = cgrp >> 4;           // 0 for ch<128, 1 for ch>=128
    const char* hb_c = (const char*)h1b + cgrp * 16;
    float acc[8] = {};

    if (deg <= 64) {
        int sj = 0; float e0 = -1e30f, e1 = -1e30f;
        if (lane < deg) {
            sj = esrc[beg + lane];
            float2 av = *(const float2*)(asrc + (size_t)sj * 2);
            e0 = av.x + ad0; e0 = e0 > 0.f ? e0 : NEG_SLOPE * e0;
            e1 = av.y + ad1; e1 = e1 > 0.f ? e1 : NEG_SLOPE * e1;
        }
        float m0 = e0, m1 = e1;
        for (int off = 32; off; off >>= 1) {
            m0 = fmaxf(m0, __shfl_xor(m0, off));
            m1 = fmaxf(m1, __shfl_xor(m1, off));
        }
        float p0 = (lane < deg) ? expf(e0 - m0) : 0.f;
        float p1 = (lane < deg) ? expf(e1 - m1) : 0.f;
        float s0 = p0, s1 = p1;
        for (int off = 32; off; off >>= 1) {
            s0 += __shfl_xor(s0, off);
            s1 += __shfl_xor(s1, off);
        }
        float w0 = p0 * (1.f / s0), w1 = p1 * (1.f / s1);
        gather2h(sj, w0, w1, deg, sub, head, hb_c, acc);
    } else {
        float m0 = -1e30f, m1 = -1e30f;
        for (int j = beg + lane; j < end; j += 64) {
            int s = esrc[j];
            float2 av = *(const float2*)(asrc + (size_t)s * 2);
            float e0 = av.x + ad0; e0 = e0 > 0.f ? e0 : NEG_SLOPE * e0;
            float e1 = av.y + ad1; e1 = e1 > 0.f ? e1 : NEG_SLOPE * e1;
            m0 = fmaxf(m0, e0); m1 = fmaxf(m1, e1);
        }
        for (int off = 32; off; off >>= 1) {
            m0 = fmaxf(m0, __shfl_xor(m0, off));
            m1 = fmaxf(m1, __shfl_xor(m1, off));
        }
        float s0 = 0.f, s1 = 0.f;
        for (int j = beg + lane; j < end; j += 64) {
            int s = esrc[j];
            float2 av = *(const float2*)(asrc + (size_t)s * 2);
            float e0 = av.x + ad0; e0 = e0 > 0.f ? e0 : NEG_SLOPE * e0;
            float e1 = av.y + ad1; e1 = e1 > 0.f ? e1 : NEG_SLOPE * e1;
            s0 += expf(e0 - m0); s1 += expf(e1 - m1);
        }
        for (int off = 32; off; off >>= 1) {
            s0 += __shfl_xor(s0, off);
            s1 += __shfl_xor(s1, off);
        }
        float rd0 = 1.f / s0, rd1 = 1.f / s1;
        for (int base = beg; base < end; base += 64) {
            int nc = end - base; if (nc > 64) nc = 64;
            int sj = 0; float w0 = 0.f, w1 = 0.f;
            if (lane < nc) {
                sj = esrc[base + lane];
                float2 av = *(const float2*)(asrc + (size_t)sj * 2);
                float e0 = av.x + ad0; e0 = e0 > 0.f ? e0 : NEG_SLOPE * e0;
                float e1 = av.y + ad1; e1 = e1 > 0.f ? e1 : NEG_SLOPE * e1;
                w0 = expf(e0 - m0) * rd0;
                w1 = expf(e1 - m1) * rd1;
            }
            gather2h(sj, w0, w1, nc, sub, head, hb_c, acc);
        }
    }
#pragma unroll
    for (int i = 0; i < 8; ++i) acc[i] += __shfl_xor(acc[i], 32);
    if (lane < 32) {
        int cl = cgrp * 8;
        unsigned short hh[8], ll[8];
#pragma unroll
        for (int i = 0; i < 8; ++i) {
            int c = cl + i;
            float v = acc[i] + b1[c];
            v = gamma[c] * (v - rm[c]) * rsqrtf(rv[c] + EPSBN) + beta[c];
            v = fmaxf(v, 0.f);
            splitf(v, hh[i], ll[i]);
        }
        *(uint4*)(x2h + (size_t)d * 256 + cl) = *(uint4*)&hh[0];
        *(uint4*)(x2l + (size_t)d * 256 + cl) = *(uint4*)&ll[0];
    }
}

// ---------------- SpMM layer 2 (all 128 ch) + fused softmax ------------------
__global__ __launch_bounds__(256) void spmm2(
    const unsigned short* __restrict__ h2b, const float* __restrict__ asrc,
    const float* __restrict__ adst, const int* __restrict__ offs,
    const int* __restrict__ esrc,
    const float* __restrict__ b2, const float* __restrict__ gamma,
    const float* __restrict__ beta, const float* __restrict__ rm,
    const float* __restrict__ rv, float* __restrict__ x3, int Nn)
{
    int d = (int)((blockIdx.x * blockDim.x + threadIdx.x) >> 6);
    int lane = threadIdx.x & 63;
    if (d >= Nn) return;
    int beg = offs[d], end = offs[d + 1];
    int deg = end - beg;
    float ad = adst[d];
    const int sub = lane >> 4;            // edge subslot 0..3
    const int cgrp = lane & 15;
    const char* hb_c = (const char*)h2b + cgrp * 16;
    float acc[8] = {};

    if (deg <= 64) {
        int sj = 0; float ev = -1e30f;
        if (lane < deg) {
            sj = esrc[beg + lane];
            float e = asrc[sj] + ad; ev = e > 0.f ? e : NEG_SLOPE * e;
        }
        float m = ev;
        for (int off = 32; off; off >>= 1) m = fmaxf(m, __shfl_xor(m, off));
        float p = (lane < deg) ? expf(ev - m) : 0.f;
        float s = p;
        for (int off = 32; off; off >>= 1) s += __shfl_xor(s, off);
        float w = p * (1.f / s);
        gather1h(sj, w, deg, sub, hb_c, acc);
    } else {
        float m = -1e30f;
        for (int j = beg + lane; j < end; j += 64) {
            int s = esrc[j];
            float e = asrc[s] + ad; e = e > 0.f ? e : NEG_SLOPE * e;
            m = fmaxf(m, e);
        }
        for (int off = 32; off; off >>= 1) m = fmaxf(m, __shfl_xor(m, off));
        float sd = 0.f;
        for (int j = beg + lane; j < end; j += 64) {
            int s = esrc[j];
            float e = asrc[s] + ad; e = e > 0.f ? e : NEG_SLOPE * e;
            sd += expf(e - m);
        }
        for (int off = 32; off; off >>= 1) sd += __shfl_xor(sd, off);
        float rd = 1.f / sd;
        for (int base = beg; base < end; base += 64) {
            int nc = end - base; if (nc > 64) nc = 64;
            int sj = 0; float wj = 0.f;
            if (lane < nc) {
                sj = esrc[base + lane];
                float e = asrc[sj] + ad; e = e > 0.f ? e : NEG_SLOPE * e;
                wj = expf(e - m) * rd;
            }
            gather1h(sj, wj, nc, sub, hb_c, acc);
        }
    }
#pragma unroll
    for (int i = 0; i < 8; ++i) {
        acc[i] += __shfl_xor(acc[i], 32);
        acc[i] += __shfl_xor(acc[i], 16);
    }
    if (lane < 16) {
        int cl = cgrp * 8;
        float vv[8];
#pragma unroll
        for (int i = 0; i < 8; ++i) {
            int c = cl + i;
            float v = acc[i] + b2[c];
            v = gamma[c] * (v - rm[c]) * rsqrtf(rv[c] + EPSBN) + beta[c];
            vv[i] = fmaxf(v, 0.f);
        }
        *(float4*)(x3 + (size_t)d * 128 + cl)     = make_float4(vv[0], vv[1], vv[2], vv[3]);
        *(float4*)(x3 + (size_t)d * 128 + cl + 4) = make_float4(vv[4], vv[5], vv[6], vv[7]);
    }
}

// ---------------- global max pool: one block per graph, no atomics ----------
__global__ __launch_bounds__(128) void pool_max_graph(
    const float* __restrict__ x3, const int* __restrict__ bat,
    float* __restrict__ out, int Nn)
{
    int g = blockIdx.x;
    int c = threadIdx.x;                  // channel 0..127
    int lo = 0, hi = Nn;
    while (lo < hi) { int mid = (lo + hi) >> 1; if (bat[mid] < g) lo = mid + 1; else hi = mid; }
    int beg = lo;
    hi = Nn;
    while (lo < hi) { int mid = (lo + hi) >> 1; if (bat[mid] < g + 1) lo = mid + 1; else hi = mid; }
    int end = lo;
    float acc = -1e30f;
    for (int n = beg; n < end; ++n)
        acc = fmaxf(acc, x3[(size_t)n * 128 + c]);
    out[(size_t)g * 128 + c] = acc;
}

// ---------------------------------------------------------------------------
extern "C" void kernel_launch(void* const* d_in, const int* in_sizes, int n_in,
                              void* d_out, int out_size, void* d_ws, size_t ws_size,
                              hipStream_t stream)
{
    const float* x   = (const float*)d_in[0];
    const int*   ei  = (const int*)d_in[1];
    const int*   bat = (const int*)d_in[2];
    const float* W1  = (const float*)d_in[3];
    const float* as1 = (const float*)d_in[4];
    const float* ad1 = (const float*)d_in[5];
    const float* b1  = (const float*)d_in[6];
    const float* g1  = (const float*)d_in[7];
    const float* be1 = (const float*)d_in[8];
    const float* rm1 = (const float*)d_in[9];
    const float* rv1 = (const float*)d_in[10];
    const float* W2  = (const float*)d_in[11];
    const float* as2 = (const float*)d_in[12];
    const float* ad2 = (const float*)d_in[13];
    const float* b2  = (const float*)d_in[14];
    const float* g2  = (const float*)d_in[15];
    const float* be2 = (const float*)d_in[16];
    const float* rm2 = (const float*)d_in[17];
    const float* rv2 = (const float*)d_in[18];
    float* out = (float*)d_out;

    const int Nn = in_sizes[0] / 128;
    const int E  = in_sizes[1] / 2;
    const int E2 = E + Nn;
    const int B  = out_size / 128;

    char* p = (char*)d_ws;
    size_t off = 0;
    auto alloc = [&](size_t bytes) -> void* {
        void* r = p + off;
        off = (off + bytes + 255) & ~(size_t)255;
        return r;
    };
    unsigned short* xh    = (unsigned short*)alloc((size_t)Nn * 128 * 2);
    unsigned short* xl    = (unsigned short*)alloc((size_t)Nn * 128 * 2);
    unsigned short* w1th  = (unsigned short*)alloc(256 * 128 * 2);
    unsigned short* w1tl  = (unsigned short*)alloc(256 * 128 * 2);
    unsigned short* w2th  = (unsigned short*)alloc(128 * 256 * 2);
    unsigned short* w2tl  = (unsigned short*)alloc(128 * 256 * 2);
    unsigned short* h1b   = (unsigned short*)alloc((size_t)Nn * 256 * 2);
    unsigned short* x2h   = (unsigned short*)alloc((size_t)Nn * 256 * 2);
    unsigned short* x2l   = (unsigned short*)alloc((size_t)Nn * 256 * 2);
    unsigned short* h2b   = (unsigned short*)alloc((size_t)Nn * 128 * 2);
    float*          x3    = (float*)alloc((size_t)Nn * 128 * 4);
    float*          attnv = (float*)alloc((size_t)Nn * 6 * 4);   // asrc1,adst1,asrc2,adst2
    float*          asrc1 = attnv;
    float*          adst1 = attnv + (size_t)Nn * 2;
    float*          asrc2 = attnv + (size_t)Nn * 4;
    float*          adst2 = attnv + (size_t)Nn * 5;
    int*            counts= (int*)alloc((size_t)Nn * 4);
    int*            erank = (int*)alloc((size_t)E2 * 4);
    int*            offs  = (int*)alloc((size_t)(Nn + 1) * 4);
    int*            bsum  = (int*)alloc(256 * 4);
    int*            boff  = (int*)alloc(256 * 4);
    int*            esrc  = (int*)alloc((size_t)E2 * 4);

    const int nb = (Nn + 255) / 256;
    const int nwB = (Nn + 3) / 4;
    const int gmB = (Nn + 127) / 128;

    hipMemsetAsync(counts, 0, (size_t)Nn * 4, stream);
    hipMemsetAsync(attnv, 0, (size_t)Nn * 6 * 4, stream);

    // ---- input splits
    split_x4<<<(Nn * 128 / 4 + 255) / 256, 256, 0, stream>>>(x, xh, xl, Nn * 128 / 4);
    split_w_both<<<(65536 + 255) / 256, 256, 0, stream>>>(W1, W2, w1th, w1tl, w2th, w2tl);

    // ---- CSR build
    count_edges<<<(E2 + 255) / 256, 256, 0, stream>>>(ei, E, Nn, counts, erank);
    scan_block<<<nb, 256, 0, stream>>>(counts, offs, bsum, Nn);
    scan_tops<<<1, 256, 0, stream>>>(bsum, boff, nb);
    add_offsets<<<(Nn + 255) / 256, 256, 0, stream>>>(offs, boff, Nn, E2);
    fill_edges<<<(E2 + 255) / 256, 256, 0, stream>>>(ei, E, Nn, offs, erank, esrc);

    // ---- layer 1: GEMM (+attn coef) then SpMM
    gemm_bf16_split_attn<<<dim3(gmB, 2), 256, 0, stream>>>(
        xh, xl, w1th, w1tl, h1b, as1, ad1, asrc1, adst1, Nn, 256, 128, 2);
    spmm1<<<nwB, 256, 0, stream>>>(h1b, asrc1, adst1, offs, esrc,
                                   b1, g1, be1, rm1, rv1, x2h, x2l, Nn);

    // ---- layer 2
    gemm_bf16_split_attn<<<dim3(gmB, 1), 256, 0, stream>>>(
        x2h, x2l, w2th, w2tl, h2b, as2, ad2, asrc2, adst2, Nn, 128, 256, 1);
    spmm2<<<nwB, 256, 0, stream>>>(h2b, asrc2, adst2, offs, esrc,
                                   b2, g2, be2, rm2, rv2, x3, Nn);

    // ---- global max pool
    pool_max_graph<<<B, 128, 0, stream>>>(x3, bat, out, Nn);
}

// Round 7
// 272.767 us; speedup vs baseline: 1.0314x; 1.0314x over previous
//
#include <hip/hip_runtime.h>
#include <hip/hip_bf16.h>
#include <math.h>

#define NEG_SLOPE 0.2f
#define EPSBN 1e-5f

typedef __attribute__((ext_vector_type(8))) short bf16x8;
typedef __attribute__((ext_vector_type(4))) float f32x4;

__device__ __forceinline__ float bfu2f(unsigned u_lo16) { return __uint_as_float(u_lo16 << 16); }
__device__ __forceinline__ unsigned short f2bf(float f) {
    return __bfloat16_as_ushort(__float2bfloat16(f));
}
__device__ __forceinline__ void splitf(float v, unsigned short &h, unsigned short &l) {
    __hip_bfloat16 hb = __float2bfloat16(v);
    float r = v - __bfloat162float(hb);
    h = __bfloat16_as_ushort(hb);
    l = __bfloat16_as_ushort(__float2bfloat16(r));
}

// ---------------- precompute v = W1 @ a vectors ------------------------------
// vsd[0][k]=sum_c W1[k,c]as1[0,c]; [1]: head1 src; [2],[3]: dst. (k<128)
__global__ void precompute_v(const float* __restrict__ W1, const float* __restrict__ as1,
                             const float* __restrict__ ad1, float* __restrict__ vsd)
{
    int k = threadIdx.x;
    if (k >= 128) return;
    float v0 = 0.f, v1 = 0.f, v2 = 0.f, v3 = 0.f;
    const float* wr = W1 + (size_t)k * 256;
    for (int c = 0; c < 128; ++c) {
        float wa = wr[c], wb = wr[128 + c];
        v0 += wa * as1[c];  v1 += wb * as1[128 + c];
        v2 += wa * ad1[c];  v3 += wb * ad1[128 + c];
    }
    vsd[k] = v0; vsd[128 + k] = v1; vsd[256 + k] = v2; vsd[384 + k] = v3;
}

// ---------------- split x + fused layer-1 attn coefficients ------------------
// wave per node: split x->xh/xl, asrc1/adst1 = x . vsd
__global__ __launch_bounds__(256) void split_x_attn(
    const float* __restrict__ X, const float* __restrict__ vsd,
    unsigned short* __restrict__ Xh, unsigned short* __restrict__ Xl,
    float* __restrict__ asrc, float* __restrict__ adst, int Nn)
{
    int n = (int)((blockIdx.x * blockDim.x + threadIdx.x) >> 6);
    int lane = threadIdx.x & 63;
    if (n >= Nn) return;
    float2 xv = *(const float2*)(X + (size_t)n * 128 + lane * 2);
    unsigned short h0, l0, h1, l1;
    splitf(xv.x, h0, l0); splitf(xv.y, h1, l1);
    unsigned short hh[2] = {h0, h1}, ll[2] = {l0, l1};
    *(unsigned*)(Xh + (size_t)n * 128 + lane * 2) = *(unsigned*)hh;
    *(unsigned*)(Xl + (size_t)n * 128 + lane * 2) = *(unsigned*)ll;
    int k = lane * 2;
    float p0 = xv.x * vsd[k]       + xv.y * vsd[k + 1];
    float p1 = xv.x * vsd[128 + k] + xv.y * vsd[129 + k];
    float p2 = xv.x * vsd[256 + k] + xv.y * vsd[257 + k];
    float p3 = xv.x * vsd[384 + k] + xv.y * vsd[385 + k];
    for (int off = 32; off; off >>= 1) {
        p0 += __shfl_xor(p0, off); p1 += __shfl_xor(p1, off);
        p2 += __shfl_xor(p2, off); p3 += __shfl_xor(p3, off);
    }
    if (lane == 0) {
        asrc[n * 2] = p0; asrc[n * 2 + 1] = p1;
        adst[n * 2] = p2; adst[n * 2 + 1] = p3;
    }
}

// both weights -> transposed split planes [N,K]
__global__ void split_w_both(const float* __restrict__ W1, const float* __restrict__ W2,
                             unsigned short* __restrict__ w1th, unsigned short* __restrict__ w1tl,
                             unsigned short* __restrict__ w2th, unsigned short* __restrict__ w2tl)
{
    int idx = blockIdx.x * blockDim.x + threadIdx.x;
    if (idx < 32768) {                      // W1 [128,256] -> [256,128]
        int nn = idx >> 7, k = idx & 127;
        unsigned short h, l; splitf(W1[(size_t)k * 256 + nn], h, l);
        w1th[idx] = h; w1tl[idx] = l;
    } else if (idx < 65536) {               // W2 [256,128] -> [128,256]
        int j = idx - 32768;
        int nn = j >> 8, k = j & 255;
        unsigned short h, l; splitf(W2[(size_t)k * 128 + nn], h, l);
        w2th[j] = h; w2tl[j] = l;
    }
}

// ---------------- CSR build -------------------------------------------------
__global__ void count_edges(const int* __restrict__ ei, int E, int Nn,
                            int* __restrict__ counts, int* __restrict__ erank)
{
    int e = blockIdx.x * blockDim.x + threadIdx.x;
    int E2 = E + Nn;
    if (e >= E2) return;
    int dst = (e < E) ? ei[E + e] : (e - E);
    erank[e] = atomicAdd(&counts[dst], 1);
}

__global__ __launch_bounds__(256) void scan_block(
    const int* __restrict__ counts, int* __restrict__ offs, int* __restrict__ bsum, int Nn)
{
    __shared__ int s[256];
    int i = blockIdx.x * 256 + threadIdx.x;
    int v = (i < Nn) ? counts[i] : 0;
    s[threadIdx.x] = v;
    __syncthreads();
    for (int off = 1; off < 256; off <<= 1) {
        int t = (threadIdx.x >= off) ? s[threadIdx.x - off] : 0;
        __syncthreads();
        s[threadIdx.x] += t;
        __syncthreads();
    }
    if (i < Nn) offs[i] = s[threadIdx.x] - v;
    if (threadIdx.x == 255) bsum[blockIdx.x] = s[255];
}

__global__ __launch_bounds__(256) void scan_tops(int* __restrict__ bsum, int* __restrict__ boff, int nb)
{
    __shared__ int s[256];
    int v = (threadIdx.x < nb) ? bsum[threadIdx.x] : 0;
    s[threadIdx.x] = v;
    __syncthreads();
    for (int off = 1; off < 256; off <<= 1) {
        int t = (threadIdx.x >= off) ? s[threadIdx.x - off] : 0;
        __syncthreads();
        s[threadIdx.x] += t;
        __syncthreads();
    }
    if (threadIdx.x < nb) boff[threadIdx.x] = s[threadIdx.x] - v;
}

__global__ void add_offsets(int* __restrict__ offs, const int* __restrict__ boff, int Nn, int E2)
{
    int i = blockIdx.x * blockDim.x + threadIdx.x;
    if (i < Nn) offs[i] += boff[i >> 8];
    if (i == 0) offs[Nn] = E2;
}

__global__ void fill_edges(const int* __restrict__ ei, int E, int Nn,
                           const int* __restrict__ offs, const int* __restrict__ erank,
                           int* __restrict__ esrc)
{
    int e = blockIdx.x * blockDim.x + threadIdx.x;
    int E2 = E + Nn;
    if (e >= E2) return;
    int src, dst;
    if (e < E) { src = ei[e]; dst = ei[E + e]; }
    else       { src = e - E; dst = e - E; }
    esrc[offs[dst] + erank[e]] = src;
}

// ---------------- unpack-FMA helpers ----------------------------------------
__device__ __forceinline__ void fma8(float wA, uint4 hv, float acc[8])
{
    acc[0] = fmaf(wA, bfu2f(hv.x & 0xffff), acc[0]);
    acc[1] = fmaf(wA, __uint_as_float(hv.x & 0xffff0000u), acc[1]);
    acc[2] = fmaf(wA, bfu2f(hv.y & 0xffff), acc[2]);
    acc[3] = fmaf(wA, __uint_as_float(hv.y & 0xffff0000u), acc[3]);
    acc[4] = fmaf(wA, bfu2f(hv.z & 0xffff), acc[4]);
    acc[5] = fmaf(wA, __uint_as_float(hv.z & 0xffff0000u), acc[5]);
    acc[6] = fmaf(wA, bfu2f(hv.w & 0xffff), acc[6]);
    acc[7] = fmaf(wA, __uint_as_float(hv.w & 0xffff0000u), acc[7]);
}

// dual-head FMA: same gathered channels, two weights
__device__ __forceinline__ void fma8x2(float wa, float wb, uint4 hv,
                                       float a0[8], float a1[8])
{
    float f;
    f = bfu2f(hv.x & 0xffff);                 a0[0]=fmaf(wa,f,a0[0]); a1[0]=fmaf(wb,f,a1[0]);
    f = __uint_as_float(hv.x & 0xffff0000u);  a0[1]=fmaf(wa,f,a0[1]); a1[1]=fmaf(wb,f,a1[1]);
    f = bfu2f(hv.y & 0xffff);                 a0[2]=fmaf(wa,f,a0[2]); a1[2]=fmaf(wb,f,a1[2]);
    f = __uint_as_float(hv.y & 0xffff0000u);  a0[3]=fmaf(wa,f,a0[3]); a1[3]=fmaf(wb,f,a1[3]);
    f = bfu2f(hv.z & 0xffff);                 a0[4]=fmaf(wa,f,a0[4]); a1[4]=fmaf(wb,f,a1[4]);
    f = __uint_as_float(hv.z & 0xffff0000u);  a0[5]=fmaf(wa,f,a0[5]); a1[5]=fmaf(wb,f,a1[5]);
    f = bfu2f(hv.w & 0xffff);                 a0[6]=fmaf(wa,f,a0[6]); a1[6]=fmaf(wb,f,a1[6]);
    f = __uint_as_float(hv.w & 0xffff0000u);  a0[7]=fmaf(wa,f,a0[7]); a1[7]=fmaf(wb,f,a1[7]);
}

// 1-head gather: 16 lanes/edge, 4 subslots, row 256 B
__device__ __forceinline__ void gather1h(
    int sj, float w, int nc, int sub,
    const char* __restrict__ hb_c, float acc[8])
{
    for (int t = 0; t < nc; t += 4) {
        int e = t + sub;
        int sA = __shfl(sj, e);
        float wA = __shfl(w, e);
        uint4 hv = *(const uint4*)(hb_c + sA * 256);
        fma8(wA, hv, acc);
    }
}

// dual-head x-gather: 16 lanes/edge, 4 subslots, row 256 B
__device__ __forceinline__ void gatherx(
    int sj, float w0, float w1, int nc, int sub,
    const char* __restrict__ hb_c, float a0[8], float a1[8])
{
    for (int t = 0; t < nc; t += 4) {
        int e = t + sub;
        int sA = __shfl(sj, e);
        float wa = __shfl(w0, e);
        float wb = __shfl(w1, e);
        uint4 hv = *(const uint4*)(hb_c + sA * 256);
        fma8x2(wa, wb, hv, a0, a1);
    }
}

// ---------------- SpMM on input features x (layer 1), dual-head -------------
// out: xt[d, head*128 + c] = sum_s alpha^head_ds x[s,c]  (split planes)
__global__ __launch_bounds__(256) void spmm_x(
    const unsigned short* __restrict__ xh, const float* __restrict__ asrc,
    const float* __restrict__ adst, const int* __restrict__ offs,
    const int* __restrict__ esrc,
    unsigned short* __restrict__ xth, unsigned short* __restrict__ xtl, int Nn)
{
    int d = (int)((blockIdx.x * blockDim.x + threadIdx.x) >> 6);
    int lane = threadIdx.x & 63;
    if (d >= Nn) return;
    int beg = offs[d], end = offs[d + 1];
    int deg = end - beg;
    float ad0 = adst[d * 2], ad1 = adst[d * 2 + 1];
    const int sub = lane >> 4;            // edge subslot 0..3
    const int cgrp = lane & 15;           // 8-ch group
    const char* hb_c = (const char*)xh + cgrp * 16;
    float a0[8] = {}, a1[8] = {};

    if (deg <= 64) {
        int sj = 0; float e0 = -1e30f, e1 = -1e30f;
        if (lane < deg) {
            sj = esrc[beg + lane];
            float2 av = *(const float2*)(asrc + (size_t)sj * 2);
            e0 = av.x + ad0; e0 = e0 > 0.f ? e0 : NEG_SLOPE * e0;
            e1 = av.y + ad1; e1 = e1 > 0.f ? e1 : NEG_SLOPE * e1;
        }
        float m0 = e0, m1 = e1;
        for (int off = 32; off; off >>= 1) {
            m0 = fmaxf(m0, __shfl_xor(m0, off));
            m1 = fmaxf(m1, __shfl_xor(m1, off));
        }
        float p0 = (lane < deg) ? expf(e0 - m0) : 0.f;
        float p1 = (lane < deg) ? expf(e1 - m1) : 0.f;
        float s0 = p0, s1 = p1;
        for (int off = 32; off; off >>= 1) {
            s0 += __shfl_xor(s0, off);
            s1 += __shfl_xor(s1, off);
        }
        float w0 = p0 * (1.f / s0), w1 = p1 * (1.f / s1);
        gatherx(sj, w0, w1, deg, sub, hb_c, a0, a1);
    } else {
        float m0 = -1e30f, m1 = -1e30f;
        for (int j = beg + lane; j < end; j += 64) {
            int s = esrc[j];
            float2 av = *(const float2*)(asrc + (size_t)s * 2);
            float e0 = av.x + ad0; e0 = e0 > 0.f ? e0 : NEG_SLOPE * e0;
            float e1 = av.y + ad1; e1 = e1 > 0.f ? e1 : NEG_SLOPE * e1;
            m0 = fmaxf(m0, e0); m1 = fmaxf(m1, e1);
        }
        for (int off = 32; off; off >>= 1) {
            m0 = fmaxf(m0, __shfl_xor(m0, off));
            m1 = fmaxf(m1, __shfl_xor(m1, off));
        }
        float s0 = 0.f, s1 = 0.f;
        for (int j = beg + lane; j < end; j += 64) {
            int s = esrc[j];
            float2 av = *(const float2*)(asrc + (size_t)s * 2);
            float e0 = av.x + ad0; e0 = e0 > 0.f ? e0 : NEG_SLOPE * e0;
            float e1 = av.y + ad1; e1 = e1 > 0.f ? e1 : NEG_SLOPE * e1;
            s0 += expf(e0 - m0); s1 += expf(e1 - m1);
        }
        for (int off = 32; off; off >>= 1) {
            s0 += __shfl_xor(s0, off);
            s1 += __shfl_xor(s1, off);
        }
        float rd0 = 1.f / s0, rd1 = 1.f / s1;
        for (int base = beg; base < end; base += 64) {
            int nc = end - base; if (nc > 64) nc = 64;
            int sj = 0; float w0 = 0.f, w1 = 0.f;
            if (lane < nc) {
                sj = esrc[base + lane];
                float2 av = *(const float2*)(asrc + (size_t)sj * 2);
                float e0 = av.x + ad0; e0 = e0 > 0.f ? e0 : NEG_SLOPE * e0;
                float e1 = av.y + ad1; e1 = e1 > 0.f ? e1 : NEG_SLOPE * e1;
                w0 = expf(e0 - m0) * rd0;
                w1 = expf(e1 - m1) * rd1;
            }
            gatherx(sj, w0, w1, nc, sub, hb_c, a0, a1);
        }
    }
#pragma unroll
    for (int i = 0; i < 8; ++i) {
        a0[i] += __shfl_xor(a0[i], 32); a0[i] += __shfl_xor(a0[i], 16);
        a1[i] += __shfl_xor(a1[i], 32); a1[i] += __shfl_xor(a1[i], 16);
    }
    if (lane < 16) {
        int cl = cgrp * 8;
        unsigned short h0[8], l0[8], h1[8], l1[8];
#pragma unroll
        for (int i = 0; i < 8; ++i) {
            splitf(a0[i], h0[i], l0[i]);
            splitf(a1[i], h1[i], l1[i]);
        }
        size_t rb = (size_t)d * 256;
        *(uint4*)(xth + rb + cl)       = *(uint4*)&h0[0];
        *(uint4*)(xtl + rb + cl)       = *(uint4*)&l0[0];
        *(uint4*)(xth + rb + 128 + cl) = *(uint4*)&h1[0];
        *(uint4*)(xtl + rb + 128 + cl) = *(uint4*)&l1[0];
    }
}

// ---------------- GEMM1b: x~ @ W1 (block-diagonal per head) + BN + split ----
// A planes [M,256], head k-offset = colBase; B = w1t planes [256 rows][K=128].
__global__ __launch_bounds__(256) void gemm_bn_split(
    const unsigned short* __restrict__ Ah, const unsigned short* __restrict__ Al,
    const unsigned short* __restrict__ Bth, const unsigned short* __restrict__ Btl,
    const float* __restrict__ bias, const float* __restrict__ gamma,
    const float* __restrict__ beta, const float* __restrict__ rm,
    const float* __restrict__ rv,
    unsigned short* __restrict__ Ch, unsigned short* __restrict__ Cl, int M)
{
    __shared__ unsigned short smem[4][128][32];
    const int tid = threadIdx.x;
    const int lane = tid & 63;
    const int wave = tid >> 6;
    const int fr = lane & 15, g = lane >> 4;
    const int wr = (wave >> 1) * 64, wc = (wave & 1) * 64;
    const int rowBase = blockIdx.x * 128, colBase = blockIdx.y * 128;

    f32x4 acc[4][4] = {};

    for (int kk = 0; kk < 128; kk += 32) {
#pragma unroll
        for (int i = 0; i < 2; ++i) {
            int idx = tid + 256 * i;
            int r = idx >> 2, c = (idx & 3) * 8;
            int grow = rowBase + r;
            uint4 va_h, va_l;
            if (grow < M) {
                va_h = *(const uint4*)(Ah + (size_t)grow * 256 + colBase + kk + c);
                va_l = *(const uint4*)(Al + (size_t)grow * 256 + colBase + kk + c);
            } else {
                va_h = make_uint4(0, 0, 0, 0); va_l = make_uint4(0, 0, 0, 0);
            }
            *(uint4*)&smem[0][r][c] = va_h;
            *(uint4*)&smem[1][r][c] = va_l;
            int gcol = colBase + r;
            *(uint4*)&smem[2][r][c] = *(const uint4*)(Bth + (size_t)gcol * 128 + kk + c);
            *(uint4*)&smem[3][r][c] = *(const uint4*)(Btl + (size_t)gcol * 128 + kk + c);
        }
        __syncthreads();

        bf16x8 ah[4], al[4], bh[4], bl[4];
#pragma unroll
        for (int m = 0; m < 4; ++m) {
            ah[m] = *(const bf16x8*)&smem[0][wr + m * 16 + fr][g * 8];
            al[m] = *(const bf16x8*)&smem[1][wr + m * 16 + fr][g * 8];
        }
#pragma unroll
        for (int n = 0; n < 4; ++n) {
            bh[n] = *(const bf16x8*)&smem[2][wc + n * 16 + fr][g * 8];
            bl[n] = *(const bf16x8*)&smem[3][wc + n * 16 + fr][g * 8];
        }
#pragma unroll
        for (int m = 0; m < 4; ++m)
#pragma unroll
            for (int n = 0; n < 4; ++n) {
                acc[m][n] = __builtin_amdgcn_mfma_f32_16x16x32_bf16(ah[m], bh[n], acc[m][n], 0, 0, 0);
                acc[m][n] = __builtin_amdgcn_mfma_f32_16x16x32_bf16(ah[m], bl[n], acc[m][n], 0, 0, 0);
                acc[m][n] = __builtin_amdgcn_mfma_f32_16x16x32_bf16(al[m], bh[n], acc[m][n], 0, 0, 0);
            }
        __syncthreads();
    }

    // per-fragment bias + BN + ReLU (params per output col)
    {
        float bi[4], ga[4], bb[4], mu[4], iv[4];
#pragma unroll
        for (int n = 0; n < 4; ++n) {
            int c = colBase + wc + n * 16 + fr;
            bi[n] = bias[c]; ga[n] = gamma[c]; bb[n] = beta[c];
            mu[n] = rm[c];   iv[n] = rsqrtf(rv[c] + EPSBN);
        }
#pragma unroll
        for (int m = 0; m < 4; ++m)
#pragma unroll
            for (int n = 0; n < 4; ++n)
#pragma unroll
                for (int j = 0; j < 4; ++j) {
                    float v = acc[m][n][j] + bi[n];
                    v = ga[n] * (v - mu[n]) * iv[n] + bb[n];
                    acc[m][n][j] = fmaxf(v, 0.f);
                }
    }

    // transpose epilogue, split bf16 stores to both planes
    float* Cs = (float*)&smem[0][0][0];
    const int rl_w = (wr >> 6) * 16;
#pragma unroll
    for (int m = 0; m < 4; ++m) {
        __syncthreads();
#pragma unroll
        for (int n = 0; n < 4; ++n)
#pragma unroll
            for (int j = 0; j < 4; ++j)
                Cs[(rl_w + g * 4 + j) * 132 + wc + n * 16 + fr] = acc[m][n][j];
        __syncthreads();
        int rl = tid >> 3, c16 = (tid & 7) * 16;
        int grow = rowBase + (rl >> 4) * 64 + m * 16 + (rl & 15);
        if (grow < M) {
            unsigned short th[16], tl[16];
#pragma unroll
            for (int i = 0; i < 16; ++i) splitf(Cs[rl * 132 + c16 + i], th[i], tl[i]);
            size_t ob = (size_t)grow * 256 + colBase + c16;
            *(uint4*)(Ch + ob)     = *(uint4*)&th[0];
            *(uint4*)(Ch + ob + 8) = *(uint4*)&th[8];
            *(uint4*)(Cl + ob)     = *(uint4*)&tl[0];
            *(uint4*)(Cl + ob + 8) = *(uint4*)&tl[8];
        }
    }
}

// ---------------- MFMA GEMM + fused attention coefficients (layer 2) --------
__global__ __launch_bounds__(256) void gemm_bf16_split_attn(
    const unsigned short* __restrict__ Ah, const unsigned short* __restrict__ Al,
    const unsigned short* __restrict__ Bth, const unsigned short* __restrict__ Btl,
    unsigned short* __restrict__ Cb,
    const float* __restrict__ aSrc, const float* __restrict__ aDst,
    float* __restrict__ asrcOut, float* __restrict__ adstOut,
    int M, int N, int K, int heads)
{
    __shared__ unsigned short smem[4][128][32];
    const int tid = threadIdx.x;
    const int lane = tid & 63;
    const int wave = tid >> 6;
    const int fr = lane & 15, g = lane >> 4;
    const int wr = (wave >> 1) * 64, wc = (wave & 1) * 64;
    const int rowBase = blockIdx.x * 128, colBase = blockIdx.y * 128;

    f32x4 acc[4][4] = {};

    for (int kk = 0; kk < K; kk += 32) {
#pragma unroll
        for (int i = 0; i < 2; ++i) {
            int idx = tid + 256 * i;
            int r = idx >> 2, c = (idx & 3) * 8;
            int grow = rowBase + r;
            uint4 va_h, va_l;
            if (grow < M) {
                va_h = *(const uint4*)(Ah + (size_t)grow * K + kk + c);
                va_l = *(const uint4*)(Al + (size_t)grow * K + kk + c);
            } else {
                va_h = make_uint4(0, 0, 0, 0); va_l = make_uint4(0, 0, 0, 0);
            }
            *(uint4*)&smem[0][r][c] = va_h;
            *(uint4*)&smem[1][r][c] = va_l;
            int gcol = colBase + r;
            *(uint4*)&smem[2][r][c] = *(const uint4*)(Bth + (size_t)gcol * K + kk + c);
            *(uint4*)&smem[3][r][c] = *(const uint4*)(Btl + (size_t)gcol * K + kk + c);
        }
        __syncthreads();

        bf16x8 ah[4], al[4], bh[4], bl[4];
#pragma unroll
        for (int m = 0; m < 4; ++m) {
            ah[m] = *(const bf16x8*)&smem[0][wr + m * 16 + fr][g * 8];
            al[m] = *(const bf16x8*)&smem[1][wr + m * 16 + fr][g * 8];
        }
#pragma unroll
        for (int n = 0; n < 4; ++n) {
            bh[n] = *(const bf16x8*)&smem[2][wc + n * 16 + fr][g * 8];
            bl[n] = *(const bf16x8*)&smem[3][wc + n * 16 + fr][g * 8];
        }
#pragma unroll
        for (int m = 0; m < 4; ++m)
#pragma unroll
            for (int n = 0; n < 4; ++n) {
                acc[m][n] = __builtin_amdgcn_mfma_f32_16x16x32_bf16(ah[m], bh[n], acc[m][n], 0, 0, 0);
                acc[m][n] = __builtin_amdgcn_mfma_f32_16x16x32_bf16(ah[m], bl[n], acc[m][n], 0, 0, 0);
                acc[m][n] = __builtin_amdgcn_mfma_f32_16x16x32_bf16(al[m], bh[n], acc[m][n], 0, 0, 0);
            }
        __syncthreads();
    }

    // fused attention coefficient partials
    {
        const int head = colBase >> 7;
        float avs[4], avd[4];
#pragma unroll
        for (int n = 0; n < 4; ++n) {
            int col = colBase + wc + n * 16 + fr;
            avs[n] = aSrc[col]; avd[n] = aDst[col];
        }
#pragma unroll
        for (int m = 0; m < 4; ++m) {
            float ps[4], pd[4];
#pragma unroll
            for (int j = 0; j < 4; ++j) {
                ps[j] = acc[m][0][j] * avs[0] + acc[m][1][j] * avs[1]
                      + acc[m][2][j] * avs[2] + acc[m][3][j] * avs[3];
                pd[j] = acc[m][0][j] * avd[0] + acc[m][1][j] * avd[1]
                      + acc[m][2][j] * avd[2] + acc[m][3][j] * avd[3];
            }
#pragma unroll
            for (int off = 8; off; off >>= 1)
#pragma unroll
                for (int j = 0; j < 4; ++j) {
                    ps[j] += __shfl_xor(ps[j], off);
                    pd[j] += __shfl_xor(pd[j], off);
                }
            if (fr == 0) {
#pragma unroll
                for (int j = 0; j < 4; ++j) {
                    int grow = rowBase + wr + m * 16 + g * 4 + j;
                    if (grow < M) {
                        atomicAdd(asrcOut + (size_t)grow * heads + head, ps[j]);
                        atomicAdd(adstOut + (size_t)grow * heads + head, pd[j]);
                    }
                }
            }
        }
    }

    // transpose epilogue, single bf16 plane
    float* Cs = (float*)&smem[0][0][0];
    const int rl_w = (wr >> 6) * 16;
#pragma unroll
    for (int m = 0; m < 4; ++m) {
        __syncthreads();
#pragma unroll
        for (int n = 0; n < 4; ++n)
#pragma unroll
            for (int j = 0; j < 4; ++j)
                Cs[(rl_w + g * 4 + j) * 132 + wc + n * 16 + fr] = acc[m][n][j];
        __syncthreads();
        int rl = tid >> 3, c16 = (tid & 7) * 16;
        int grow = rowBase + (rl >> 4) * 64 + m * 16 + (rl & 15);
        if (grow < M) {
            unsigned short tmp[16];
#pragma unroll
            for (int i = 0; i < 16; ++i) tmp[i] = f2bf(Cs[rl * 132 + c16 + i]);
            *(uint4*)(Cb + (size_t)grow * N + colBase + c16)     = *(uint4*)&tmp[0];
            *(uint4*)(Cb + (size_t)grow * N + colBase + c16 + 8) = *(uint4*)&tmp[8];
        }
    }
}

// ---------------- SpMM layer 2 (all 128 ch) + fused softmax ------------------
__global__ __launch_bounds__(256) void spmm2(
    const unsigned short* __restrict__ h2b, const float* __restrict__ asrc,
    const float* __restrict__ adst, const int* __restrict__ offs,
    const int* __restrict__ esrc,
    const float* __restrict__ b2, const float* __restrict__ gamma,
    const float* __restrict__ beta, const float* __restrict__ rm,
    const float* __restrict__ rv, float* __restrict__ x3, int Nn)
{
    int d = (int)((blockIdx.x * blockDim.x + threadIdx.x) >> 6);
    int lane = threadIdx.x & 63;
    if (d >= Nn) return;
    int beg = offs[d], end = offs[d + 1];
    int deg = end - beg;
    float ad = adst[d];
    const int sub = lane >> 4;
    const int cgrp = lane & 15;
    const char* hb_c = (const char*)h2b + cgrp * 16;
    float acc[8] = {};

    if (deg <= 64) {
        int sj = 0; float ev = -1e30f;
        if (lane < deg) {
            sj = esrc[beg + lane];
            float e = asrc[sj] + ad; ev = e > 0.f ? e : NEG_SLOPE * e;
        }
        float m = ev;
        for (int off = 32; off; off >>= 1) m = fmaxf(m, __shfl_xor(m, off));
        float p = (lane < deg) ? expf(ev - m) : 0.f;
        float s = p;
        for (int off = 32; off; off >>= 1) s += __shfl_xor(s, off);
        float w = p * (1.f / s);
        gather1h(sj, w, deg, sub, hb_c, acc);
    } else {
        float m = -1e30f;
        for (int j = beg + lane; j < end; j += 64) {
            int s = esrc[j];
            float e = asrc[s] + ad; e = e > 0.f ? e : NEG_SLOPE * e;
            m = fmaxf(m, e);
        }
        for (int off = 32; off; off >>= 1) m = fmaxf(m, __shfl_xor(m, off));
        float sd = 0.f;
        for (int j = beg + lane; j < end; j += 64) {
            int s = esrc[j];
            float e = asrc[s] + ad; e = e > 0.f ? e : NEG_SLOPE * e;
            sd += expf(e - m);
        }
        for (int off = 32; off; off >>= 1) sd += __shfl_xor(sd, off);
        float rd = 1.f / sd;
        for (int base = beg; base < end; base += 64) {
            int nc = end - base; if (nc > 64) nc = 64;
            int sj = 0; float wj = 0.f;
            if (lane < nc) {
                sj = esrc[base + lane];
                float e = asrc[sj] + ad; e = e > 0.f ? e : NEG_SLOPE * e;
                wj = expf(e - m) * rd;
            }
            gather1h(sj, wj, nc, sub, hb_c, acc);
        }
    }
#pragma unroll
    for (int i = 0; i < 8; ++i) {
        acc[i] += __shfl_xor(acc[i], 32);
        acc[i] += __shfl_xor(acc[i], 16);
    }
    if (lane < 16) {
        int cl = cgrp * 8;
        float vv[8];
#pragma unroll
        for (int i = 0; i < 8; ++i) {
            int c = cl + i;
            float v = acc[i] + b2[c];
            v = gamma[c] * (v - rm[c]) * rsqrtf(rv[c] + EPSBN) + beta[c];
            vv[i] = fmaxf(v, 0.f);
        }
        *(float4*)(x3 + (size_t)d * 128 + cl)     = make_float4(vv[0], vv[1], vv[2], vv[3]);
        *(float4*)(x3 + (size_t)d * 128 + cl + 4) = make_float4(vv[4], vv[5], vv[6], vv[7]);
    }
}

// ---------------- global max pool: one block per graph, no atomics ----------
__global__ __launch_bounds__(128) void pool_max_graph(
    const float* __restrict__ x3, const int* __restrict__ bat,
    float* __restrict__ out, int Nn)
{
    int g = blockIdx.x;
    int c = threadIdx.x;
    int lo = 0, hi = Nn;
    while (lo < hi) { int mid = (lo + hi) >> 1; if (bat[mid] < g) lo = mid + 1; else hi = mid; }
    int beg = lo;
    hi = Nn;
    while (lo < hi) { int mid = (lo + hi) >> 1; if (bat[mid] < g + 1) lo = mid + 1; else hi = mid; }
    int end = lo;
    float acc = -1e30f;
    for (int n = beg; n < end; ++n)
        acc = fmaxf(acc, x3[(size_t)n * 128 + c]);
    out[(size_t)g * 128 + c] = acc;
}

// ---------------------------------------------------------------------------
extern "C" void kernel_launch(void* const* d_in, const int* in_sizes, int n_in,
                              void* d_out, int out_size, void* d_ws, size_t ws_size,
                              hipStream_t stream)
{
    const float* x   = (const float*)d_in[0];
    const int*   ei  = (const int*)d_in[1];
    const int*   bat = (const int*)d_in[2];
    const float* W1  = (const float*)d_in[3];
    const float* as1 = (const float*)d_in[4];
    const float* ad1 = (const float*)d_in[5];
    const float* b1  = (const float*)d_in[6];
    const float* g1  = (const float*)d_in[7];
    const float* be1 = (const float*)d_in[8];
    const float* rm1 = (const float*)d_in[9];
    const float* rv1 = (const float*)d_in[10];
    const float* W2  = (const float*)d_in[11];
    const float* as2 = (const float*)d_in[12];
    const float* ad2 = (const float*)d_in[13];
    const float* b2  = (const float*)d_in[14];
    const float* g2  = (const float*)d_in[15];
    const float* be2 = (const float*)d_in[16];
    const float* rm2 = (const float*)d_in[17];
    const float* rv2 = (const float*)d_in[18];
    float* out = (float*)d_out;

    const int Nn = in_sizes[0] / 128;
    const int E  = in_sizes[1] / 2;
    const int E2 = E + Nn;
    const int B  = out_size / 128;

    char* p = (char*)d_ws;
    size_t off = 0;
    auto alloc = [&](size_t bytes) -> void* {
        void* r = p + off;
        off = (off + bytes + 255) & ~(size_t)255;
        return r;
    };
    unsigned short* xh    = (unsigned short*)alloc((size_t)Nn * 128 * 2);
    unsigned short* xl    = (unsigned short*)alloc((size_t)Nn * 128 * 2);
    unsigned short* w1th  = (unsigned short*)alloc(256 * 128 * 2);
    unsigned short* w1tl  = (unsigned short*)alloc(256 * 128 * 2);
    unsigned short* w2th  = (unsigned short*)alloc(128 * 256 * 2);
    unsigned short* w2tl  = (unsigned short*)alloc(128 * 256 * 2);
    unsigned short* xth   = (unsigned short*)alloc((size_t)Nn * 256 * 2);
    unsigned short* xtl   = (unsigned short*)alloc((size_t)Nn * 256 * 2);
    unsigned short* x2h   = (unsigned short*)alloc((size_t)Nn * 256 * 2);
    unsigned short* x2l   = (unsigned short*)alloc((size_t)Nn * 256 * 2);
    float*          vsd   = (float*)alloc(4 * 128 * 4);
    float*          asrc1 = (float*)alloc((size_t)Nn * 2 * 4);
    float*          adst1 = (float*)alloc((size_t)Nn * 2 * 4);
    float*          attnv = (float*)alloc((size_t)Nn * 2 * 4);   // asrc2, adst2
    float*          asrc2 = attnv;
    float*          adst2 = attnv + Nn;
    int*            counts= (int*)alloc((size_t)Nn * 4);
    int*            erank = (int*)alloc((size_t)E2 * 4);
    int*            offs  = (int*)alloc((size_t)(Nn + 1) * 4);
    int*            bsum  = (int*)alloc(256 * 4);
    int*            boff  = (int*)alloc(256 * 4);
    int*            esrc  = (int*)alloc((size_t)E2 * 4);
    // aliases: xth dead after gemm1b -> x3; xh dead after spmm_x -> h2b
    float*          x3    = (float*)xth;
    unsigned short* h2b   = xh;

    const int nb = (Nn + 255) / 256;
    const int nwB = (Nn + 3) / 4;
    const int gmB = (Nn + 127) / 128;

    hipMemsetAsync(counts, 0, (size_t)Nn * 4, stream);
    hipMemsetAsync(attnv, 0, (size_t)Nn * 2 * 4, stream);

    // ---- precompute + splits + layer-1 attn coefs
    precompute_v<<<1, 128, 0, stream>>>(W1, as1, ad1, vsd);
    split_x_attn<<<nwB, 256, 0, stream>>>(x, vsd, xh, xl, asrc1, adst1, Nn);
    split_w_both<<<(65536 + 255) / 256, 256, 0, stream>>>(W1, W2, w1th, w1tl, w2th, w2tl);

    // ---- CSR build
    count_edges<<<(E2 + 255) / 256, 256, 0, stream>>>(ei, E, Nn, counts, erank);
    scan_block<<<nb, 256, 0, stream>>>(counts, offs, bsum, Nn);
    scan_tops<<<1, 256, 0, stream>>>(bsum, boff, nb);
    add_offsets<<<(Nn + 255) / 256, 256, 0, stream>>>(offs, boff, Nn, E2);
    fill_edges<<<(E2 + 255) / 256, 256, 0, stream>>>(ei, E, Nn, offs, erank, esrc);

    // ---- layer 1: aggregate x (dual-head) then project + BN + ReLU
    spmm_x<<<nwB, 256, 0, stream>>>(xh, asrc1, adst1, offs, esrc, xth, xtl, Nn);
    gemm_bn_split<<<dim3(gmB, 2), 256, 0, stream>>>(
        xth, xtl, w1th, w1tl, b1, g1, be1, rm1, rv1, x2h, x2l, Nn);

    // ---- layer 2: GEMM (+attn coef) then SpMM
    gemm_bf16_split_attn<<<dim3(gmB, 1), 256, 0, stream>>>(
        x2h, x2l, w2th, w2tl, h2b, as2, ad2, asrc2, adst2, Nn, 128, 256, 1);
    spmm2<<<nwB, 256, 0, stream>>>(h2b, asrc2, adst2, offs, esrc,
                                   b2, g2, be2, rm2, rv2, x3, Nn);

    // ---- global max pool
    pool_max_graph<<<B, 128, 0, stream>>>(x3, bat, out, Nn);
}

// Round 9
// 267.200 us; speedup vs baseline: 1.0529x; 1.0208x over previous
//
#include <hip/hip_runtime.h>
#include <hip/hip_bf16.h>
#include <math.h>

#define NEG_SLOPE 0.2f
#define EPSBN 1e-5f

typedef __attribute__((ext_vector_type(8))) short bf16x8;
typedef __attribute__((ext_vector_type(4))) float f32x4;

__device__ __forceinline__ float bfu2f(unsigned u_lo16) { return __uint_as_float(u_lo16 << 16); }
__device__ __forceinline__ unsigned short f2bf(float f) {
    return __bfloat16_as_ushort(__float2bfloat16(f));
}
__device__ __forceinline__ void splitf(float v, unsigned short &h, unsigned short &l) {
    __hip_bfloat16 hb = __float2bfloat16(v);
    float r = v - __bfloat162float(hb);
    h = __bfloat16_as_ushort(hb);
    l = __bfloat16_as_ushort(__float2bfloat16(r));
}

// ---------------- precompute v = W1 @ a vectors ------------------------------
__global__ void precompute_v(const float* __restrict__ W1, const float* __restrict__ as1,
                             const float* __restrict__ ad1, float* __restrict__ vsd)
{
    int k = threadIdx.x;
    if (k >= 128) return;
    float v0 = 0.f, v1 = 0.f, v2 = 0.f, v3 = 0.f;
    const float* wr = W1 + (size_t)k * 256;
    for (int c = 0; c < 128; ++c) {
        float wa = wr[c], wb = wr[128 + c];
        v0 += wa * as1[c];  v1 += wb * as1[128 + c];
        v2 += wa * ad1[c];  v3 += wb * ad1[128 + c];
    }
    vsd[k] = v0; vsd[128 + k] = v1; vsd[256 + k] = v2; vsd[384 + k] = v3;
}

// ---------------- split x (bf16 plane) + layer-1 attn coefficients -----------
__global__ __launch_bounds__(256) void split_x_attn(
    const float* __restrict__ X, const float* __restrict__ vsd,
    unsigned short* __restrict__ Xh,
    float* __restrict__ asrc, float* __restrict__ adst, int Nn)
{
    int n = (int)((blockIdx.x * blockDim.x + threadIdx.x) >> 6);
    int lane = threadIdx.x & 63;
    if (n >= Nn) return;
    float2 xv = *(const float2*)(X + (size_t)n * 128 + lane * 2);
    unsigned short hh[2] = {f2bf(xv.x), f2bf(xv.y)};
    *(unsigned*)(Xh + (size_t)n * 128 + lane * 2) = *(unsigned*)hh;
    int k = lane * 2;
    float p0 = xv.x * vsd[k]       + xv.y * vsd[k + 1];
    float p1 = xv.x * vsd[128 + k] + xv.y * vsd[129 + k];
    float p2 = xv.x * vsd[256 + k] + xv.y * vsd[257 + k];
    float p3 = xv.x * vsd[384 + k] + xv.y * vsd[385 + k];
    for (int off = 32; off; off >>= 1) {
        p0 += __shfl_xor(p0, off); p1 += __shfl_xor(p1, off);
        p2 += __shfl_xor(p2, off); p3 += __shfl_xor(p3, off);
    }
    if (lane == 0) {
        asrc[n * 2] = p0; asrc[n * 2 + 1] = p1;
        adst[n * 2] = p2; adst[n * 2 + 1] = p3;
    }
}

// both weights -> transposed split planes [N,K]
__global__ void split_w_both(const float* __restrict__ W1, const float* __restrict__ W2,
                             unsigned short* __restrict__ w1th, unsigned short* __restrict__ w1tl,
                             unsigned short* __restrict__ w2th, unsigned short* __restrict__ w2tl)
{
    int idx = blockIdx.x * blockDim.x + threadIdx.x;
    if (idx < 32768) {                      // W1 [128,256] -> [256,128]
        int nn = idx >> 7, k = idx & 127;
        unsigned short h, l; splitf(W1[(size_t)k * 256 + nn], h, l);
        w1th[idx] = h; w1tl[idx] = l;
    } else if (idx < 65536) {               // W2 [256,128] -> [128,256]
        int j = idx - 32768;
        int nn = j >> 8, k = j & 255;
        unsigned short h, l; splitf(W2[(size_t)k * 128 + nn], h, l);
        w2th[j] = h; w2tl[j] = l;
    }
}

// ---------------- CSR build -------------------------------------------------
__global__ void count_edges(const int* __restrict__ ei, int E, int Nn,
                            int* __restrict__ counts, int* __restrict__ erank)
{
    int e = blockIdx.x * blockDim.x + threadIdx.x;
    int E2 = E + Nn;
    if (e >= E2) return;
    int dst = (e < E) ? ei[E + e] : (e - E);
    erank[e] = atomicAdd(&counts[dst], 1);
}

__global__ __launch_bounds__(256) void scan_block(
    const int* __restrict__ counts, int* __restrict__ offs, int* __restrict__ bsum, int Nn)
{
    __shared__ int s[256];
    int i = blockIdx.x * 256 + threadIdx.x;
    int v = (i < Nn) ? counts[i] : 0;
    s[threadIdx.x] = v;
    __syncthreads();
    for (int off = 1; off < 256; off <<= 1) {
        int t = (threadIdx.x >= off) ? s[threadIdx.x - off] : 0;
        __syncthreads();
        s[threadIdx.x] += t;
        __syncthreads();
    }
    if (i < Nn) offs[i] = s[threadIdx.x] - v;
    if (threadIdx.x == 255) bsum[blockIdx.x] = s[255];
}

__global__ __launch_bounds__(256) void scan_tops(int* __restrict__ bsum, int* __restrict__ boff, int nb)
{
    __shared__ int s[256];
    int v = (threadIdx.x < nb) ? bsum[threadIdx.x] : 0;
    s[threadIdx.x] = v;
    __syncthreads();
    for (int off = 1; off < 256; off <<= 1) {
        int t = (threadIdx.x >= off) ? s[threadIdx.x - off] : 0;
        __syncthreads();
        s[threadIdx.x] += t;
        __syncthreads();
    }
    if (threadIdx.x < nb) boff[threadIdx.x] = s[threadIdx.x] - v;
}

__global__ void add_offsets(int* __restrict__ offs, const int* __restrict__ boff, int Nn, int E2)
{
    int i = blockIdx.x * blockDim.x + threadIdx.x;
    if (i < Nn) offs[i] += boff[i >> 8];
    if (i == 0) offs[Nn] = E2;
}

__global__ void fill_edges(const int* __restrict__ ei, int E, int Nn,
                           const int* __restrict__ offs, const int* __restrict__ erank,
                           int* __restrict__ esrc)
{
    int e = blockIdx.x * blockDim.x + threadIdx.x;
    int E2 = E + Nn;
    if (e >= E2) return;
    int src, dst;
    if (e < E) { src = ei[e]; dst = ei[E + e]; }
    else       { src = e - E; dst = e - E; }
    esrc[offs[dst] + erank[e]] = src;
}

// ---------------- unpack-FMA helpers ----------------------------------------
__device__ __forceinline__ void fma8(float wA, uint4 hv, float acc[8])
{
    acc[0] = fmaf(wA, bfu2f(hv.x & 0xffff), acc[0]);
    acc[1] = fmaf(wA, __uint_as_float(hv.x & 0xffff0000u), acc[1]);
    acc[2] = fmaf(wA, bfu2f(hv.y & 0xffff), acc[2]);
    acc[3] = fmaf(wA, __uint_as_float(hv.y & 0xffff0000u), acc[3]);
    acc[4] = fmaf(wA, bfu2f(hv.z & 0xffff), acc[4]);
    acc[5] = fmaf(wA, __uint_as_float(hv.z & 0xffff0000u), acc[5]);
    acc[6] = fmaf(wA, bfu2f(hv.w & 0xffff), acc[6]);
    acc[7] = fmaf(wA, __uint_as_float(hv.w & 0xffff0000u), acc[7]);
}

__device__ __forceinline__ void fma8x2(float wa, float wb, uint4 hv,
                                       float a0[8], float a1[8])
{
    float f;
    f = bfu2f(hv.x & 0xffff);                 a0[0]=fmaf(wa,f,a0[0]); a1[0]=fmaf(wb,f,a1[0]);
    f = __uint_as_float(hv.x & 0xffff0000u);  a0[1]=fmaf(wa,f,a0[1]); a1[1]=fmaf(wb,f,a1[1]);
    f = bfu2f(hv.y & 0xffff);                 a0[2]=fmaf(wa,f,a0[2]); a1[2]=fmaf(wb,f,a1[2]);
    f = __uint_as_float(hv.y & 0xffff0000u);  a0[3]=fmaf(wa,f,a0[3]); a1[3]=fmaf(wb,f,a1[3]);
    f = bfu2f(hv.z & 0xffff);                 a0[4]=fmaf(wa,f,a0[4]); a1[4]=fmaf(wb,f,a1[4]);
    f = __uint_as_float(hv.z & 0xffff0000u);  a0[5]=fmaf(wa,f,a0[5]); a1[5]=fmaf(wb,f,a1[5]);
    f = bfu2f(hv.w & 0xffff);                 a0[6]=fmaf(wa,f,a0[6]); a1[6]=fmaf(wb,f,a1[6]);
    f = __uint_as_float(hv.w & 0xffff0000u);  a0[7]=fmaf(wa,f,a0[7]); a1[7]=fmaf(wb,f,a1[7]);
}

// 1-head gather: 16 lanes/edge, 4 subslots, row 256 B
__device__ __forceinline__ void gather1h(
    int sj, float w, int nc, int sub,
    const char* __restrict__ hb_c, float acc[8])
{
    for (int t = 0; t < nc; t += 4) {
        int e = t + sub;
        int sA = __shfl(sj, e);
        float wA = __shfl(w, e);
        uint4 hv = *(const uint4*)(hb_c + sA * 256);
        fma8(wA, hv, acc);
    }
}

// dual-head x-gather: 16 lanes/edge, 4 subslots, row 256 B
__device__ __forceinline__ void gatherx(
    int sj, float w0, float w1, int nc, int sub,
    const char* __restrict__ hb_c, float a0[8], float a1[8])
{
    for (int t = 0; t < nc; t += 4) {
        int e = t + sub;
        int sA = __shfl(sj, e);
        float wa = __shfl(w0, e);
        float wb = __shfl(w1, e);
        uint4 hv = *(const uint4*)(hb_c + sA * 256);
        fma8x2(wa, wb, hv, a0, a1);
    }
}

// ---------------- SpMM on input features x (layer 1), dual-head -------------
// out: xth[d, head*128 + c] = bf16( sum_s alpha^head_ds x[s,c] )
__global__ __launch_bounds__(256) void spmm_x(
    const unsigned short* __restrict__ xh, const float* __restrict__ asrc,
    const float* __restrict__ adst, const int* __restrict__ offs,
    const int* __restrict__ esrc,
    unsigned short* __restrict__ xth, int Nn)
{
    int d = (int)((blockIdx.x * blockDim.x + threadIdx.x) >> 6);
    int lane = threadIdx.x & 63;
    if (d >= Nn) return;
    int beg = offs[d], end = offs[d + 1];
    int deg = end - beg;
    float ad0 = adst[d * 2], ad1 = adst[d * 2 + 1];
    const int sub = lane >> 4;            // edge subslot 0..3
    const int cgrp = lane & 15;           // 8-ch group
    const char* hb_c = (const char*)xh + cgrp * 16;
    float a0[8] = {}, a1[8] = {};

    if (deg <= 64) {
        int sj = 0; float e0 = -1e30f, e1 = -1e30f;
        if (lane < deg) {
            sj = esrc[beg + lane];
            float2 av = *(const float2*)(asrc + (size_t)sj * 2);
            e0 = av.x + ad0; e0 = e0 > 0.f ? e0 : NEG_SLOPE * e0;
            e1 = av.y + ad1; e1 = e1 > 0.f ? e1 : NEG_SLOPE * e1;
        }
        float m0 = e0, m1 = e1;
        for (int off = 32; off; off >>= 1) {
            m0 = fmaxf(m0, __shfl_xor(m0, off));
            m1 = fmaxf(m1, __shfl_xor(m1, off));
        }
        float p0 = (lane < deg) ? expf(e0 - m0) : 0.f;
        float p1 = (lane < deg) ? expf(e1 - m1) : 0.f;
        float s0 = p0, s1 = p1;
        for (int off = 32; off; off >>= 1) {
            s0 += __shfl_xor(s0, off);
            s1 += __shfl_xor(s1, off);
        }
        float w0 = p0 * (1.f / s0), w1 = p1 * (1.f / s1);
        gatherx(sj, w0, w1, deg, sub, hb_c, a0, a1);
    } else {
        float m0 = -1e30f, m1 = -1e30f;
        for (int j = beg + lane; j < end; j += 64) {
            int s = esrc[j];
            float2 av = *(const float2*)(asrc + (size_t)s * 2);
            float e0 = av.x + ad0; e0 = e0 > 0.f ? e0 : NEG_SLOPE * e0;
            float e1 = av.y + ad1; e1 = e1 > 0.f ? e1 : NEG_SLOPE * e1;
            m0 = fmaxf(m0, e0); m1 = fmaxf(m1, e1);
        }
        for (int off = 32; off; off >>= 1) {
            m0 = fmaxf(m0, __shfl_xor(m0, off));
            m1 = fmaxf(m1, __shfl_xor(m1, off));
        }
        float s0 = 0.f, s1 = 0.f;
        for (int j = beg + lane; j < end; j += 64) {
            int s = esrc[j];
            float2 av = *(const float2*)(asrc + (size_t)s * 2);
            float e0 = av.x + ad0; e0 = e0 > 0.f ? e0 : NEG_SLOPE * e0;
            float e1 = av.y + ad1; e1 = e1 > 0.f ? e1 : NEG_SLOPE * e1;
            s0 += expf(e0 - m0); s1 += expf(e1 - m1);
        }
        for (int off = 32; off; off >>= 1) {
            s0 += __shfl_xor(s0, off);
            s1 += __shfl_xor(s1, off);
        }
        float rd0 = 1.f / s0, rd1 = 1.f / s1;
        for (int base = beg; base < end; base += 64) {
            int nc = end - base; if (nc > 64) nc = 64;
            int sj = 0; float w0 = 0.f, w1 = 0.f;
            if (lane < nc) {
                sj = esrc[base + lane];
                float2 av = *(const float2*)(asrc + (size_t)sj * 2);
                float e0 = av.x + ad0; e0 = e0 > 0.f ? e0 : NEG_SLOPE * e0;
                float e1 = av.y + ad1; e1 = e1 > 0.f ? e1 : NEG_SLOPE * e1;
                w0 = expf(e0 - m0) * rd0;
                w1 = expf(e1 - m1) * rd1;
            }
            gatherx(sj, w0, w1, nc, sub, hb_c, a0, a1);
        }
    }
#pragma unroll
    for (int i = 0; i < 8; ++i) {
        a0[i] += __shfl_xor(a0[i], 32); a0[i] += __shfl_xor(a0[i], 16);
        a1[i] += __shfl_xor(a1[i], 32); a1[i] += __shfl_xor(a1[i], 16);
    }
    if (lane < 16) {
        int cl = cgrp * 8;
        unsigned short h0[8], h1[8];
#pragma unroll
        for (int i = 0; i < 8; ++i) { h0[i] = f2bf(a0[i]); h1[i] = f2bf(a1[i]); }
        size_t rb = (size_t)d * 256;
        *(uint4*)(xth + rb + cl)       = *(uint4*)&h0[0];
        *(uint4*)(xth + rb + 128 + cl) = *(uint4*)&h1[0];
    }
}

// ---------------- GEMM1b: x~ @ W1 (block-diag per head) + BN + split out ----
// A single bf16 plane [M,256] (head k-offset = colBase); B = w1t split planes.
__global__ __launch_bounds__(256) void gemm_bn_split(
    const unsigned short* __restrict__ Ah,
    const unsigned short* __restrict__ Bth, const unsigned short* __restrict__ Btl,
    const float* __restrict__ bias, const float* __restrict__ gamma,
    const float* __restrict__ beta, const float* __restrict__ rm,
    const float* __restrict__ rv,
    unsigned short* __restrict__ Ch, unsigned short* __restrict__ Cl, int M)
{
    __shared__ unsigned short smem[3][128][32];
    const int tid = threadIdx.x;
    const int lane = tid & 63;
    const int wave = tid >> 6;
    const int fr = lane & 15, g = lane >> 4;
    const int wr = (wave >> 1) * 64, wc = (wave & 1) * 64;
    const int rowBase = blockIdx.x * 128, colBase = blockIdx.y * 128;

    f32x4 acc[4][4] = {};

    for (int kk = 0; kk < 128; kk += 32) {
#pragma unroll
        for (int i = 0; i < 2; ++i) {
            int idx = tid + 256 * i;
            int r = idx >> 2, c = (idx & 3) * 8;
            int grow = rowBase + r;
            uint4 va_h = make_uint4(0, 0, 0, 0);
            if (grow < M) va_h = *(const uint4*)(Ah + (size_t)grow * 256 + colBase + kk + c);
            *(uint4*)&smem[0][r][c] = va_h;
            int gcol = colBase + r;
            *(uint4*)&smem[1][r][c] = *(const uint4*)(Bth + (size_t)gcol * 128 + kk + c);
            *(uint4*)&smem[2][r][c] = *(const uint4*)(Btl + (size_t)gcol * 128 + kk + c);
        }
        __syncthreads();

        bf16x8 ah[4], bh[4], bl[4];
#pragma unroll
        for (int m = 0; m < 4; ++m)
            ah[m] = *(const bf16x8*)&smem[0][wr + m * 16 + fr][g * 8];
#pragma unroll
        for (int n = 0; n < 4; ++n) {
            bh[n] = *(const bf16x8*)&smem[1][wc + n * 16 + fr][g * 8];
            bl[n] = *(const bf16x8*)&smem[2][wc + n * 16 + fr][g * 8];
        }
#pragma unroll
        for (int m = 0; m < 4; ++m)
#pragma unroll
            for (int n = 0; n < 4; ++n) {
                acc[m][n] = __builtin_amdgcn_mfma_f32_16x16x32_bf16(ah[m], bh[n], acc[m][n], 0, 0, 0);
                acc[m][n] = __builtin_amdgcn_mfma_f32_16x16x32_bf16(ah[m], bl[n], acc[m][n], 0, 0, 0);
            }
        __syncthreads();
    }

    // bias + BN + ReLU
    {
        float bi[4], ga[4], bb[4], mu[4], iv[4];
#pragma unroll
        for (int n = 0; n < 4; ++n) {
            int c = colBase + wc + n * 16 + fr;
            bi[n] = bias[c]; ga[n] = gamma[c]; bb[n] = beta[c];
            mu[n] = rm[c];   iv[n] = rsqrtf(rv[c] + EPSBN);
        }
#pragma unroll
        for (int m = 0; m < 4; ++m)
#pragma unroll
            for (int n = 0; n < 4; ++n)
#pragma unroll
                for (int j = 0; j < 4; ++j) {
                    float v = acc[m][n][j] + bi[n];
                    v = ga[n] * (v - mu[n]) * iv[n] + bb[n];
                    acc[m][n][j] = fmaxf(v, 0.f);
                }
    }

    // transpose epilogue, split bf16 stores
    float* Cs = (float*)&smem[0][0][0];
    const int rl_w = (wr >> 6) * 16;
#pragma unroll
    for (int m = 0; m < 4; ++m) {
        __syncthreads();
#pragma unroll
        for (int n = 0; n < 4; ++n)
#pragma unroll
            for (int j = 0; j < 4; ++j)
                Cs[(rl_w + g * 4 + j) * 132 + wc + n * 16 + fr] = acc[m][n][j];
        __syncthreads();
        int rl = tid >> 3, c16 = (tid & 7) * 16;
        int grow = rowBase + (rl >> 4) * 64 + m * 16 + (rl & 15);
        if (grow < M) {
            unsigned short th[16], tl[16];
#pragma unroll
            for (int i = 0; i < 16; ++i) splitf(Cs[rl * 132 + c16 + i], th[i], tl[i]);
            size_t ob = (size_t)grow * 256 + colBase + c16;
            *(uint4*)(Ch + ob)     = *(uint4*)&th[0];
            *(uint4*)(Ch + ob + 8) = *(uint4*)&th[8];
            *(uint4*)(Cl + ob)     = *(uint4*)&tl[0];
            *(uint4*)(Cl + ob + 8) = *(uint4*)&tl[8];
        }
    }
}

// ---------------- MFMA GEMM + fused attention coefficients (layer 2) --------
__global__ __launch_bounds__(256) void gemm_bf16_split_attn(
    const unsigned short* __restrict__ Ah, const unsigned short* __restrict__ Al,
    const unsigned short* __restrict__ Bth, const unsigned short* __restrict__ Btl,
    unsigned short* __restrict__ Cb,
    const float* __restrict__ aSrc, const float* __restrict__ aDst,
    float* __restrict__ asrcOut, float* __restrict__ adstOut,
    int M, int N, int K, int heads)
{
    __shared__ unsigned short smem[4][128][32];
    const int tid = threadIdx.x;
    const int lane = tid & 63;
    const int wave = tid >> 6;
    const int fr = lane & 15, g = lane >> 4;
    const int wr = (wave >> 1) * 64, wc = (wave & 1) * 64;
    const int rowBase = blockIdx.x * 128, colBase = blockIdx.y * 128;

    f32x4 acc[4][4] = {};

    for (int kk = 0; kk < K; kk += 32) {
#pragma unroll
        for (int i = 0; i < 2; ++i) {
            int idx = tid + 256 * i;
            int r = idx >> 2, c = (idx & 3) * 8;
            int grow = rowBase + r;
            uint4 va_h, va_l;
            if (grow < M) {
                va_h = *(const uint4*)(Ah + (size_t)grow * K + kk + c);
                va_l = *(const uint4*)(Al + (size_t)grow * K + kk + c);
            } else {
                va_h = make_uint4(0, 0, 0, 0); va_l = make_uint4(0, 0, 0, 0);
            }
            *(uint4*)&smem[0][r][c] = va_h;
            *(uint4*)&smem[1][r][c] = va_l;
            int gcol = colBase + r;
            *(uint4*)&smem[2][r][c] = *(const uint4*)(Bth + (size_t)gcol * K + kk + c);
            *(uint4*)&smem[3][r][c] = *(const uint4*)(Btl + (size_t)gcol * K + kk + c);
        }
        __syncthreads();

        bf16x8 ah[4], al[4], bh[4], bl[4];
#pragma unroll
        for (int m = 0; m < 4; ++m) {
            ah[m] = *(const bf16x8*)&smem[0][wr + m * 16 + fr][g * 8];
            al[m] = *(const bf16x8*)&smem[1][wr + m * 16 + fr][g * 8];
        }
#pragma unroll
        for (int n = 0; n < 4; ++n) {
            bh[n] = *(const bf16x8*)&smem[2][wc + n * 16 + fr][g * 8];
            bl[n] = *(const bf16x8*)&smem[3][wc + n * 16 + fr][g * 8];
        }
#pragma unroll
        for (int m = 0; m < 4; ++m)
#pragma unroll
            for (int n = 0; n < 4; ++n) {
                acc[m][n] = __builtin_amdgcn_mfma_f32_16x16x32_bf16(ah[m], bh[n], acc[m][n], 0, 0, 0);
                acc[m][n] = __builtin_amdgcn_mfma_f32_16x16x32_bf16(ah[m], bl[n], acc[m][n], 0, 0, 0);
                acc[m][n] = __builtin_amdgcn_mfma_f32_16x16x32_bf16(al[m], bh[n], acc[m][n], 0, 0, 0);
            }
        __syncthreads();
    }

    // fused attention coefficient partials
    {
        const int head = colBase >> 7;
        float avs[4], avd[4];
#pragma unroll
        for (int n = 0; n < 4; ++n) {
            int col = colBase + wc + n * 16 + fr;
            avs[n] = aSrc[col]; avd[n] = aDst[col];
        }
#pragma unroll
        for (int m = 0; m < 4; ++m) {
            float ps[4], pd[4];
#pragma unroll
            for (int j = 0; j < 4; ++j) {
                ps[j] = acc[m][0][j] * avs[0] + acc[m][1][j] * avs[1]
                      + acc[m][2][j] * avs[2] + acc[m][3][j] * avs[3];
                pd[j] = acc[m][0][j] * avd[0] + acc[m][1][j] * avd[1]
                      + acc[m][2][j] * avd[2] + acc[m][3][j] * avd[3];
            }
#pragma unroll
            for (int off = 8; off; off >>= 1)
#pragma unroll
                for (int j = 0; j < 4; ++j) {
                    ps[j] += __shfl_xor(ps[j], off);
                    pd[j] += __shfl_xor(pd[j], off);
                }
            if (fr == 0) {
#pragma unroll
                for (int j = 0; j < 4; ++j) {
                    int grow = rowBase + wr + m * 16 + g * 4 + j;
                    if (grow < M) {
                        atomicAdd(asrcOut + (size_t)grow * heads + head, ps[j]);
                        atomicAdd(adstOut + (size_t)grow * heads + head, pd[j]);
                    }
                }
            }
        }
    }

    // transpose epilogue, single bf16 plane
    float* Cs = (float*)&smem[0][0][0];
    const int rl_w = (wr >> 6) * 16;
#pragma unroll
    for (int m = 0; m < 4; ++m) {
        __syncthreads();
#pragma unroll
        for (int n = 0; n < 4; ++n)
#pragma unroll
            for (int j = 0; j < 4; ++j)
                Cs[(rl_w + g * 4 + j) * 132 + wc + n * 16 + fr] = acc[m][n][j];
        __syncthreads();
        int rl = tid >> 3, c16 = (tid & 7) * 16;
        int grow = rowBase + (rl >> 4) * 64 + m * 16 + (rl & 15);
        if (grow < M) {
            unsigned short tmp[16];
#pragma unroll
            for (int i = 0; i < 16; ++i) tmp[i] = f2bf(Cs[rl * 132 + c16 + i]);
            *(uint4*)(Cb + (size_t)grow * N + colBase + c16)     = *(uint4*)&tmp[0];
            *(uint4*)(Cb + (size_t)grow * N + colBase + c16 + 8) = *(uint4*)&tmp[8];
        }
    }
}

// ---------------- SpMM layer 2 (all 128 ch) + fused softmax ------------------
__global__ __launch_bounds__(256) void spmm2(
    const unsigned short* __restrict__ h2b, const float* __restrict__ asrc,
    const float* __restrict__ adst, const int* __restrict__ offs,
    const int* __restrict__ esrc,
    const float* __restrict__ b2, const float* __restrict__ gamma,
    const float* __restrict__ beta, const float* __restrict__ rm,
    const float* __restrict__ rv, float* __restrict__ x3, int Nn)
{
    int d = (int)((blockIdx.x * blockDim.x + threadIdx.x) >> 6);
    int lane = threadIdx.x & 63;
    if (d >= Nn) return;
    int beg = offs[d], end = offs[d + 1];
    int deg = end - beg;
    float ad = adst[d];
    const int sub = lane >> 4;
    const int cgrp = lane & 15;
    const char* hb_c = (const char*)h2b + cgrp * 16;
    float acc[8] = {};

    if (deg <= 64) {
        int sj = 0; float ev = -1e30f;
        if (lane < deg) {
            sj = esrc[beg + lane];
            float e = asrc[sj] + ad; ev = e > 0.f ? e : NEG_SLOPE * e;
        }
        float m = ev;
        for (int off = 32; off; off >>= 1) m = fmaxf(m, __shfl_xor(m, off));
        float p = (lane < deg) ? expf(ev - m) : 0.f;
        float s = p;
        for (int off = 32; off; off >>= 1) s += __shfl_xor(s, off);
        float w = p * (1.f / s);
        gather1h(sj, w, deg, sub, hb_c, acc);
    } else {
        float m = -1e30f;
        for (int j = beg + lane; j < end; j += 64) {
            int s = esrc[j];
            float e = asrc[s] + ad; e = e > 0.f ? e : NEG_SLOPE * e;
            m = fmaxf(m, e);
        }
        for (int off = 32; off; off >>= 1) m = fmaxf(m, __shfl_xor(m, off));
        float sd = 0.f;
        for (int j = beg + lane; j < end; j += 64) {
            int s = esrc[j];
            float e = asrc[s] + ad; e = e > 0.f ? e : NEG_SLOPE * e;
            sd += expf(e - m);
        }
        for (int off = 32; off; off >>= 1) sd += __shfl_xor(sd, off);
        float rd = 1.f / sd;
        for (int base = beg; base < end; base += 64) {
            int nc = end - base; if (nc > 64) nc = 64;
            int sj = 0; float wj = 0.f;
            if (lane < nc) {
                sj = esrc[base + lane];
                float e = asrc[sj] + ad; e = e > 0.f ? e : NEG_SLOPE * e;
                wj = expf(e - m) * rd;
            }
            gather1h(sj, wj, nc, sub, hb_c, acc);
        }
    }
#pragma unroll
    for (int i = 0; i < 8; ++i) {
        acc[i] += __shfl_xor(acc[i], 32);
        acc[i] += __shfl_xor(acc[i], 16);
    }
    if (lane < 16) {
        int cl = cgrp * 8;
        float vv[8];
#pragma unroll
        for (int i = 0; i < 8; ++i) {
            int c = cl + i;
            float v = acc[i] + b2[c];
            v = gamma[c] * (v - rm[c]) * rsqrtf(rv[c] + EPSBN) + beta[c];
            vv[i] = fmaxf(v, 0.f);
        }
        *(float4*)(x3 + (size_t)d * 128 + cl)     = make_float4(vv[0], vv[1], vv[2], vv[3]);
        *(float4*)(x3 + (size_t)d * 128 + cl + 4) = make_float4(vv[4], vv[5], vv[6], vv[7]);
    }
}

// ---------------- global max pool: one block per graph, no atomics ----------
__global__ __launch_bounds__(128) void pool_max_graph(
    const float* __restrict__ x3, const int* __restrict__ bat,
    float* __restrict__ out, int Nn)
{
    int g = blockIdx.x;
    int c = threadIdx.x;
    int lo = 0, hi = Nn;
    while (lo < hi) { int mid = (lo + hi) >> 1; if (bat[mid] < g) lo = mid + 1; else hi = mid; }
    int beg = lo;
    hi = Nn;
    while (lo < hi) { int mid = (lo + hi) >> 1; if (bat[mid] < g + 1) lo = mid + 1; else hi = mid; }
    int end = lo;
    float acc = -1e30f;
    for (int n = beg; n < end; ++n)
        acc = fmaxf(acc, x3[(size_t)n * 128 + c]);
    out[(size_t)g * 128 + c] = acc;
}

// ---------------------------------------------------------------------------
extern "C" void kernel_launch(void* const* d_in, const int* in_sizes, int n_in,
                              void* d_out, int out_size, void* d_ws, size_t ws_size,
                              hipStream_t stream)
{
    const float* x   = (const float*)d_in[0];
    const int*   ei  = (const int*)d_in[1];
    const int*   bat = (const int*)d_in[2];
    const float* W1  = (const float*)d_in[3];
    const float* as1 = (const float*)d_in[4];
    const float* ad1 = (const float*)d_in[5];
    const float* b1  = (const float*)d_in[6];
    const float* g1  = (const float*)d_in[7];
    const float* be1 = (const float*)d_in[8];
    const float* rm1 = (const float*)d_in[9];
    const float* rv1 = (const float*)d_in[10];
    const float* W2  = (const float*)d_in[11];
    const float* as2 = (const float*)d_in[12];
    const float* ad2 = (const float*)d_in[13];
    const float* b2  = (const float*)d_in[14];
    const float* g2  = (const float*)d_in[15];
    const float* be2 = (const float*)d_in[16];
    const float* rm2 = (const float*)d_in[17];
    const float* rv2 = (const float*)d_in[18];
    float* out = (float*)d_out;

    const int Nn = in_sizes[0] / 128;
    const int E  = in_sizes[1] / 2;
    const int E2 = E + Nn;
    const int B  = out_size / 128;

    char* p = (char*)d_ws;
    size_t off = 0;
    auto alloc = [&](size_t bytes) -> void* {
        void* r = p + off;
        off = (off + bytes + 255) & ~(size_t)255;
        return r;
    };
    unsigned short* xh    = (unsigned short*)alloc((size_t)Nn * 128 * 2);
    unsigned short* w1th  = (unsigned short*)alloc(256 * 128 * 2);
    unsigned short* w1tl  = (unsigned short*)alloc(256 * 128 * 2);
    unsigned short* w2th  = (unsigned short*)alloc(128 * 256 * 2);
    unsigned short* w2tl  = (unsigned short*)alloc(128 * 256 * 2);
    unsigned short* xth   = (unsigned short*)alloc((size_t)Nn * 256 * 2);
    unsigned short* x2h   = (unsigned short*)alloc((size_t)Nn * 256 * 2);
    unsigned short* x2l   = (unsigned short*)alloc((size_t)Nn * 256 * 2);
    float*          vsd   = (float*)alloc(4 * 128 * 4);
    float*          asrc1 = (float*)alloc((size_t)Nn * 2 * 4);
    float*          adst1 = (float*)alloc((size_t)Nn * 2 * 4);
    float*          attnv = (float*)alloc((size_t)Nn * 2 * 4);   // asrc2, adst2
    float*          asrc2 = attnv;
    float*          adst2 = attnv + Nn;
    int*            counts= (int*)alloc((size_t)Nn * 4);
    int*            erank = (int*)alloc((size_t)E2 * 4);
    int*            offs  = (int*)alloc((size_t)(Nn + 1) * 4);
    int*            bsum  = (int*)alloc(256 * 4);
    int*            boff  = (int*)alloc(256 * 4);
    int*            esrc  = (int*)alloc((size_t)E2 * 4);
    // aliases (round-7 proven): xth dead after gemm_bn_split -> x3;
    // xh dead after spmm_x -> h2b target for layer-2 GEMM
    float*          x3    = (float*)xth;
    unsigned short* h2b   = xh;

    const int nb = (Nn + 255) / 256;
    const int nwB = (Nn + 3) / 4;
    const int gmB = (Nn + 127) / 128;

    hipMemsetAsync(counts, 0, (size_t)Nn * 4, stream);
    hipMemsetAsync(attnv, 0, (size_t)Nn * 2 * 4, stream);

    // ---- precompute + splits + layer-1 attn coefs
    precompute_v<<<1, 128, 0, stream>>>(W1, as1, ad1, vsd);
    split_x_attn<<<nwB, 256, 0, stream>>>(x, vsd, xh, asrc1, adst1, Nn);
    split_w_both<<<(65536 + 255) / 256, 256, 0, stream>>>(W1, W2, w1th, w1tl, w2th, w2tl);

    // ---- CSR build
    count_edges<<<(E2 + 255) / 256, 256, 0, stream>>>(ei, E, Nn, counts, erank);
    scan_block<<<nb, 256, 0, stream>>>(counts, offs, bsum, Nn);
    scan_tops<<<1, 256, 0, stream>>>(bsum, boff, nb);
    add_offsets<<<(Nn + 255) / 256, 256, 0, stream>>>(offs, boff, Nn, E2);
    fill_edges<<<(E2 + 255) / 256, 256, 0, stream>>>(ei, E, Nn, offs, erank, esrc);

    // ---- layer 1: aggregate x (dual-head) then project + BN + ReLU
    spmm_x<<<nwB, 256, 0, stream>>>(xh, asrc1, adst1, offs, esrc, xth, Nn);
    gemm_bn_split<<<dim3(gmB, 2), 256, 0, stream>>>(
        xth, w1th, w1tl, b1, g1, be1, rm1, rv1, x2h, x2l, Nn);

    // ---- layer 2: GEMM (+attn coef) then SpMM
    gemm_bf16_split_attn<<<dim3(gmB, 1), 256, 0, stream>>>(
        x2h, x2l, w2th, w2tl, h2b, as2, ad2, asrc2, adst2, Nn, 128, 256, 1);
    spmm2<<<nwB, 256, 0, stream>>>(h2b, asrc2, adst2, offs, esrc,
                                   b2, g2, be2, rm2, rv2, x3, Nn);

    // ---- global max pool
    pool_max_graph<<<B, 128, 0, stream>>>(x3, bat, out, Nn);
}

// Round 10
// 249.644 us; speedup vs baseline: 1.1269x; 1.0703x over previous
//
#include <hip/hip_runtime.h>
#include <hip/hip_bf16.h>
#include <math.h>

#define NEG_SLOPE 0.2f
#define EPSBN 1e-5f

typedef __attribute__((ext_vector_type(8))) short bf16x8;
typedef __attribute__((ext_vector_type(4))) float f32x4;

__device__ __forceinline__ float bfu2f(unsigned u_lo16) { return __uint_as_float(u_lo16 << 16); }
__device__ __forceinline__ unsigned short f2bf(float f) {
    return __bfloat16_as_ushort(__float2bfloat16(f));
}
__device__ __forceinline__ void splitf(float v, unsigned short &h, unsigned short &l) {
    __hip_bfloat16 hb = __float2bfloat16(v);
    float r = v - __bfloat162float(hb);
    h = __bfloat16_as_ushort(hb);
    l = __bfloat16_as_ushort(__float2bfloat16(r));
}

// ---------------- precompute v = W1 @ a vectors (1 block, runs first) --------
__global__ void precompute_v(const float* __restrict__ W1, const float* __restrict__ as1,
                             const float* __restrict__ ad1, float* __restrict__ vsd)
{
    int k = threadIdx.x;
    if (k >= 128) return;
    float v0 = 0.f, v1 = 0.f, v2 = 0.f, v3 = 0.f;
    const float* wr = W1 + (size_t)k * 256;
    for (int c = 0; c < 128; ++c) {
        float wa = wr[c], wb = wr[128 + c];
        v0 += wa * as1[c];  v1 += wb * as1[128 + c];
        v2 += wa * ad1[c];  v3 += wb * ad1[128 + c];
    }
    vsd[k] = v0; vsd[128 + k] = v1; vsd[256 + k] = v2; vsd[384 + k] = v3;
}

// ---------------- mega-prep: split_x+attn | count_edges | split_w ------------
// independent block ranges, no inter-block deps (vsd produced by prior launch)
__global__ __launch_bounds__(256) void prep(
    const float* __restrict__ X, const float* __restrict__ vsd,
    const float* __restrict__ W1, const float* __restrict__ W2,
    const int* __restrict__ ei,
    unsigned short* __restrict__ Xh, float* __restrict__ asrc, float* __restrict__ adst,
    unsigned short* __restrict__ w1th, unsigned short* __restrict__ w1tl,
    unsigned short* __restrict__ w2th, unsigned short* __restrict__ w2tl,
    int* __restrict__ counts, int* __restrict__ erank,
    int Nn, int E, int nwB, int countB)
{
    const int b = blockIdx.x;
    const int tid = threadIdx.x;
    if (b < nwB) {
        // ---- split x -> bf16 plane + layer-1 attn coefficients
        int n = (int)((b * 256 + tid) >> 6);
        int lane = tid & 63;
        if (n >= Nn) return;
        float2 xv = *(const float2*)(X + (size_t)n * 128 + lane * 2);
        unsigned short hh[2] = {f2bf(xv.x), f2bf(xv.y)};
        *(unsigned*)(Xh + (size_t)n * 128 + lane * 2) = *(unsigned*)hh;
        int k = lane * 2;
        float p0 = xv.x * vsd[k]       + xv.y * vsd[k + 1];
        float p1 = xv.x * vsd[128 + k] + xv.y * vsd[129 + k];
        float p2 = xv.x * vsd[256 + k] + xv.y * vsd[257 + k];
        float p3 = xv.x * vsd[384 + k] + xv.y * vsd[385 + k];
        for (int off = 32; off; off >>= 1) {
            p0 += __shfl_xor(p0, off); p1 += __shfl_xor(p1, off);
            p2 += __shfl_xor(p2, off); p3 += __shfl_xor(p3, off);
        }
        if (lane == 0) {
            asrc[n * 2] = p0; asrc[n * 2 + 1] = p1;
            adst[n * 2] = p2; adst[n * 2 + 1] = p3;
        }
    } else if (b < nwB + countB) {
        // ---- count_edges
        int e = (b - nwB) * 256 + tid;
        int E2 = E + Nn;
        if (e >= E2) return;
        int dst = (e < E) ? ei[E + e] : (e - E);
        erank[e] = atomicAdd(&counts[dst], 1);
    } else {
        // ---- split weights -> transposed split planes
        int idx = (b - nwB - countB) * 256 + tid;
        if (idx < 32768) {                      // W1 [128,256] -> [256,128]
            int nn = idx >> 7, k = idx & 127;
            unsigned short h, l; splitf(W1[(size_t)k * 256 + nn], h, l);
            w1th[idx] = h; w1tl[idx] = l;
        } else if (idx < 65536) {               // W2 [256,128] -> [128,256]
            int j = idx - 32768;
            int nn = j >> 8, k = j & 255;
            unsigned short h, l; splitf(W2[(size_t)k * 128 + nn], h, l);
            w2th[j] = h; w2tl[j] = l;
        }
    }
}

// ---------------- CSR scan + fill -------------------------------------------
__global__ __launch_bounds__(256) void scan_block(
    const int* __restrict__ counts, int* __restrict__ offs, int* __restrict__ bsum, int Nn)
{
    __shared__ int s[256];
    int i = blockIdx.x * 256 + threadIdx.x;
    int v = (i < Nn) ? counts[i] : 0;
    s[threadIdx.x] = v;
    __syncthreads();
    for (int off = 1; off < 256; off <<= 1) {
        int t = (threadIdx.x >= off) ? s[threadIdx.x - off] : 0;
        __syncthreads();
        s[threadIdx.x] += t;
        __syncthreads();
    }
    if (i < Nn) offs[i] = s[threadIdx.x] - v;
    if (threadIdx.x == 255) bsum[blockIdx.x] = s[255];
}

__global__ __launch_bounds__(256) void scan_tops(int* __restrict__ bsum, int* __restrict__ boff, int nb)
{
    __shared__ int s[256];
    int v = (threadIdx.x < nb) ? bsum[threadIdx.x] : 0;
    s[threadIdx.x] = v;
    __syncthreads();
    for (int off = 1; off < 256; off <<= 1) {
        int t = (threadIdx.x >= off) ? s[threadIdx.x - off] : 0;
        __syncthreads();
        s[threadIdx.x] += t;
        __syncthreads();
    }
    if (threadIdx.x < nb) boff[threadIdx.x] = s[threadIdx.x] - v;
}

__global__ void add_offsets(int* __restrict__ offs, const int* __restrict__ boff, int Nn, int E2)
{
    int i = blockIdx.x * blockDim.x + threadIdx.x;
    if (i < Nn) offs[i] += boff[i >> 8];
    if (i == 0) offs[Nn] = E2;
}

__global__ void fill_edges(const int* __restrict__ ei, int E, int Nn,
                           const int* __restrict__ offs, const int* __restrict__ erank,
                           int* __restrict__ esrc)
{
    int e = blockIdx.x * blockDim.x + threadIdx.x;
    int E2 = E + Nn;
    if (e >= E2) return;
    int src, dst;
    if (e < E) { src = ei[e]; dst = ei[E + e]; }
    else       { src = e - E; dst = e - E; }
    esrc[offs[dst] + erank[e]] = src;
}

// ---------------- unpack-FMA helpers ----------------------------------------
__device__ __forceinline__ void fma8(float wA, uint4 hv, float acc[8])
{
    acc[0] = fmaf(wA, bfu2f(hv.x & 0xffff), acc[0]);
    acc[1] = fmaf(wA, __uint_as_float(hv.x & 0xffff0000u), acc[1]);
    acc[2] = fmaf(wA, bfu2f(hv.y & 0xffff), acc[2]);
    acc[3] = fmaf(wA, __uint_as_float(hv.y & 0xffff0000u), acc[3]);
    acc[4] = fmaf(wA, bfu2f(hv.z & 0xffff), acc[4]);
    acc[5] = fmaf(wA, __uint_as_float(hv.z & 0xffff0000u), acc[5]);
    acc[6] = fmaf(wA, bfu2f(hv.w & 0xffff), acc[6]);
    acc[7] = fmaf(wA, __uint_as_float(hv.w & 0xffff0000u), acc[7]);
}

__device__ __forceinline__ void fma8x2(float wa, float wb, uint4 hv,
                                       float a0[8], float a1[8])
{
    float f;
    f = bfu2f(hv.x & 0xffff);                 a0[0]=fmaf(wa,f,a0[0]); a1[0]=fmaf(wb,f,a1[0]);
    f = __uint_as_float(hv.x & 0xffff0000u);  a0[1]=fmaf(wa,f,a0[1]); a1[1]=fmaf(wb,f,a1[1]);
    f = bfu2f(hv.y & 0xffff);                 a0[2]=fmaf(wa,f,a0[2]); a1[2]=fmaf(wb,f,a1[2]);
    f = __uint_as_float(hv.y & 0xffff0000u);  a0[3]=fmaf(wa,f,a0[3]); a1[3]=fmaf(wb,f,a1[3]);
    f = bfu2f(hv.z & 0xffff);                 a0[4]=fmaf(wa,f,a0[4]); a1[4]=fmaf(wb,f,a1[4]);
    f = __uint_as_float(hv.z & 0xffff0000u);  a0[5]=fmaf(wa,f,a0[5]); a1[5]=fmaf(wb,f,a1[5]);
    f = bfu2f(hv.w & 0xffff);                 a0[6]=fmaf(wa,f,a0[6]); a1[6]=fmaf(wb,f,a1[6]);
    f = __uint_as_float(hv.w & 0xffff0000u);  a0[7]=fmaf(wa,f,a0[7]); a1[7]=fmaf(wb,f,a1[7]);
}

// 1-head gather: 16 lanes/edge, 4 subslots, row 256 B
__device__ __forceinline__ void gather1h(
    int sj, float w, int nc, int sub,
    const char* __restrict__ hb_c, float acc[8])
{
    for (int t = 0; t < nc; t += 4) {
        int e = t + sub;
        int sA = __shfl(sj, e);
        float wA = __shfl(w, e);
        uint4 hv = *(const uint4*)(hb_c + sA * 256);
        fma8(wA, hv, acc);
    }
}

// dual-head x-gather: 16 lanes/edge, 4 subslots, row 256 B
__device__ __forceinline__ void gatherx(
    int sj, float w0, float w1, int nc, int sub,
    const char* __restrict__ hb_c, float a0[8], float a1[8])
{
    for (int t = 0; t < nc; t += 4) {
        int e = t + sub;
        int sA = __shfl(sj, e);
        float wa = __shfl(w0, e);
        float wb = __shfl(w1, e);
        uint4 hv = *(const uint4*)(hb_c + sA * 256);
        fma8x2(wa, wb, hv, a0, a1);
    }
}

// ---------------- SpMM on input features x (layer 1), dual-head -------------
__global__ __launch_bounds__(256) void spmm_x(
    const unsigned short* __restrict__ xh, const float* __restrict__ asrc,
    const float* __restrict__ adst, const int* __restrict__ offs,
    const int* __restrict__ esrc,
    unsigned short* __restrict__ xth, int Nn)
{
    int d = (int)((blockIdx.x * blockDim.x + threadIdx.x) >> 6);
    int lane = threadIdx.x & 63;
    if (d >= Nn) return;
    int beg = offs[d], end = offs[d + 1];
    int deg = end - beg;
    float ad0 = adst[d * 2], ad1 = adst[d * 2 + 1];
    const int sub = lane >> 4;
    const int cgrp = lane & 15;
    const char* hb_c = (const char*)xh + cgrp * 16;
    float a0[8] = {}, a1[8] = {};

    if (deg <= 64) {
        int sj = 0; float e0 = -1e30f, e1 = -1e30f;
        if (lane < deg) {
            sj = esrc[beg + lane];
            float2 av = *(const float2*)(asrc + (size_t)sj * 2);
            e0 = av.x + ad0; e0 = e0 > 0.f ? e0 : NEG_SLOPE * e0;
            e1 = av.y + ad1; e1 = e1 > 0.f ? e1 : NEG_SLOPE * e1;
        }
        float m0 = e0, m1 = e1;
        for (int off = 32; off; off >>= 1) {
            m0 = fmaxf(m0, __shfl_xor(m0, off));
            m1 = fmaxf(m1, __shfl_xor(m1, off));
        }
        float p0 = (lane < deg) ? expf(e0 - m0) : 0.f;
        float p1 = (lane < deg) ? expf(e1 - m1) : 0.f;
        float s0 = p0, s1 = p1;
        for (int off = 32; off; off >>= 1) {
            s0 += __shfl_xor(s0, off);
            s1 += __shfl_xor(s1, off);
        }
        float w0 = p0 * (1.f / s0), w1 = p1 * (1.f / s1);
        gatherx(sj, w0, w1, deg, sub, hb_c, a0, a1);
    } else {
        float m0 = -1e30f, m1 = -1e30f;
        for (int j = beg + lane; j < end; j += 64) {
            int s = esrc[j];
            float2 av = *(const float2*)(asrc + (size_t)s * 2);
            float e0 = av.x + ad0; e0 = e0 > 0.f ? e0 : NEG_SLOPE * e0;
            float e1 = av.y + ad1; e1 = e1 > 0.f ? e1 : NEG_SLOPE * e1;
            m0 = fmaxf(m0, e0); m1 = fmaxf(m1, e1);
        }
        for (int off = 32; off; off >>= 1) {
            m0 = fmaxf(m0, __shfl_xor(m0, off));
            m1 = fmaxf(m1, __shfl_xor(m1, off));
        }
        float s0 = 0.f, s1 = 0.f;
        for (int j = beg + lane; j < end; j += 64) {
            int s = esrc[j];
            float2 av = *(const float2*)(asrc + (size_t)s * 2);
            float e0 = av.x + ad0; e0 = e0 > 0.f ? e0 : NEG_SLOPE * e0;
            float e1 = av.y + ad1; e1 = e1 > 0.f ? e1 : NEG_SLOPE * e1;
            s0 += expf(e0 - m0); s1 += expf(e1 - m1);
        }
        for (int off = 32; off; off >>= 1) {
            s0 += __shfl_xor(s0, off);
            s1 += __shfl_xor(s1, off);
        }
        float rd0 = 1.f / s0, rd1 = 1.f / s1;
        for (int base = beg; base < end; base += 64) {
            int nc = end - base; if (nc > 64) nc = 64;
            int sj = 0; float w0 = 0.f, w1 = 0.f;
            if (lane < nc) {
                sj = esrc[base + lane];
                float2 av = *(const float2*)(asrc + (size_t)sj * 2);
                float e0 = av.x + ad0; e0 = e0 > 0.f ? e0 : NEG_SLOPE * e0;
                float e1 = av.y + ad1; e1 = e1 > 0.f ? e1 : NEG_SLOPE * e1;
                w0 = expf(e0 - m0) * rd0;
                w1 = expf(e1 - m1) * rd1;
            }
            gatherx(sj, w0, w1, nc, sub, hb_c, a0, a1);
        }
    }
#pragma unroll
    for (int i = 0; i < 8; ++i) {
        a0[i] += __shfl_xor(a0[i], 32); a0[i] += __shfl_xor(a0[i], 16);
        a1[i] += __shfl_xor(a1[i], 32); a1[i] += __shfl_xor(a1[i], 16);
    }
    if (lane < 16) {
        int cl = cgrp * 8;
        unsigned short h0[8], h1[8];
#pragma unroll
        for (int i = 0; i < 8; ++i) { h0[i] = f2bf(a0[i]); h1[i] = f2bf(a1[i]); }
        size_t rb = (size_t)d * 256;
        *(uint4*)(xth + rb + cl)       = *(uint4*)&h0[0];
        *(uint4*)(xth + rb + 128 + cl) = *(uint4*)&h1[0];
    }
}

// ---------------- GEMM1b: x~ @ W1 (block-diag per head) + BN + bf16 out -----
__global__ __launch_bounds__(256) void gemm_bn_split(
    const unsigned short* __restrict__ Ah,
    const unsigned short* __restrict__ Bth, const unsigned short* __restrict__ Btl,
    const float* __restrict__ bias, const float* __restrict__ gamma,
    const float* __restrict__ beta, const float* __restrict__ rm,
    const float* __restrict__ rv,
    unsigned short* __restrict__ Ch, int M)
{
    __shared__ unsigned short smem[3][128][32];
    const int tid = threadIdx.x;
    const int lane = tid & 63;
    const int wave = tid >> 6;
    const int fr = lane & 15, g = lane >> 4;
    const int wr = (wave >> 1) * 64, wc = (wave & 1) * 64;
    const int rowBase = blockIdx.x * 128, colBase = blockIdx.y * 128;

    f32x4 acc[4][4] = {};

    for (int kk = 0; kk < 128; kk += 32) {
#pragma unroll
        for (int i = 0; i < 2; ++i) {
            int idx = tid + 256 * i;
            int r = idx >> 2, c = (idx & 3) * 8;
            int grow = rowBase + r;
            uint4 va_h = make_uint4(0, 0, 0, 0);
            if (grow < M) va_h = *(const uint4*)(Ah + (size_t)grow * 256 + colBase + kk + c);
            *(uint4*)&smem[0][r][c] = va_h;
            int gcol = colBase + r;
            *(uint4*)&smem[1][r][c] = *(const uint4*)(Bth + (size_t)gcol * 128 + kk + c);
            *(uint4*)&smem[2][r][c] = *(const uint4*)(Btl + (size_t)gcol * 128 + kk + c);
        }
        __syncthreads();

        bf16x8 ah[4], bh[4], bl[4];
#pragma unroll
        for (int m = 0; m < 4; ++m)
            ah[m] = *(const bf16x8*)&smem[0][wr + m * 16 + fr][g * 8];
#pragma unroll
        for (int n = 0; n < 4; ++n) {
            bh[n] = *(const bf16x8*)&smem[1][wc + n * 16 + fr][g * 8];
            bl[n] = *(const bf16x8*)&smem[2][wc + n * 16 + fr][g * 8];
        }
#pragma unroll
        for (int m = 0; m < 4; ++m)
#pragma unroll
            for (int n = 0; n < 4; ++n) {
                acc[m][n] = __builtin_amdgcn_mfma_f32_16x16x32_bf16(ah[m], bh[n], acc[m][n], 0, 0, 0);
                acc[m][n] = __builtin_amdgcn_mfma_f32_16x16x32_bf16(ah[m], bl[n], acc[m][n], 0, 0, 0);
            }
        __syncthreads();
    }

    // bias + BN + ReLU
    {
        float bi[4], ga[4], bb[4], mu[4], iv[4];
#pragma unroll
        for (int n = 0; n < 4; ++n) {
            int c = colBase + wc + n * 16 + fr;
            bi[n] = bias[c]; ga[n] = gamma[c]; bb[n] = beta[c];
            mu[n] = rm[c];   iv[n] = rsqrtf(rv[c] + EPSBN);
        }
#pragma unroll
        for (int m = 0; m < 4; ++m)
#pragma unroll
            for (int n = 0; n < 4; ++n)
#pragma unroll
                for (int j = 0; j < 4; ++j) {
                    float v = acc[m][n][j] + bi[n];
                    v = ga[n] * (v - mu[n]) * iv[n] + bb[n];
                    acc[m][n][j] = fmaxf(v, 0.f);
                }
    }

    // transpose epilogue, bf16 stores
    float* Cs = (float*)&smem[0][0][0];
    const int rl_w = (wr >> 6) * 16;
#pragma unroll
    for (int m = 0; m < 4; ++m) {
        __syncthreads();
#pragma unroll
        for (int n = 0; n < 4; ++n)
#pragma unroll
            for (int j = 0; j < 4; ++j)
                Cs[(rl_w + g * 4 + j) * 132 + wc + n * 16 + fr] = acc[m][n][j];
        __syncthreads();
        int rl = tid >> 3, c16 = (tid & 7) * 16;
        int grow = rowBase + (rl >> 4) * 64 + m * 16 + (rl & 15);
        if (grow < M) {
            unsigned short th[16];
#pragma unroll
            for (int i = 0; i < 16; ++i) th[i] = f2bf(Cs[rl * 132 + c16 + i]);
            size_t ob = (size_t)grow * 256 + colBase + c16;
            *(uint4*)(Ch + ob)     = *(uint4*)&th[0];
            *(uint4*)(Ch + ob + 8) = *(uint4*)&th[8];
        }
    }
}

// ---------------- layer-2 GEMM (single A plane) + fused attn coefs ----------
// C[M,128] = A[M,256] @ W2; A = bf16 x2; B = transposed split planes [128][256].
__global__ __launch_bounds__(256) void gemm_bf16_attn(
    const unsigned short* __restrict__ Ah,
    const unsigned short* __restrict__ Bth, const unsigned short* __restrict__ Btl,
    unsigned short* __restrict__ Cb,
    const float* __restrict__ aSrc, const float* __restrict__ aDst,
    float* __restrict__ asrcOut, float* __restrict__ adstOut, int M)
{
    __shared__ unsigned short smem[3][128][32];
    const int tid = threadIdx.x;
    const int lane = tid & 63;
    const int wave = tid >> 6;
    const int fr = lane & 15, g = lane >> 4;
    const int wr = (wave >> 1) * 64, wc = (wave & 1) * 64;
    const int rowBase = blockIdx.x * 128;

    f32x4 acc[4][4] = {};

    for (int kk = 0; kk < 256; kk += 32) {
#pragma unroll
        for (int i = 0; i < 2; ++i) {
            int idx = tid + 256 * i;
            int r = idx >> 2, c = (idx & 3) * 8;
            int grow = rowBase + r;
            uint4 va_h = make_uint4(0, 0, 0, 0);
            if (grow < M) va_h = *(const uint4*)(Ah + (size_t)grow * 256 + kk + c);
            *(uint4*)&smem[0][r][c] = va_h;
            *(uint4*)&smem[1][r][c] = *(const uint4*)(Bth + (size_t)r * 256 + kk + c);
            *(uint4*)&smem[2][r][c] = *(const uint4*)(Btl + (size_t)r * 256 + kk + c);
        }
        __syncthreads();

        bf16x8 ah[4], bh[4], bl[4];
#pragma unroll
        for (int m = 0; m < 4; ++m)
            ah[m] = *(const bf16x8*)&smem[0][wr + m * 16 + fr][g * 8];
#pragma unroll
        for (int n = 0; n < 4; ++n) {
            bh[n] = *(const bf16x8*)&smem[1][wc + n * 16 + fr][g * 8];
            bl[n] = *(const bf16x8*)&smem[2][wc + n * 16 + fr][g * 8];
        }
#pragma unroll
        for (int m = 0; m < 4; ++m)
#pragma unroll
            for (int n = 0; n < 4; ++n) {
                acc[m][n] = __builtin_amdgcn_mfma_f32_16x16x32_bf16(ah[m], bh[n], acc[m][n], 0, 0, 0);
                acc[m][n] = __builtin_amdgcn_mfma_f32_16x16x32_bf16(ah[m], bl[n], acc[m][n], 0, 0, 0);
            }
        __syncthreads();
    }

    // fused attention coefficient partials (heads = 1)
    {
        float avs[4], avd[4];
#pragma unroll
        for (int n = 0; n < 4; ++n) {
            int col = wc + n * 16 + fr;
            avs[n] = aSrc[col]; avd[n] = aDst[col];
        }
#pragma unroll
        for (int m = 0; m < 4; ++m) {
            float ps[4], pd[4];
#pragma unroll
            for (int j = 0; j < 4; ++j) {
                ps[j] = acc[m][0][j] * avs[0] + acc[m][1][j] * avs[1]
                      + acc[m][2][j] * avs[2] + acc[m][3][j] * avs[3];
                pd[j] = acc[m][0][j] * avd[0] + acc[m][1][j] * avd[1]
                      + acc[m][2][j] * avd[2] + acc[m][3][j] * avd[3];
            }
#pragma unroll
            for (int off = 8; off; off >>= 1)
#pragma unroll
                for (int j = 0; j < 4; ++j) {
                    ps[j] += __shfl_xor(ps[j], off);
                    pd[j] += __shfl_xor(pd[j], off);
                }
            if (fr == 0) {
#pragma unroll
                for (int j = 0; j < 4; ++j) {
                    int grow = rowBase + wr + m * 16 + g * 4 + j;
                    if (grow < M) {
                        atomicAdd(asrcOut + grow, ps[j]);
                        atomicAdd(adstOut + grow, pd[j]);
                    }
                }
            }
        }
    }

    // transpose epilogue, bf16 C (N = 128)
    float* Cs = (float*)&smem[0][0][0];
    const int rl_w = (wr >> 6) * 16;
#pragma unroll
    for (int m = 0; m < 4; ++m) {
        __syncthreads();
#pragma unroll
        for (int n = 0; n < 4; ++n)
#pragma unroll
            for (int j = 0; j < 4; ++j)
                Cs[(rl_w + g * 4 + j) * 132 + wc + n * 16 + fr] = acc[m][n][j];
        __syncthreads();
        int rl = tid >> 3, c16 = (tid & 7) * 16;
        int grow = rowBase + (rl >> 4) * 64 + m * 16 + (rl & 15);
        if (grow < M) {
            unsigned short tmp[16];
#pragma unroll
            for (int i = 0; i < 16; ++i) tmp[i] = f2bf(Cs[rl * 132 + c16 + i]);
            *(uint4*)(Cb + (size_t)grow * 128 + c16)     = *(uint4*)&tmp[0];
            *(uint4*)(Cb + (size_t)grow * 128 + c16 + 8) = *(uint4*)&tmp[8];
        }
    }
}

// ---------------- SpMM layer 2 + fused softmax, bf16 x3 out ------------------
__global__ __launch_bounds__(256) void spmm2(
    const unsigned short* __restrict__ h2b, const float* __restrict__ asrc,
    const float* __restrict__ adst, const int* __restrict__ offs,
    const int* __restrict__ esrc,
    const float* __restrict__ b2, const float* __restrict__ gamma,
    const float* __restrict__ beta, const float* __restrict__ rm,
    const float* __restrict__ rv, unsigned short* __restrict__ x3b, int Nn)
{
    int d = (int)((blockIdx.x * blockDim.x + threadIdx.x) >> 6);
    int lane = threadIdx.x & 63;
    if (d >= Nn) return;
    int beg = offs[d], end = offs[d + 1];
    int deg = end - beg;
    float ad = adst[d];
    const int sub = lane >> 4;
    const int cgrp = lane & 15;
    const char* hb_c = (const char*)h2b + cgrp * 16;
    float acc[8] = {};

    if (deg <= 64) {
        int sj = 0; float ev = -1e30f;
        if (lane < deg) {
            sj = esrc[beg + lane];
            float e = asrc[sj] + ad; ev = e > 0.f ? e : NEG_SLOPE * e;
        }
        float m = ev;
        for (int off = 32; off; off >>= 1) m = fmaxf(m, __shfl_xor(m, off));
        float p = (lane < deg) ? expf(ev - m) : 0.f;
        float s = p;
        for (int off = 32; off; off >>= 1) s += __shfl_xor(s, off);
        float w = p * (1.f / s);
        gather1h(sj, w, deg, sub, hb_c, acc);
    } else {
        float m = -1e30f;
        for (int j = beg + lane; j < end; j += 64) {
            int s = esrc[j];
            float e = asrc[s] + ad; e = e > 0.f ? e : NEG_SLOPE * e;
            m = fmaxf(m, e);
        }
        for (int off = 32; off; off >>= 1) m = fmaxf(m, __shfl_xor(m, off));
        float sd = 0.f;
        for (int j = beg + lane; j < end; j += 64) {
            int s = esrc[j];
            float e = asrc[s] + ad; e = e > 0.f ? e : NEG_SLOPE * e;
            sd += expf(e - m);
        }
        for (int off = 32; off; off >>= 1) sd += __shfl_xor(sd, off);
        float rd = 1.f / sd;
        for (int base = beg; base < end; base += 64) {
            int nc = end - base; if (nc > 64) nc = 64;
            int sj = 0; float wj = 0.f;
            if (lane < nc) {
                sj = esrc[base + lane];
                float e = asrc[sj] + ad; e = e > 0.f ? e : NEG_SLOPE * e;
                wj = expf(e - m) * rd;
            }
            gather1h(sj, wj, nc, sub, hb_c, acc);
        }
    }
#pragma unroll
    for (int i = 0; i < 8; ++i) {
        acc[i] += __shfl_xor(acc[i], 32);
        acc[i] += __shfl_xor(acc[i], 16);
    }
    if (lane < 16) {
        int cl = cgrp * 8;
        unsigned short hh[8];
#pragma unroll
        for (int i = 0; i < 8; ++i) {
            int c = cl + i;
            float v = acc[i] + b2[c];
            v = gamma[c] * (v - rm[c]) * rsqrtf(rv[c] + EPSBN) + beta[c];
            hh[i] = f2bf(fmaxf(v, 0.f));
        }
        *(uint4*)(x3b + (size_t)d * 128 + cl) = *(uint4*)&hh[0];
    }
}

// ---------------- global max pool over bf16 x3: one block per graph ---------
__global__ __launch_bounds__(128) void pool_max_graph(
    const unsigned short* __restrict__ x3b, const int* __restrict__ bat,
    float* __restrict__ out, int Nn)
{
    int g = blockIdx.x;
    int c = threadIdx.x;
    int lo = 0, hi = Nn;
    while (lo < hi) { int mid = (lo + hi) >> 1; if (bat[mid] < g) lo = mid + 1; else hi = mid; }
    int beg = lo;
    hi = Nn;
    while (lo < hi) { int mid = (lo + hi) >> 1; if (bat[mid] < g + 1) lo = mid + 1; else hi = mid; }
    int end = lo;
    float acc = -1e30f;
    for (int n = beg; n < end; ++n)
        acc = fmaxf(acc, bfu2f((unsigned)x3b[(size_t)n * 128 + c]));
    out[(size_t)g * 128 + c] = acc;
}

// ---------------------------------------------------------------------------
extern "C" void kernel_launch(void* const* d_in, const int* in_sizes, int n_in,
                              void* d_out, int out_size, void* d_ws, size_t ws_size,
                              hipStream_t stream)
{
    const float* x   = (const float*)d_in[0];
    const int*   ei  = (const int*)d_in[1];
    const int*   bat = (const int*)d_in[2];
    const float* W1  = (const float*)d_in[3];
    const float* as1 = (const float*)d_in[4];
    const float* ad1 = (const float*)d_in[5];
    const float* b1  = (const float*)d_in[6];
    const float* g1  = (const float*)d_in[7];
    const float* be1 = (const float*)d_in[8];
    const float* rm1 = (const float*)d_in[9];
    const float* rv1 = (const float*)d_in[10];
    const float* W2  = (const float*)d_in[11];
    const float* as2 = (const float*)d_in[12];
    const float* ad2 = (const float*)d_in[13];
    const float* b2  = (const float*)d_in[14];
    const float* g2  = (const float*)d_in[15];
    const float* be2 = (const float*)d_in[16];
    const float* rm2 = (const float*)d_in[17];
    const float* rv2 = (const float*)d_in[18];
    float* out = (float*)d_out;

    const int Nn = in_sizes[0] / 128;
    const int E  = in_sizes[1] / 2;
    const int E2 = E + Nn;
    const int B  = out_size / 128;

    char* p = (char*)d_ws;
    size_t off = 0;
    auto alloc = [&](size_t bytes) -> void* {
        void* r = p + off;
        off = (off + bytes + 255) & ~(size_t)255;
        return r;
    };
    unsigned short* xh    = (unsigned short*)alloc((size_t)Nn * 128 * 2);
    unsigned short* w1th  = (unsigned short*)alloc(256 * 128 * 2);
    unsigned short* w1tl  = (unsigned short*)alloc(256 * 128 * 2);
    unsigned short* w2th  = (unsigned short*)alloc(128 * 256 * 2);
    unsigned short* w2tl  = (unsigned short*)alloc(128 * 256 * 2);
    unsigned short* xth   = (unsigned short*)alloc((size_t)Nn * 256 * 2);
    unsigned short* x2h   = (unsigned short*)alloc((size_t)Nn * 256 * 2);
    float*          vsd   = (float*)alloc(4 * 128 * 4);
    float*          asrc1 = (float*)alloc((size_t)Nn * 2 * 4);
    float*          adst1 = (float*)alloc((size_t)Nn * 2 * 4);
    float*          attnv = (float*)alloc((size_t)Nn * 2 * 4);   // asrc2, adst2
    float*          asrc2 = attnv;
    float*          adst2 = attnv + Nn;
    int*            counts= (int*)alloc((size_t)Nn * 4);
    int*            erank = (int*)alloc((size_t)E2 * 4);
    int*            offs  = (int*)alloc((size_t)(Nn + 1) * 4);
    int*            bsum  = (int*)alloc(256 * 4);
    int*            boff  = (int*)alloc(256 * 4);
    int*            esrc  = (int*)alloc((size_t)E2 * 4);
    // aliases (proven pattern): xth dead after gemm_bn_split -> x3b;
    // xh dead after spmm_x -> h2b target for layer-2 GEMM
    unsigned short* x3b   = xth;
    unsigned short* h2b   = xh;

    const int nb = (Nn + 255) / 256;
    const int nwB = (Nn + 3) / 4;
    const int countB = (E2 + 255) / 256;
    const int gmB = (Nn + 127) / 128;

    hipMemsetAsync(counts, 0, (size_t)Nn * 4, stream);
    hipMemsetAsync(attnv, 0, (size_t)Nn * 2 * 4, stream);

    // ---- prep: vsd, then fused {split_x+attn | count_edges | split_w}
    precompute_v<<<1, 128, 0, stream>>>(W1, as1, ad1, vsd);
    prep<<<nwB + countB + 256, 256, 0, stream>>>(
        x, vsd, W1, W2, ei, xh, asrc1, adst1,
        w1th, w1tl, w2th, w2tl, counts, erank, Nn, E, nwB, countB);

    // ---- CSR scan + fill
    scan_block<<<nb, 256, 0, stream>>>(counts, offs, bsum, Nn);
    scan_tops<<<1, 256, 0, stream>>>(bsum, boff, nb);
    add_offsets<<<(Nn + 255) / 256, 256, 0, stream>>>(offs, boff, Nn, E2);
    fill_edges<<<(E2 + 255) / 256, 256, 0, stream>>>(ei, E, Nn, offs, erank, esrc);

    // ---- layer 1: aggregate x (dual-head) then project + BN + ReLU
    spmm_x<<<nwB, 256, 0, stream>>>(xh, asrc1, adst1, offs, esrc, xth, Nn);
    gemm_bn_split<<<dim3(gmB, 2), 256, 0, stream>>>(
        xth, w1th, w1tl, b1, g1, be1, rm1, rv1, x2h, Nn);

    // ---- layer 2: GEMM (+attn coef) then SpMM (bf16 out)
    gemm_bf16_attn<<<gmB, 256, 0, stream>>>(
        x2h, w2th, w2tl, h2b, as2, ad2, asrc2, adst2, Nn);
    spmm2<<<nwB, 256, 0, stream>>>(h2b, asrc2, adst2, offs, esrc,
                                   b2, g2, be2, rm2, rv2, x3b, Nn);

    // ---- global max pool (bf16 in, f32 out)
    pool_max_graph<<<B, 128, 0, stream>>>(x3b, bat, out, Nn);
}

// Round 11
// 246.421 us; speedup vs baseline: 1.1416x; 1.0131x over previous
//
#include <hip/hip_runtime.h>
#include <hip/hip_bf16.h>
#include <math.h>

#define NEG_SLOPE 0.2f
#define EPSBN 1e-5f

typedef __attribute__((ext_vector_type(8))) short bf16x8;
typedef __attribute__((ext_vector_type(4))) float f32x4;

__device__ __forceinline__ float bfu2f(unsigned u_lo16) { return __uint_as_float(u_lo16 << 16); }
__device__ __forceinline__ unsigned short f2bf(float f) {
    return __bfloat16_as_ushort(__float2bfloat16(f));
}
__device__ __forceinline__ void splitf(float v, unsigned short &h, unsigned short &l) {
    __hip_bfloat16 hb = __float2bfloat16(v);
    float r = v - __bfloat162float(hb);
    h = __bfloat16_as_ushort(hb);
    l = __bfloat16_as_ushort(__float2bfloat16(r));
}

// ---------------- precompute v = W1 @ a vectors (2 blocks x 256) -------------
// vsd[which*128+k]; which: 0=h0 src, 1=h1 src, 2=h0 dst, 3=h1 dst
__global__ __launch_bounds__(256) void precompute_v(
    const float* __restrict__ W1, const float* __restrict__ as1,
    const float* __restrict__ ad1, float* __restrict__ vsd)
{
    int idx = blockIdx.x * 256 + threadIdx.x;
    if (idx >= 512) return;
    int k = idx & 127, which = idx >> 7;
    const float* av = ((which >= 2) ? ad1 : as1) + ((which & 1) ? 128 : 0);
    const float* wr = W1 + (size_t)k * 256 + ((which & 1) ? 128 : 0);
    float v = 0.f;
    for (int c = 0; c < 128; ++c) v += wr[c] * av[c];
    vsd[which * 128 + k] = v;
}

// ---------------- mega-prep: split_x+attn | count_edges(x8 MLP) | split_w ----
__global__ __launch_bounds__(256) void prep(
    const float* __restrict__ X, const float* __restrict__ vsd,
    const float* __restrict__ W1, const float* __restrict__ W2,
    const int* __restrict__ ei,
    unsigned short* __restrict__ Xh, float* __restrict__ asrc, float* __restrict__ adst,
    unsigned short* __restrict__ w1th, unsigned short* __restrict__ w1tl,
    unsigned short* __restrict__ w2th, unsigned short* __restrict__ w2tl,
    int* __restrict__ counts, int* __restrict__ erank,
    int Nn, int E, int nwB, int countB)
{
    const int b = blockIdx.x;
    const int tid = threadIdx.x;
    if (b < nwB) {
        // ---- split x -> bf16 plane + layer-1 attn coefficients
        int n = (int)((b * 256 + tid) >> 6);
        int lane = tid & 63;
        if (n >= Nn) return;
        float2 xv = *(const float2*)(X + (size_t)n * 128 + lane * 2);
        unsigned short hh[2] = {f2bf(xv.x), f2bf(xv.y)};
        *(unsigned*)(Xh + (size_t)n * 128 + lane * 2) = *(unsigned*)hh;
        int k = lane * 2;
        float p0 = xv.x * vsd[k]       + xv.y * vsd[k + 1];
        float p1 = xv.x * vsd[128 + k] + xv.y * vsd[129 + k];
        float p2 = xv.x * vsd[256 + k] + xv.y * vsd[257 + k];
        float p3 = xv.x * vsd[384 + k] + xv.y * vsd[385 + k];
        for (int off = 32; off; off >>= 1) {
            p0 += __shfl_xor(p0, off); p1 += __shfl_xor(p1, off);
            p2 += __shfl_xor(p2, off); p3 += __shfl_xor(p3, off);
        }
        if (lane == 0) {
            asrc[n * 2] = p0; asrc[n * 2 + 1] = p1;
            adst[n * 2] = p2; adst[n * 2 + 1] = p3;
        }
    } else if (b < nwB + countB) {
        // ---- count_edges: 8 edges per thread, independent atomic chains
        int base = (b - nwB) * 2048 + tid;
        int E2 = E + Nn;
#pragma unroll
        for (int k = 0; k < 8; ++k) {
            int e = base + k * 256;
            if (e < E2) {
                int dst = (e < E) ? ei[E + e] : (e - E);
                erank[e] = atomicAdd(&counts[dst], 1);
            }
        }
    } else {
        // ---- split weights -> transposed split planes
        int idx = (b - nwB - countB) * 256 + tid;
        if (idx < 32768) {                      // W1 [128,256] -> [256,128]
            int nn = idx >> 7, k = idx & 127;
            unsigned short h, l; splitf(W1[(size_t)k * 256 + nn], h, l);
            w1th[idx] = h; w1tl[idx] = l;
        } else if (idx < 65536) {               // W2 [256,128] -> [128,256]
            int j = idx - 32768;
            int nn = j >> 8, k = j & 255;
            unsigned short h, l; splitf(W2[(size_t)k * 128 + nn], h, l);
            w2th[j] = h; w2tl[j] = l;
        }
    }
}

// ---------------- CSR scan + fill -------------------------------------------
__global__ __launch_bounds__(256) void scan_block(
    const int* __restrict__ counts, int* __restrict__ offs, int* __restrict__ bsum, int Nn)
{
    __shared__ int s[256];
    int i = blockIdx.x * 256 + threadIdx.x;
    int v = (i < Nn) ? counts[i] : 0;
    s[threadIdx.x] = v;
    __syncthreads();
    for (int off = 1; off < 256; off <<= 1) {
        int t = (threadIdx.x >= off) ? s[threadIdx.x - off] : 0;
        __syncthreads();
        s[threadIdx.x] += t;
        __syncthreads();
    }
    if (i < Nn) offs[i] = s[threadIdx.x] - v;
    if (threadIdx.x == 255) bsum[blockIdx.x] = s[255];
}

// fused scan_tops + add_offsets: each block reduces bsum[0..b) itself (nb<=256)
__global__ __launch_bounds__(256) void finalize_offsets(
    const int* __restrict__ bsum, int* __restrict__ offs, int Nn, int E2)
{
    __shared__ int ws[4];
    int b = blockIdx.x, t = threadIdx.x;
    int v = (t < b) ? bsum[t] : 0;
    for (int off = 32; off; off >>= 1) v += __shfl_xor(v, off);
    if ((t & 63) == 0) ws[t >> 6] = v;
    __syncthreads();
    int S = ws[0] + ws[1] + ws[2] + ws[3];
    int i = b * 256 + t;
    if (i < Nn) offs[i] += S;
    if (b == 0 && t == 0) offs[Nn] = E2;
}

// atomic-free scatter, 4 edges per thread (independent latency chains)
__global__ __launch_bounds__(256) void fill_edges(
    const int* __restrict__ ei, int E, int Nn,
    const int* __restrict__ offs, const int* __restrict__ erank,
    int* __restrict__ esrc)
{
    int base = blockIdx.x * 1024 + threadIdx.x;
    int E2 = E + Nn;
#pragma unroll
    for (int k = 0; k < 4; ++k) {
        int e = base + k * 256;
        if (e >= E2) continue;
        int src, dst;
        if (e < E) { src = ei[e]; dst = ei[E + e]; }
        else       { src = e - E; dst = e - E; }
        esrc[offs[dst] + erank[e]] = src;
    }
}

// ---------------- unpack-FMA helpers ----------------------------------------
__device__ __forceinline__ void fma8(float wA, uint4 hv, float acc[8])
{
    acc[0] = fmaf(wA, bfu2f(hv.x & 0xffff), acc[0]);
    acc[1] = fmaf(wA, __uint_as_float(hv.x & 0xffff0000u), acc[1]);
    acc[2] = fmaf(wA, bfu2f(hv.y & 0xffff), acc[2]);
    acc[3] = fmaf(wA, __uint_as_float(hv.y & 0xffff0000u), acc[3]);
    acc[4] = fmaf(wA, bfu2f(hv.z & 0xffff), acc[4]);
    acc[5] = fmaf(wA, __uint_as_float(hv.z & 0xffff0000u), acc[5]);
    acc[6] = fmaf(wA, bfu2f(hv.w & 0xffff), acc[6]);
    acc[7] = fmaf(wA, __uint_as_float(hv.w & 0xffff0000u), acc[7]);
}

__device__ __forceinline__ void fma8x2(float wa, float wb, uint4 hv,
                                       float a0[8], float a1[8])
{
    float f;
    f = bfu2f(hv.x & 0xffff);                 a0[0]=fmaf(wa,f,a0[0]); a1[0]=fmaf(wb,f,a1[0]);
    f = __uint_as_float(hv.x & 0xffff0000u);  a0[1]=fmaf(wa,f,a0[1]); a1[1]=fmaf(wb,f,a1[1]);
    f = bfu2f(hv.y & 0xffff);                 a0[2]=fmaf(wa,f,a0[2]); a1[2]=fmaf(wb,f,a1[2]);
    f = __uint_as_float(hv.y & 0xffff0000u);  a0[3]=fmaf(wa,f,a0[3]); a1[3]=fmaf(wb,f,a1[3]);
    f = bfu2f(hv.z & 0xffff);                 a0[4]=fmaf(wa,f,a0[4]); a1[4]=fmaf(wb,f,a1[4]);
    f = __uint_as_float(hv.z & 0xffff0000u);  a0[5]=fmaf(wa,f,a0[5]); a1[5]=fmaf(wb,f,a1[5]);
    f = bfu2f(hv.w & 0xffff);                 a0[6]=fmaf(wa,f,a0[6]); a1[6]=fmaf(wb,f,a1[6]);
    f = __uint_as_float(hv.w & 0xffff0000u);  a0[7]=fmaf(wa,f,a0[7]); a1[7]=fmaf(wb,f,a1[7]);
}

// 1-head gather: 16 lanes/edge, 4 subslots, row 256 B
__device__ __forceinline__ void gather1h(
    int sj, float w, int nc, int sub,
    const char* __restrict__ hb_c, float acc[8])
{
    for (int t = 0; t < nc; t += 4) {
        int e = t + sub;
        int sA = __shfl(sj, e);
        float wA = __shfl(w, e);
        uint4 hv = *(const uint4*)(hb_c + sA * 256);
        fma8(wA, hv, acc);
    }
}

// dual-head x-gather: 16 lanes/edge, 4 subslots, row 256 B
__device__ __forceinline__ void gatherx(
    int sj, float w0, float w1, int nc, int sub,
    const char* __restrict__ hb_c, float a0[8], float a1[8])
{
    for (int t = 0; t < nc; t += 4) {
        int e = t + sub;
        int sA = __shfl(sj, e);
        float wa = __shfl(w0, e);
        float wb = __shfl(w1, e);
        uint4 hv = *(const uint4*)(hb_c + sA * 256);
        fma8x2(wa, wb, hv, a0, a1);
    }
}

// ---------------- SpMM on input features x (layer 1), dual-head -------------
__global__ __launch_bounds__(256) void spmm_x(
    const unsigned short* __restrict__ xh, const float* __restrict__ asrc,
    const float* __restrict__ adst, const int* __restrict__ offs,
    const int* __restrict__ esrc,
    unsigned short* __restrict__ xth, int Nn)
{
    int d = (int)((blockIdx.x * blockDim.x + threadIdx.x) >> 6);
    int lane = threadIdx.x & 63;
    if (d >= Nn) return;
    int beg = offs[d], end = offs[d + 1];
    int deg = end - beg;
    float ad0 = adst[d * 2], ad1 = adst[d * 2 + 1];
    const int sub = lane >> 4;
    const int cgrp = lane & 15;
    const char* hb_c = (const char*)xh + cgrp * 16;
    float a0[8] = {}, a1[8] = {};

    if (deg <= 64) {
        int sj = 0; float e0 = -1e30f, e1 = -1e30f;
        if (lane < deg) {
            sj = esrc[beg + lane];
            float2 av = *(const float2*)(asrc + (size_t)sj * 2);
            e0 = av.x + ad0; e0 = e0 > 0.f ? e0 : NEG_SLOPE * e0;
            e1 = av.y + ad1; e1 = e1 > 0.f ? e1 : NEG_SLOPE * e1;
        }
        float m0 = e0, m1 = e1;
        for (int off = 32; off; off >>= 1) {
            m0 = fmaxf(m0, __shfl_xor(m0, off));
            m1 = fmaxf(m1, __shfl_xor(m1, off));
        }
        float p0 = (lane < deg) ? expf(e0 - m0) : 0.f;
        float p1 = (lane < deg) ? expf(e1 - m1) : 0.f;
        float s0 = p0, s1 = p1;
        for (int off = 32; off; off >>= 1) {
            s0 += __shfl_xor(s0, off);
            s1 += __shfl_xor(s1, off);
        }
        float w0 = p0 * (1.f / s0), w1 = p1 * (1.f / s1);
        gatherx(sj, w0, w1, deg, sub, hb_c, a0, a1);
    } else {
        float m0 = -1e30f, m1 = -1e30f;
        for (int j = beg + lane; j < end; j += 64) {
            int s = esrc[j];
            float2 av = *(const float2*)(asrc + (size_t)s * 2);
            float e0 = av.x + ad0; e0 = e0 > 0.f ? e0 : NEG_SLOPE * e0;
            float e1 = av.y + ad1; e1 = e1 > 0.f ? e1 : NEG_SLOPE * e1;
            m0 = fmaxf(m0, e0); m1 = fmaxf(m1, e1);
        }
        for (int off = 32; off; off >>= 1) {
            m0 = fmaxf(m0, __shfl_xor(m0, off));
            m1 = fmaxf(m1, __shfl_xor(m1, off));
        }
        float s0 = 0.f, s1 = 0.f;
        for (int j = beg + lane; j < end; j += 64) {
            int s = esrc[j];
            float2 av = *(const float2*)(asrc + (size_t)s * 2);
            float e0 = av.x + ad0; e0 = e0 > 0.f ? e0 : NEG_SLOPE * e0;
            float e1 = av.y + ad1; e1 = e1 > 0.f ? e1 : NEG_SLOPE * e1;
            s0 += expf(e0 - m0); s1 += expf(e1 - m1);
        }
        for (int off = 32; off; off >>= 1) {
            s0 += __shfl_xor(s0, off);
            s1 += __shfl_xor(s1, off);
        }
        float rd0 = 1.f / s0, rd1 = 1.f / s1;
        for (int base = beg; base < end; base += 64) {
            int nc = end - base; if (nc > 64) nc = 64;
            int sj = 0; float w0 = 0.f, w1 = 0.f;
            if (lane < nc) {
                sj = esrc[base + lane];
                float2 av = *(const float2*)(asrc + (size_t)sj * 2);
                float e0 = av.x + ad0; e0 = e0 > 0.f ? e0 : NEG_SLOPE * e0;
                float e1 = av.y + ad1; e1 = e1 > 0.f ? e1 : NEG_SLOPE * e1;
                w0 = expf(e0 - m0) * rd0;
                w1 = expf(e1 - m1) * rd1;
            }
            gatherx(sj, w0, w1, nc, sub, hb_c, a0, a1);
        }
    }
#pragma unroll
    for (int i = 0; i < 8; ++i) {
        a0[i] += __shfl_xor(a0[i], 32); a0[i] += __shfl_xor(a0[i], 16);
        a1[i] += __shfl_xor(a1[i], 32); a1[i] += __shfl_xor(a1[i], 16);
    }
    if (lane < 16) {
        int cl = cgrp * 8;
        unsigned short h0[8], h1[8];
#pragma unroll
        for (int i = 0; i < 8; ++i) { h0[i] = f2bf(a0[i]); h1[i] = f2bf(a1[i]); }
        size_t rb = (size_t)d * 256;
        *(uint4*)(xth + rb + cl)       = *(uint4*)&h0[0];
        *(uint4*)(xth + rb + 128 + cl) = *(uint4*)&h1[0];
    }
}

// ---------------- GEMM1b: x~ @ W1 (block-diag per head) + BN + bf16 out -----
__global__ __launch_bounds__(256) void gemm_bn_split(
    const unsigned short* __restrict__ Ah,
    const unsigned short* __restrict__ Bth, const unsigned short* __restrict__ Btl,
    const float* __restrict__ bias, const float* __restrict__ gamma,
    const float* __restrict__ beta, const float* __restrict__ rm,
    const float* __restrict__ rv,
    unsigned short* __restrict__ Ch, int M)
{
    __shared__ unsigned short smem[3][128][32];
    const int tid = threadIdx.x;
    const int lane = tid & 63;
    const int wave = tid >> 6;
    const int fr = lane & 15, g = lane >> 4;
    const int wr = (wave >> 1) * 64, wc = (wave & 1) * 64;
    const int rowBase = blockIdx.x * 128, colBase = blockIdx.y * 128;

    f32x4 acc[4][4] = {};

    for (int kk = 0; kk < 128; kk += 32) {
#pragma unroll
        for (int i = 0; i < 2; ++i) {
            int idx = tid + 256 * i;
            int r = idx >> 2, c = (idx & 3) * 8;
            int grow = rowBase + r;
            uint4 va_h = make_uint4(0, 0, 0, 0);
            if (grow < M) va_h = *(const uint4*)(Ah + (size_t)grow * 256 + colBase + kk + c);
            *(uint4*)&smem[0][r][c] = va_h;
            int gcol = colBase + r;
            *(uint4*)&smem[1][r][c] = *(const uint4*)(Bth + (size_t)gcol * 128 + kk + c);
            *(uint4*)&smem[2][r][c] = *(const uint4*)(Btl + (size_t)gcol * 128 + kk + c);
        }
        __syncthreads();

        bf16x8 ah[4], bh[4], bl[4];
#pragma unroll
        for (int m = 0; m < 4; ++m)
            ah[m] = *(const bf16x8*)&smem[0][wr + m * 16 + fr][g * 8];
#pragma unroll
        for (int n = 0; n < 4; ++n) {
            bh[n] = *(const bf16x8*)&smem[1][wc + n * 16 + fr][g * 8];
            bl[n] = *(const bf16x8*)&smem[2][wc + n * 16 + fr][g * 8];
        }
#pragma unroll
        for (int m = 0; m < 4; ++m)
#pragma unroll
            for (int n = 0; n < 4; ++n) {
                acc[m][n] = __builtin_amdgcn_mfma_f32_16x16x32_bf16(ah[m], bh[n], acc[m][n], 0, 0, 0);
                acc[m][n] = __builtin_amdgcn_mfma_f32_16x16x32_bf16(ah[m], bl[n], acc[m][n], 0, 0, 0);
            }
        __syncthreads();
    }

    // bias + BN + ReLU
    {
        float bi[4], ga[4], bb[4], mu[4], iv[4];
#pragma unroll
        for (int n = 0; n < 4; ++n) {
            int c = colBase + wc + n * 16 + fr;
            bi[n] = bias[c]; ga[n] = gamma[c]; bb[n] = beta[c];
            mu[n] = rm[c];   iv[n] = rsqrtf(rv[c] + EPSBN);
        }
#pragma unroll
        for (int m = 0; m < 4; ++m)
#pragma unroll
            for (int n = 0; n < 4; ++n)
#pragma unroll
                for (int j = 0; j < 4; ++j) {
                    float v = acc[m][n][j] + bi[n];
                    v = ga[n] * (v - mu[n]) * iv[n] + bb[n];
                    acc[m][n][j] = fmaxf(v, 0.f);
                }
    }

    // transpose epilogue, bf16 stores
    float* Cs = (float*)&smem[0][0][0];
    const int rl_w = (wr >> 6) * 16;
#pragma unroll
    for (int m = 0; m < 4; ++m) {
        __syncthreads();
#pragma unroll
        for (int n = 0; n < 4; ++n)
#pragma unroll
            for (int j = 0; j < 4; ++j)
                Cs[(rl_w + g * 4 + j) * 132 + wc + n * 16 + fr] = acc[m][n][j];
        __syncthreads();
        int rl = tid >> 3, c16 = (tid & 7) * 16;
        int grow = rowBase + (rl >> 4) * 64 + m * 16 + (rl & 15);
        if (grow < M) {
            unsigned short th[16];
#pragma unroll
            for (int i = 0; i < 16; ++i) th[i] = f2bf(Cs[rl * 132 + c16 + i]);
            size_t ob = (size_t)grow * 256 + colBase + c16;
            *(uint4*)(Ch + ob)     = *(uint4*)&th[0];
            *(uint4*)(Ch + ob + 8) = *(uint4*)&th[8];
        }
    }
}

// ---------------- layer-2 GEMM (single A plane) + fused attn coefs ----------
__global__ __launch_bounds__(256) void gemm_bf16_attn(
    const unsigned short* __restrict__ Ah,
    const unsigned short* __restrict__ Bth, const unsigned short* __restrict__ Btl,
    unsigned short* __restrict__ Cb,
    const float* __restrict__ aSrc, const float* __restrict__ aDst,
    float* __restrict__ asrcOut, float* __restrict__ adstOut, int M)
{
    __shared__ unsigned short smem[3][128][32];
    const int tid = threadIdx.x;
    const int lane = tid & 63;
    const int wave = tid >> 6;
    const int fr = lane & 15, g = lane >> 4;
    const int wr = (wave >> 1) * 64, wc = (wave & 1) * 64;
    const int rowBase = blockIdx.x * 128;

    f32x4 acc[4][4] = {};

    for (int kk = 0; kk < 256; kk += 32) {
#pragma unroll
        for (int i = 0; i < 2; ++i) {
            int idx = tid + 256 * i;
            int r = idx >> 2, c = (idx & 3) * 8;
            int grow = rowBase + r;
            uint4 va_h = make_uint4(0, 0, 0, 0);
            if (grow < M) va_h = *(const uint4*)(Ah + (size_t)grow * 256 + kk + c);
            *(uint4*)&smem[0][r][c] = va_h;
            *(uint4*)&smem[1][r][c] = *(const uint4*)(Bth + (size_t)r * 256 + kk + c);
            *(uint4*)&smem[2][r][c] = *(const uint4*)(Btl + (size_t)r * 256 + kk + c);
        }
        __syncthreads();

        bf16x8 ah[4], bh[4], bl[4];
#pragma unroll
        for (int m = 0; m < 4; ++m)
            ah[m] = *(const bf16x8*)&smem[0][wr + m * 16 + fr][g * 8];
#pragma unroll
        for (int n = 0; n < 4; ++n) {
            bh[n] = *(const bf16x8*)&smem[1][wc + n * 16 + fr][g * 8];
            bl[n] = *(const bf16x8*)&smem[2][wc + n * 16 + fr][g * 8];
        }
#pragma unroll
        for (int m = 0; m < 4; ++m)
#pragma unroll
            for (int n = 0; n < 4; ++n) {
                acc[m][n] = __builtin_amdgcn_mfma_f32_16x16x32_bf16(ah[m], bh[n], acc[m][n], 0, 0, 0);
                acc[m][n] = __builtin_amdgcn_mfma_f32_16x16x32_bf16(ah[m], bl[n], acc[m][n], 0, 0, 0);
            }
        __syncthreads();
    }

    // fused attention coefficient partials (heads = 1)
    {
        float avs[4], avd[4];
#pragma unroll
        for (int n = 0; n < 4; ++n) {
            int col = wc + n * 16 + fr;
            avs[n] = aSrc[col]; avd[n] = aDst[col];
        }
#pragma unroll
        for (int m = 0; m < 4; ++m) {
            float ps[4], pd[4];
#pragma unroll
            for (int j = 0; j < 4; ++j) {
                ps[j] = acc[m][0][j] * avs[0] + acc[m][1][j] * avs[1]
                      + acc[m][2][j] * avs[2] + acc[m][3][j] * avs[3];
                pd[j] = acc[m][0][j] * avd[0] + acc[m][1][j] * avd[1]
                      + acc[m][2][j] * avd[2] + acc[m][3][j] * avd[3];
            }
#pragma unroll
            for (int off = 8; off; off >>= 1)
#pragma unroll
                for (int j = 0; j < 4; ++j) {
                    ps[j] += __shfl_xor(ps[j], off);
                    pd[j] += __shfl_xor(pd[j], off);
                }
            if (fr == 0) {
#pragma unroll
                for (int j = 0; j < 4; ++j) {
                    int grow = rowBase + wr + m * 16 + g * 4 + j;
                    if (grow < M) {
                        atomicAdd(asrcOut + grow, ps[j]);
                        atomicAdd(adstOut + grow, pd[j]);
                    }
                }
            }
        }
    }

    // transpose epilogue, bf16 C (N = 128)
    float* Cs = (float*)&smem[0][0][0];
    const int rl_w = (wr >> 6) * 16;
#pragma unroll
    for (int m = 0; m < 4; ++m) {
        __syncthreads();
#pragma unroll
        for (int n = 0; n < 4; ++n)
#pragma unroll
            for (int j = 0; j < 4; ++j)
                Cs[(rl_w + g * 4 + j) * 132 + wc + n * 16 + fr] = acc[m][n][j];
        __syncthreads();
        int rl = tid >> 3, c16 = (tid & 7) * 16;
        int grow = rowBase + (rl >> 4) * 64 + m * 16 + (rl & 15);
        if (grow < M) {
            unsigned short tmp[16];
#pragma unroll
            for (int i = 0; i < 16; ++i) tmp[i] = f2bf(Cs[rl * 132 + c16 + i]);
            *(uint4*)(Cb + (size_t)grow * 128 + c16)     = *(uint4*)&tmp[0];
            *(uint4*)(Cb + (size_t)grow * 128 + c16 + 8) = *(uint4*)&tmp[8];
        }
    }
}

// ---------------- SpMM layer 2 + fused softmax, bf16 x3 out ------------------
__global__ __launch_bounds__(256) void spmm2(
    const unsigned short* __restrict__ h2b, const float* __restrict__ asrc,
    const float* __restrict__ adst, const int* __restrict__ offs,
    const int* __restrict__ esrc,
    const float* __restrict__ b2, const float* __restrict__ gamma,
    const float* __restrict__ beta, const float* __restrict__ rm,
    const float* __restrict__ rv, unsigned short* __restrict__ x3b, int Nn)
{
    int d = (int)((blockIdx.x * blockDim.x + threadIdx.x) >> 6);
    int lane = threadIdx.x & 63;
    if (d >= Nn) return;
    int beg = offs[d], end = offs[d + 1];
    int deg = end - beg;
    float ad = adst[d];
    const int sub = lane >> 4;
    const int cgrp = lane & 15;
    const char* hb_c = (const char*)h2b + cgrp * 16;
    float acc[8] = {};

    if (deg <= 64) {
        int sj = 0; float ev = -1e30f;
        if (lane < deg) {
            sj = esrc[beg + lane];
            float e = asrc[sj] + ad; ev = e > 0.f ? e : NEG_SLOPE * e;
        }
        float m = ev;
        for (int off = 32; off; off >>= 1) m = fmaxf(m, __shfl_xor(m, off));
        float p = (lane < deg) ? expf(ev - m) : 0.f;
        float s = p;
        for (int off = 32; off; off >>= 1) s += __shfl_xor(s, off);
        float w = p * (1.f / s);
        gather1h(sj, w, deg, sub, hb_c, acc);
    } else {
        float m = -1e30f;
        for (int j = beg + lane; j < end; j += 64) {
            int s = esrc[j];
            float e = asrc[s] + ad; e = e > 0.f ? e : NEG_SLOPE * e;
            m = fmaxf(m, e);
        }
        for (int off = 32; off; off >>= 1) m = fmaxf(m, __shfl_xor(m, off));
        float sd = 0.f;
        for (int j = beg + lane; j < end; j += 64) {
            int s = esrc[j];
            float e = asrc[s] + ad; e = e > 0.f ? e : NEG_SLOPE * e;
            sd += expf(e - m);
        }
        for (int off = 32; off; off >>= 1) sd += __shfl_xor(sd, off);
        float rd = 1.f / sd;
        for (int base = beg; base < end; base += 64) {
            int nc = end - base; if (nc > 64) nc = 64;
            int sj = 0; float wj = 0.f;
            if (lane < nc) {
                sj = esrc[base + lane];
                float e = asrc[sj] + ad; e = e > 0.f ? e : NEG_SLOPE * e;
                wj = expf(e - m) * rd;
            }
            gather1h(sj, wj, nc, sub, hb_c, acc);
        }
    }
#pragma unroll
    for (int i = 0; i < 8; ++i) {
        acc[i] += __shfl_xor(acc[i], 32);
        acc[i] += __shfl_xor(acc[i], 16);
    }
    if (lane < 16) {
        int cl = cgrp * 8;
        unsigned short hh[8];
#pragma unroll
        for (int i = 0; i < 8; ++i) {
            int c = cl + i;
            float v = acc[i] + b2[c];
            v = gamma[c] * (v - rm[c]) * rsqrtf(rv[c] + EPSBN) + beta[c];
            hh[i] = f2bf(fmaxf(v, 0.f));
        }
        *(uint4*)(x3b + (size_t)d * 128 + cl) = *(uint4*)&hh[0];
    }
}

// ---------------- global max pool over bf16 x3: one block per graph ---------
__global__ __launch_bounds__(128) void pool_max_graph(
    const unsigned short* __restrict__ x3b, const int* __restrict__ bat,
    float* __restrict__ out, int Nn)
{
    int g = blockIdx.x;
    int c = threadIdx.x;
    int lo = 0, hi = Nn;
    while (lo < hi) { int mid = (lo + hi) >> 1; if (bat[mid] < g) lo = mid + 1; else hi = mid; }
    int beg = lo;
    hi = Nn;
    while (lo < hi) { int mid = (lo + hi) >> 1; if (bat[mid] < g + 1) lo = mid + 1; else hi = mid; }
    int end = lo;
    float acc = -1e30f;
    for (int n = beg; n < end; ++n)
        acc = fmaxf(acc, bfu2f((unsigned)x3b[(size_t)n * 128 + c]));
    out[(size_t)g * 128 + c] = acc;
}

// ---------------------------------------------------------------------------
extern "C" void kernel_launch(void* const* d_in, const int* in_sizes, int n_in,
                              void* d_out, int out_size, void* d_ws, size_t ws_size,
                              hipStream_t stream)
{
    const float* x   = (const float*)d_in[0];
    const int*   ei  = (const int*)d_in[1];
    const int*   bat = (const int*)d_in[2];
    const float* W1  = (const float*)d_in[3];
    const float* as1 = (const float*)d_in[4];
    const float* ad1 = (const float*)d_in[5];
    const float* b1  = (const float*)d_in[6];
    const float* g1  = (const float*)d_in[7];
    const float* be1 = (const float*)d_in[8];
    const float* rm1 = (const float*)d_in[9];
    const float* rv1 = (const float*)d_in[10];
    const float* W2  = (const float*)d_in[11];
    const float* as2 = (const float*)d_in[12];
    const float* ad2 = (const float*)d_in[13];
    const float* b2  = (const float*)d_in[14];
    const float* g2  = (const float*)d_in[15];
    const float* be2 = (const float*)d_in[16];
    const float* rm2 = (const float*)d_in[17];
    const float* rv2 = (const float*)d_in[18];
    float* out = (float*)d_out;

    const int Nn = in_sizes[0] / 128;
    const int E  = in_sizes[1] / 2;
    const int E2 = E + Nn;
    const int B  = out_size / 128;

    char* p = (char*)d_ws;
    size_t off = 0;
    auto alloc = [&](size_t bytes) -> void* {
        void* r = p + off;
        off = (off + bytes + 255) & ~(size_t)255;
        return r;
    };
    unsigned short* xh    = (unsigned short*)alloc((size_t)Nn * 128 * 2);
    unsigned short* w1th  = (unsigned short*)alloc(256 * 128 * 2);
    unsigned short* w1tl  = (unsigned short*)alloc(256 * 128 * 2);
    unsigned short* w2th  = (unsigned short*)alloc(128 * 256 * 2);
    unsigned short* w2tl  = (unsigned short*)alloc(128 * 256 * 2);
    unsigned short* xth   = (unsigned short*)alloc((size_t)Nn * 256 * 2);
    unsigned short* x2h   = (unsigned short*)alloc((size_t)Nn * 256 * 2);
    float*          vsd   = (float*)alloc(4 * 128 * 4);
    float*          asrc1 = (float*)alloc((size_t)Nn * 2 * 4);
    float*          adst1 = (float*)alloc((size_t)Nn * 2 * 4);
    float*          attnv = (float*)alloc((size_t)Nn * 2 * 4);   // asrc2, adst2
    float*          asrc2 = attnv;
    float*          adst2 = attnv + Nn;
    int*            counts= (int*)alloc((size_t)Nn * 4);
    int*            erank = (int*)alloc((size_t)E2 * 4);
    int*            offs  = (int*)alloc((size_t)(Nn + 1) * 4);
    int*            bsum  = (int*)alloc(256 * 4);
    int*            esrc  = (int*)alloc((size_t)E2 * 4);
    // aliases (proven pattern): xth dead after gemm_bn_split -> x3b;
    // xh dead after spmm_x -> h2b target for layer-2 GEMM
    unsigned short* x3b   = xth;
    unsigned short* h2b   = xh;

    const int nb = (Nn + 255) / 256;
    const int nwB = (Nn + 3) / 4;
    const int countB = (E2 + 2047) / 2048;
    const int gmB = (Nn + 127) / 128;

    hipMemsetAsync(counts, 0, (size_t)Nn * 4, stream);
    hipMemsetAsync(attnv, 0, (size_t)Nn * 2 * 4, stream);

    // ---- prep: vsd, then fused {split_x+attn | count_edges(x8) | split_w}
    precompute_v<<<2, 256, 0, stream>>>(W1, as1, ad1, vsd);
    prep<<<nwB + countB + 256, 256, 0, stream>>>(
        x, vsd, W1, W2, ei, xh, asrc1, adst1,
        w1th, w1tl, w2th, w2tl, counts, erank, Nn, E, nwB, countB);

    // ---- CSR scan + fill
    scan_block<<<nb, 256, 0, stream>>>(counts, offs, bsum, Nn);
    finalize_offsets<<<nb, 256, 0, stream>>>(bsum, offs, Nn, E2);
    fill_edges<<<(E2 + 1023) / 1024, 256, 0, stream>>>(ei, E, Nn, offs, erank, esrc);

    // ---- layer 1: aggregate x (dual-head) then project + BN + ReLU
    spmm_x<<<nwB, 256, 0, stream>>>(xh, asrc1, adst1, offs, esrc, xth, Nn);
    gemm_bn_split<<<dim3(gmB, 2), 256, 0, stream>>>(
        xth, w1th, w1tl, b1, g1, be1, rm1, rv1, x2h, Nn);

    // ---- layer 2: GEMM (+attn coef) then SpMM (bf16 out)
    gemm_bf16_attn<<<gmB, 256, 0, stream>>>(
        x2h, w2th, w2tl, h2b, as2, ad2, asrc2, adst2, Nn);
    spmm2<<<nwB, 256, 0, stream>>>(h2b, asrc2, adst2, offs, esrc,
                                   b2, g2, be2, rm2, rv2, x3b, Nn);

    // ---- global max pool (bf16 in, f32 out)
    pool_max_graph<<<B, 128, 0, stream>>>(x3b, bat, out, Nn);
}

// Round 12
// 246.042 us; speedup vs baseline: 1.1434x; 1.0015x over previous
//
#include <hip/hip_runtime.h>
#include <hip/hip_bf16.h>
#include <math.h>

#define NEG_SLOPE 0.2f
#define EPSBN 1e-5f
#define NREP 8

typedef __attribute__((ext_vector_type(8))) short bf16x8;
typedef __attribute__((ext_vector_type(4))) float f32x4;

__device__ __forceinline__ float bfu2f(unsigned u_lo16) { return __uint_as_float(u_lo16 << 16); }
__device__ __forceinline__ unsigned short f2bf(float f) {
    return __bfloat16_as_ushort(__float2bfloat16(f));
}
__device__ __forceinline__ void splitf(float v, unsigned short &h, unsigned short &l) {
    __hip_bfloat16 hb = __float2bfloat16(v);
    float r = v - __bfloat162float(hb);
    h = __bfloat16_as_ushort(hb);
    l = __bfloat16_as_ushort(__float2bfloat16(r));
}

// ---------------- precompute v = W1 @ a vectors (2 blocks x 256) -------------
__global__ __launch_bounds__(256) void precompute_v(
    const float* __restrict__ W1, const float* __restrict__ as1,
    const float* __restrict__ ad1, float* __restrict__ vsd)
{
    int idx = blockIdx.x * 256 + threadIdx.x;
    if (idx >= 512) return;
    int k = idx & 127, which = idx >> 7;
    const float* av = ((which >= 2) ? ad1 : as1) + ((which & 1) ? 128 : 0);
    const float* wr = W1 + (size_t)k * 256 + ((which & 1) ? 128 : 0);
    float v = 0.f;
    for (int c = 0; c < 128; ++c) v += wr[c] * av[c];
    vsd[which * 128 + k] = v;
}

// ---------------- mega-prep: count_edges(8-rep) | split_x+attn | split_w -----
// count blocks dispatched FIRST so atomics drain under the streaming blocks
__global__ __launch_bounds__(256) void prep(
    const float* __restrict__ X, const float* __restrict__ vsd,
    const float* __restrict__ W1, const float* __restrict__ W2,
    const int* __restrict__ ei,
    unsigned short* __restrict__ Xh, float* __restrict__ asrc, float* __restrict__ adst,
    unsigned short* __restrict__ w1th, unsigned short* __restrict__ w1tl,
    unsigned short* __restrict__ w2th, unsigned short* __restrict__ w2tl,
    int* __restrict__ counts, int* __restrict__ erank,
    int Nn, int E, int nwB, int countB)
{
    const int b = blockIdx.x;
    const int tid = threadIdx.x;
    if (b < countB) {
        // ---- count_edges: replica r = e&7 cuts same-address contention 8x
        int e = b * 256 + tid;
        int E2 = E + Nn;
        if (e >= E2) return;
        int dst = (e < E) ? ei[E + e] : (e - E);
        erank[e] = atomicAdd(&counts[(e & (NREP - 1)) * Nn + dst], 1);
    } else if (b < countB + nwB) {
        // ---- split x -> bf16 plane + layer-1 attn coefficients
        int n = (int)(((b - countB) * 256 + tid) >> 6);
        int lane = tid & 63;
        if (n >= Nn) return;
        float2 xv = *(const float2*)(X + (size_t)n * 128 + lane * 2);
        unsigned short hh[2] = {f2bf(xv.x), f2bf(xv.y)};
        *(unsigned*)(Xh + (size_t)n * 128 + lane * 2) = *(unsigned*)hh;
        int k = lane * 2;
        float p0 = xv.x * vsd[k]       + xv.y * vsd[k + 1];
        float p1 = xv.x * vsd[128 + k] + xv.y * vsd[129 + k];
        float p2 = xv.x * vsd[256 + k] + xv.y * vsd[257 + k];
        float p3 = xv.x * vsd[384 + k] + xv.y * vsd[385 + k];
        for (int off = 32; off; off >>= 1) {
            p0 += __shfl_xor(p0, off); p1 += __shfl_xor(p1, off);
            p2 += __shfl_xor(p2, off); p3 += __shfl_xor(p3, off);
        }
        if (lane == 0) {
            asrc[n * 2] = p0; asrc[n * 2 + 1] = p1;
            adst[n * 2] = p2; adst[n * 2 + 1] = p3;
        }
    } else {
        // ---- split weights -> transposed split planes
        int idx = (b - countB - nwB) * 256 + tid;
        if (idx < 32768) {                      // W1 [128,256] -> [256,128]
            int nn = idx >> 7, k = idx & 127;
            unsigned short h, l; splitf(W1[(size_t)k * 256 + nn], h, l);
            w1th[idx] = h; w1tl[idx] = l;
        } else if (idx < 65536) {               // W2 [256,128] -> [128,256]
            int j = idx - 32768;
            int nn = j >> 8, k = j & 255;
            unsigned short h, l; splitf(W2[(size_t)k * 128 + nn], h, l);
            w2th[j] = h; w2tl[j] = l;
        }
    }
}

// ---------------- CSR scan (folds 8 replicas -> repoff in place) -------------
__global__ __launch_bounds__(256) void scan_block(
    int* __restrict__ counts, int* __restrict__ offs, int* __restrict__ bsum, int Nn)
{
    __shared__ int s[256];
    int i = blockIdx.x * 256 + threadIdx.x;
    int v = 0;
    if (i < Nn) {
        int c[NREP];
#pragma unroll
        for (int r = 0; r < NREP; ++r) c[r] = counts[r * Nn + i];
        int run = 0;
#pragma unroll
        for (int r = 0; r < NREP; ++r) { counts[r * Nn + i] = run; run += c[r]; }
        v = run;
    }
    s[threadIdx.x] = v;
    __syncthreads();
    for (int off = 1; off < 256; off <<= 1) {
        int t = (threadIdx.x >= off) ? s[threadIdx.x - off] : 0;
        __syncthreads();
        s[threadIdx.x] += t;
        __syncthreads();
    }
    if (i < Nn) offs[i] = s[threadIdx.x] - v;
    if (threadIdx.x == 255) bsum[blockIdx.x] = s[255];
}

// fused scan_tops + add_offsets: each block reduces bsum[0..b) itself (nb<=256)
__global__ __launch_bounds__(256) void finalize_offsets(
    const int* __restrict__ bsum, int* __restrict__ offs, int Nn, int E2)
{
    __shared__ int ws[4];
    int b = blockIdx.x, t = threadIdx.x;
    int v = (t < b) ? bsum[t] : 0;
    for (int off = 32; off; off >>= 1) v += __shfl_xor(v, off);
    if ((t & 63) == 0) ws[t >> 6] = v;
    __syncthreads();
    int S = ws[0] + ws[1] + ws[2] + ws[3];
    int i = b * 256 + t;
    if (i < Nn) offs[i] += S;
    if (b == 0 && t == 0) offs[Nn] = E2;
}

// atomic-free scatter using replica base + in-replica rank
__global__ void fill_edges(
    const int* __restrict__ ei, int E, int Nn,
    const int* __restrict__ offs, const int* __restrict__ repoff,
    const int* __restrict__ erank, int* __restrict__ esrc)
{
    int e = blockIdx.x * blockDim.x + threadIdx.x;
    int E2 = E + Nn;
    if (e >= E2) return;
    int src, dst;
    if (e < E) { src = ei[e]; dst = ei[E + e]; }
    else       { src = e - E; dst = e - E; }
    esrc[offs[dst] + repoff[(e & (NREP - 1)) * Nn + dst] + erank[e]] = src;
}

// ---------------- unpack-FMA helpers ----------------------------------------
__device__ __forceinline__ void fma8(float wA, uint4 hv, float acc[8])
{
    acc[0] = fmaf(wA, bfu2f(hv.x & 0xffff), acc[0]);
    acc[1] = fmaf(wA, __uint_as_float(hv.x & 0xffff0000u), acc[1]);
    acc[2] = fmaf(wA, bfu2f(hv.y & 0xffff), acc[2]);
    acc[3] = fmaf(wA, __uint_as_float(hv.y & 0xffff0000u), acc[3]);
    acc[4] = fmaf(wA, bfu2f(hv.z & 0xffff), acc[4]);
    acc[5] = fmaf(wA, __uint_as_float(hv.z & 0xffff0000u), acc[5]);
    acc[6] = fmaf(wA, bfu2f(hv.w & 0xffff), acc[6]);
    acc[7] = fmaf(wA, __uint_as_float(hv.w & 0xffff0000u), acc[7]);
}

__device__ __forceinline__ void fma8x2(float wa, float wb, uint4 hv,
                                       float a0[8], float a1[8])
{
    float f;
    f = bfu2f(hv.x & 0xffff);                 a0[0]=fmaf(wa,f,a0[0]); a1[0]=fmaf(wb,f,a1[0]);
    f = __uint_as_float(hv.x & 0xffff0000u);  a0[1]=fmaf(wa,f,a0[1]); a1[1]=fmaf(wb,f,a1[1]);
    f = bfu2f(hv.y & 0xffff);                 a0[2]=fmaf(wa,f,a0[2]); a1[2]=fmaf(wb,f,a1[2]);
    f = __uint_as_float(hv.y & 0xffff0000u);  a0[3]=fmaf(wa,f,a0[3]); a1[3]=fmaf(wb,f,a1[3]);
    f = bfu2f(hv.z & 0xffff);                 a0[4]=fmaf(wa,f,a0[4]); a1[4]=fmaf(wb,f,a1[4]);
    f = __uint_as_float(hv.z & 0xffff0000u);  a0[5]=fmaf(wa,f,a0[5]); a1[5]=fmaf(wb,f,a1[5]);
    f = bfu2f(hv.w & 0xffff);                 a0[6]=fmaf(wa,f,a0[6]); a1[6]=fmaf(wb,f,a1[6]);
    f = __uint_as_float(hv.w & 0xffff0000u);  a0[7]=fmaf(wa,f,a0[7]); a1[7]=fmaf(wb,f,a1[7]);
}

// 1-head gather: 16 lanes/edge, 4 subslots, row 256 B
__device__ __forceinline__ void gather1h(
    int sj, float w, int nc, int sub,
    const char* __restrict__ hb_c, float acc[8])
{
    for (int t = 0; t < nc; t += 4) {
        int e = t + sub;
        int sA = __shfl(sj, e);
        float wA = __shfl(w, e);
        uint4 hv = *(const uint4*)(hb_c + sA * 256);
        fma8(wA, hv, acc);
    }
}

// dual-head x-gather: 16 lanes/edge, 4 subslots, row 256 B
__device__ __forceinline__ void gatherx(
    int sj, float w0, float w1, int nc, int sub,
    const char* __restrict__ hb_c, float a0[8], float a1[8])
{
    for (int t = 0; t < nc; t += 4) {
        int e = t + sub;
        int sA = __shfl(sj, e);
        float wa = __shfl(w0, e);
        float wb = __shfl(w1, e);
        uint4 hv = *(const uint4*)(hb_c + sA * 256);
        fma8x2(wa, wb, hv, a0, a1);
    }
}

// ---------------- SpMM on input features x (layer 1), dual-head -------------
__global__ __launch_bounds__(256) void spmm_x(
    const unsigned short* __restrict__ xh, const float* __restrict__ asrc,
    const float* __restrict__ adst, const int* __restrict__ offs,
    const int* __restrict__ esrc,
    unsigned short* __restrict__ xth, int Nn)
{
    int d = (int)((blockIdx.x * blockDim.x + threadIdx.x) >> 6);
    int lane = threadIdx.x & 63;
    if (d >= Nn) return;
    int beg = offs[d], end = offs[d + 1];
    int deg = end - beg;
    float ad0 = adst[d * 2], ad1 = adst[d * 2 + 1];
    const int sub = lane >> 4;
    const int cgrp = lane & 15;
    const char* hb_c = (const char*)xh + cgrp * 16;
    float a0[8] = {}, a1[8] = {};

    if (deg <= 64) {
        int sj = 0; float e0 = -1e30f, e1 = -1e30f;
        if (lane < deg) {
            sj = esrc[beg + lane];
            float2 av = *(const float2*)(asrc + (size_t)sj * 2);
            e0 = av.x + ad0; e0 = e0 > 0.f ? e0 : NEG_SLOPE * e0;
            e1 = av.y + ad1; e1 = e1 > 0.f ? e1 : NEG_SLOPE * e1;
        }
        float m0 = e0, m1 = e1;
        for (int off = 32; off; off >>= 1) {
            m0 = fmaxf(m0, __shfl_xor(m0, off));
            m1 = fmaxf(m1, __shfl_xor(m1, off));
        }
        float p0 = (lane < deg) ? expf(e0 - m0) : 0.f;
        float p1 = (lane < deg) ? expf(e1 - m1) : 0.f;
        float s0 = p0, s1 = p1;
        for (int off = 32; off; off >>= 1) {
            s0 += __shfl_xor(s0, off);
            s1 += __shfl_xor(s1, off);
        }
        float w0 = p0 * (1.f / s0), w1 = p1 * (1.f / s1);
        gatherx(sj, w0, w1, deg, sub, hb_c, a0, a1);
    } else {
        float m0 = -1e30f, m1 = -1e30f;
        for (int j = beg + lane; j < end; j += 64) {
            int s = esrc[j];
            float2 av = *(const float2*)(asrc + (size_t)s * 2);
            float e0 = av.x + ad0; e0 = e0 > 0.f ? e0 : NEG_SLOPE * e0;
            float e1 = av.y + ad1; e1 = e1 > 0.f ? e1 : NEG_SLOPE * e1;
            m0 = fmaxf(m0, e0); m1 = fmaxf(m1, e1);
        }
        for (int off = 32; off; off >>= 1) {
            m0 = fmaxf(m0, __shfl_xor(m0, off));
            m1 = fmaxf(m1, __shfl_xor(m1, off));
        }
        float s0 = 0.f, s1 = 0.f;
        for (int j = beg + lane; j < end; j += 64) {
            int s = esrc[j];
            float2 av = *(const float2*)(asrc + (size_t)s * 2);
            float e0 = av.x + ad0; e0 = e0 > 0.f ? e0 : NEG_SLOPE * e0;
            float e1 = av.y + ad1; e1 = e1 > 0.f ? e1 : NEG_SLOPE * e1;
            s0 += expf(e0 - m0); s1 += expf(e1 - m1);
        }
        for (int off = 32; off; off >>= 1) {
            s0 += __shfl_xor(s0, off);
            s1 += __shfl_xor(s1, off);
        }
        float rd0 = 1.f / s0, rd1 = 1.f / s1;
        for (int base = beg; base < end; base += 64) {
            int nc = end - base; if (nc > 64) nc = 64;
            int sj = 0; float w0 = 0.f, w1 = 0.f;
            if (lane < nc) {
                sj = esrc[base + lane];
                float2 av = *(const float2*)(asrc + (size_t)sj * 2);
                float e0 = av.x + ad0; e0 = e0 > 0.f ? e0 : NEG_SLOPE * e0;
                float e1 = av.y + ad1; e1 = e1 > 0.f ? e1 : NEG_SLOPE * e1;
                w0 = expf(e0 - m0) * rd0;
                w1 = expf(e1 - m1) * rd1;
            }
            gatherx(sj, w0, w1, nc, sub, hb_c, a0, a1);
        }
    }
#pragma unroll
    for (int i = 0; i < 8; ++i) {
        a0[i] += __shfl_xor(a0[i], 32); a0[i] += __shfl_xor(a0[i], 16);
        a1[i] += __shfl_xor(a1[i], 32); a1[i] += __shfl_xor(a1[i], 16);
    }
    if (lane < 16) {
        int cl = cgrp * 8;
        unsigned short h0[8], h1[8];
#pragma unroll
        for (int i = 0; i < 8; ++i) { h0[i] = f2bf(a0[i]); h1[i] = f2bf(a1[i]); }
        size_t rb = (size_t)d * 256;
        *(uint4*)(xth + rb + cl)       = *(uint4*)&h0[0];
        *(uint4*)(xth + rb + 128 + cl) = *(uint4*)&h1[0];
    }
}

// ---------------- GEMM1b: x~ @ W1 (block-diag per head) + BN + bf16 out -----
__global__ __launch_bounds__(256) void gemm_bn_split(
    const unsigned short* __restrict__ Ah,
    const unsigned short* __restrict__ Bth, const unsigned short* __restrict__ Btl,
    const float* __restrict__ bias, const float* __restrict__ gamma,
    const float* __restrict__ beta, const float* __restrict__ rm,
    const float* __restrict__ rv,
    unsigned short* __restrict__ Ch, int M)
{
    __shared__ unsigned short smem[3][128][32];
    const int tid = threadIdx.x;
    const int lane = tid & 63;
    const int wave = tid >> 6;
    const int fr = lane & 15, g = lane >> 4;
    const int wr = (wave >> 1) * 64, wc = (wave & 1) * 64;
    const int rowBase = blockIdx.x * 128, colBase = blockIdx.y * 128;

    f32x4 acc[4][4] = {};

    for (int kk = 0; kk < 128; kk += 32) {
#pragma unroll
        for (int i = 0; i < 2; ++i) {
            int idx = tid + 256 * i;
            int r = idx >> 2, c = (idx & 3) * 8;
            int grow = rowBase + r;
            uint4 va_h = make_uint4(0, 0, 0, 0);
            if (grow < M) va_h = *(const uint4*)(Ah + (size_t)grow * 256 + colBase + kk + c);
            *(uint4*)&smem[0][r][c] = va_h;
            int gcol = colBase + r;
            *(uint4*)&smem[1][r][c] = *(const uint4*)(Bth + (size_t)gcol * 128 + kk + c);
            *(uint4*)&smem[2][r][c] = *(const uint4*)(Btl + (size_t)gcol * 128 + kk + c);
        }
        __syncthreads();

        bf16x8 ah[4], bh[4], bl[4];
#pragma unroll
        for (int m = 0; m < 4; ++m)
            ah[m] = *(const bf16x8*)&smem[0][wr + m * 16 + fr][g * 8];
#pragma unroll
        for (int n = 0; n < 4; ++n) {
            bh[n] = *(const bf16x8*)&smem[1][wc + n * 16 + fr][g * 8];
            bl[n] = *(const bf16x8*)&smem[2][wc + n * 16 + fr][g * 8];
        }
#pragma unroll
        for (int m = 0; m < 4; ++m)
#pragma unroll
            for (int n = 0; n < 4; ++n) {
                acc[m][n] = __builtin_amdgcn_mfma_f32_16x16x32_bf16(ah[m], bh[n], acc[m][n], 0, 0, 0);
                acc[m][n] = __builtin_amdgcn_mfma_f32_16x16x32_bf16(ah[m], bl[n], acc[m][n], 0, 0, 0);
            }
        __syncthreads();
    }

    // bias + BN + ReLU
    {
        float bi[4], ga[4], bb[4], mu[4], iv[4];
#pragma unroll
        for (int n = 0; n < 4; ++n) {
            int c = colBase + wc + n * 16 + fr;
            bi[n] = bias[c]; ga[n] = gamma[c]; bb[n] = beta[c];
            mu[n] = rm[c];   iv[n] = rsqrtf(rv[c] + EPSBN);
        }
#pragma unroll
        for (int m = 0; m < 4; ++m)
#pragma unroll
            for (int n = 0; n < 4; ++n)
#pragma unroll
                for (int j = 0; j < 4; ++j) {
                    float v = acc[m][n][j] + bi[n];
                    v = ga[n] * (v - mu[n]) * iv[n] + bb[n];
                    acc[m][n][j] = fmaxf(v, 0.f);
                }
    }

    // transpose epilogue, bf16 stores
    float* Cs = (float*)&smem[0][0][0];
    const int rl_w = (wr >> 6) * 16;
#pragma unroll
    for (int m = 0; m < 4; ++m) {
        __syncthreads();
#pragma unroll
        for (int n = 0; n < 4; ++n)
#pragma unroll
            for (int j = 0; j < 4; ++j)
                Cs[(rl_w + g * 4 + j) * 132 + wc + n * 16 + fr] = acc[m][n][j];
        __syncthreads();
        int rl = tid >> 3, c16 = (tid & 7) * 16;
        int grow = rowBase + (rl >> 4) * 64 + m * 16 + (rl & 15);
        if (grow < M) {
            unsigned short th[16];
#pragma unroll
            for (int i = 0; i < 16; ++i) th[i] = f2bf(Cs[rl * 132 + c16 + i]);
            size_t ob = (size_t)grow * 256 + colBase + c16;
            *(uint4*)(Ch + ob)     = *(uint4*)&th[0];
            *(uint4*)(Ch + ob + 8) = *(uint4*)&th[8];
        }
    }
}

// ---------------- layer-2 GEMM (single A plane) + fused attn coefs ----------
__global__ __launch_bounds__(256) void gemm_bf16_attn(
    const unsigned short* __restrict__ Ah,
    const unsigned short* __restrict__ Bth, const unsigned short* __restrict__ Btl,
    unsigned short* __restrict__ Cb,
    const float* __restrict__ aSrc, const float* __restrict__ aDst,
    float* __restrict__ asrcOut, float* __restrict__ adstOut, int M)
{
    __shared__ unsigned short smem[3][128][32];
    const int tid = threadIdx.x;
    const int lane = tid & 63;
    const int wave = tid >> 6;
    const int fr = lane & 15, g = lane >> 4;
    const int wr = (wave >> 1) * 64, wc = (wave & 1) * 64;
    const int rowBase = blockIdx.x * 128;

    f32x4 acc[4][4] = {};

    for (int kk = 0; kk < 256; kk += 32) {
#pragma unroll
        for (int i = 0; i < 2; ++i) {
            int idx = tid + 256 * i;
            int r = idx >> 2, c = (idx & 3) * 8;
            int grow = rowBase + r;
            uint4 va_h = make_uint4(0, 0, 0, 0);
            if (grow < M) va_h = *(const uint4*)(Ah + (size_t)grow * 256 + kk + c);
            *(uint4*)&smem[0][r][c] = va_h;
            *(uint4*)&smem[1][r][c] = *(const uint4*)(Bth + (size_t)r * 256 + kk + c);
            *(uint4*)&smem[2][r][c] = *(const uint4*)(Btl + (size_t)r * 256 + kk + c);
        }
        __syncthreads();

        bf16x8 ah[4], bh[4], bl[4];
#pragma unroll
        for (int m = 0; m < 4; ++m)
            ah[m] = *(const bf16x8*)&smem[0][wr + m * 16 + fr][g * 8];
#pragma unroll
        for (int n = 0; n < 4; ++n) {
            bh[n] = *(const bf16x8*)&smem[1][wc + n * 16 + fr][g * 8];
            bl[n] = *(const bf16x8*)&smem[2][wc + n * 16 + fr][g * 8];
        }
#pragma unroll
        for (int m = 0; m < 4; ++m)
#pragma unroll
            for (int n = 0; n < 4; ++n) {
                acc[m][n] = __builtin_amdgcn_mfma_f32_16x16x32_bf16(ah[m], bh[n], acc[m][n], 0, 0, 0);
                acc[m][n] = __builtin_amdgcn_mfma_f32_16x16x32_bf16(ah[m], bl[n], acc[m][n], 0, 0, 0);
            }
        __syncthreads();
    }

    // fused attention coefficient partials (heads = 1)
    {
        float avs[4], avd[4];
#pragma unroll
        for (int n = 0; n < 4; ++n) {
            int col = wc + n * 16 + fr;
            avs[n] = aSrc[col]; avd[n] = aDst[col];
        }
#pragma unroll
        for (int m = 0; m < 4; ++m) {
            float ps[4], pd[4];
#pragma unroll
            for (int j = 0; j < 4; ++j) {
                ps[j] = acc[m][0][j] * avs[0] + acc[m][1][j] * avs[1]
                      + acc[m][2][j] * avs[2] + acc[m][3][j] * avs[3];
                pd[j] = acc[m][0][j] * avd[0] + acc[m][1][j] * avd[1]
                      + acc[m][2][j] * avd[2] + acc[m][3][j] * avd[3];
            }
#pragma unroll
            for (int off = 8; off; off >>= 1)
#pragma unroll
                for (int j = 0; j < 4; ++j) {
                    ps[j] += __shfl_xor(ps[j], off);
                    pd[j] += __shfl_xor(pd[j], off);
                }
            if (fr == 0) {
#pragma unroll
                for (int j = 0; j < 4; ++j) {
                    int grow = rowBase + wr + m * 16 + g * 4 + j;
                    if (grow < M) {
                        atomicAdd(asrcOut + grow, ps[j]);
                        atomicAdd(adstOut + grow, pd[j]);
                    }
                }
            }
        }
    }

    // transpose epilogue, bf16 C (N = 128)
    float* Cs = (float*)&smem[0][0][0];
    const int rl_w = (wr >> 6) * 16;
#pragma unroll
    for (int m = 0; m < 4; ++m) {
        __syncthreads();
#pragma unroll
        for (int n = 0; n < 4; ++n)
#pragma unroll
            for (int j = 0; j < 4; ++j)
                Cs[(rl_w + g * 4 + j) * 132 + wc + n * 16 + fr] = acc[m][n][j];
        __syncthreads();
        int rl = tid >> 3, c16 = (tid & 7) * 16;
        int grow = rowBase + (rl >> 4) * 64 + m * 16 + (rl & 15);
        if (grow < M) {
            unsigned short tmp[16];
#pragma unroll
            for (int i = 0; i < 16; ++i) tmp[i] = f2bf(Cs[rl * 132 + c16 + i]);
            *(uint4*)(Cb + (size_t)grow * 128 + c16)     = *(uint4*)&tmp[0];
            *(uint4*)(Cb + (size_t)grow * 128 + c16 + 8) = *(uint4*)&tmp[8];
        }
    }
}

// ---------------- SpMM layer 2 + fused softmax, bf16 x3 out ------------------
__global__ __launch_bounds__(256) void spmm2(
    const unsigned short* __restrict__ h2b, const float* __restrict__ asrc,
    const float* __restrict__ adst, const int* __restrict__ offs,
    const int* __restrict__ esrc,
    const float* __restrict__ b2, const float* __restrict__ gamma,
    const float* __restrict__ beta, const float* __restrict__ rm,
    const float* __restrict__ rv, unsigned short* __restrict__ x3b, int Nn)
{
    int d = (int)((blockIdx.x * blockDim.x + threadIdx.x) >> 6);
    int lane = threadIdx.x & 63;
    if (d >= Nn) return;
    int beg = offs[d], end = offs[d + 1];
    int deg = end - beg;
    float ad = adst[d];
    const int sub = lane >> 4;
    const int cgrp = lane & 15;
    const char* hb_c = (const char*)h2b + cgrp * 16;
    float acc[8] = {};

    if (deg <= 64) {
        int sj = 0; float ev = -1e30f;
        if (lane < deg) {
            sj = esrc[beg + lane];
            float e = asrc[sj] + ad; ev = e > 0.f ? e : NEG_SLOPE * e;
        }
        float m = ev;
        for (int off = 32; off; off >>= 1) m = fmaxf(m, __shfl_xor(m, off));
        float p = (lane < deg) ? expf(ev - m) : 0.f;
        float s = p;
        for (int off = 32; off; off >>= 1) s += __shfl_xor(s, off);
        float w = p * (1.f / s);
        gather1h(sj, w, deg, sub, hb_c, acc);
    } else {
        float m = -1e30f;
        for (int j = beg + lane; j < end; j += 64) {
            int s = esrc[j];
            float e = asrc[s] + ad; e = e > 0.f ? e : NEG_SLOPE * e;
            m = fmaxf(m, e);
        }
        for (int off = 32; off; off >>= 1) m = fmaxf(m, __shfl_xor(m, off));
        float sd = 0.f;
        for (int j = beg + lane; j < end; j += 64) {
            int s = esrc[j];
            float e = asrc[s] + ad; e = e > 0.f ? e : NEG_SLOPE * e;
            sd += expf(e - m);
        }
        for (int off = 32; off; off >>= 1) sd += __shfl_xor(sd, off);
        float rd = 1.f / sd;
        for (int base = beg; base < end; base += 64) {
            int nc = end - base; if (nc > 64) nc = 64;
            int sj = 0; float wj = 0.f;
            if (lane < nc) {
                sj = esrc[base + lane];
                float e = asrc[sj] + ad; e = e > 0.f ? e : NEG_SLOPE * e;
                wj = expf(e - m) * rd;
            }
            gather1h(sj, wj, nc, sub, hb_c, acc);
        }
    }
#pragma unroll
    for (int i = 0; i < 8; ++i) {
        acc[i] += __shfl_xor(acc[i], 32);
        acc[i] += __shfl_xor(acc[i], 16);
    }
    if (lane < 16) {
        int cl = cgrp * 8;
        unsigned short hh[8];
#pragma unroll
        for (int i = 0; i < 8; ++i) {
            int c = cl + i;
            float v = acc[i] + b2[c];
            v = gamma[c] * (v - rm[c]) * rsqrtf(rv[c] + EPSBN) + beta[c];
            hh[i] = f2bf(fmaxf(v, 0.f));
        }
        *(uint4*)(x3b + (size_t)d * 128 + cl) = *(uint4*)&hh[0];
    }
}

// ---------------- global max pool over bf16 x3: one block per graph ---------
__global__ __launch_bounds__(128) void pool_max_graph(
    const unsigned short* __restrict__ x3b, const int* __restrict__ bat,
    float* __restrict__ out, int Nn)
{
    int g = blockIdx.x;
    int c = threadIdx.x;
    int lo = 0, hi = Nn;
    while (lo < hi) { int mid = (lo + hi) >> 1; if (bat[mid] < g) lo = mid + 1; else hi = mid; }
    int beg = lo;
    hi = Nn;
    while (lo < hi) { int mid = (lo + hi) >> 1; if (bat[mid] < g + 1) lo = mid + 1; else hi = mid; }
    int end = lo;
    float acc = -1e30f;
    for (int n = beg; n < end; ++n)
        acc = fmaxf(acc, bfu2f((unsigned)x3b[(size_t)n * 128 + c]));
    out[(size_t)g * 128 + c] = acc;
}

// ---------------------------------------------------------------------------
extern "C" void kernel_launch(void* const* d_in, const int* in_sizes, int n_in,
                              void* d_out, int out_size, void* d_ws, size_t ws_size,
                              hipStream_t stream)
{
    const float* x   = (const float*)d_in[0];
    const int*   ei  = (const int*)d_in[1];
    const int*   bat = (const int*)d_in[2];
    const float* W1  = (const float*)d_in[3];
    const float* as1 = (const float*)d_in[4];
    const float* ad1 = (const float*)d_in[5];
    const float* b1  = (const float*)d_in[6];
    const float* g1  = (const float*)d_in[7];
    const float* be1 = (const float*)d_in[8];
    const float* rm1 = (const float*)d_in[9];
    const float* rv1 = (const float*)d_in[10];
    const float* W2  = (const float*)d_in[11];
    const float* as2 = (const float*)d_in[12];
    const float* ad2 = (const float*)d_in[13];
    const float* b2  = (const float*)d_in[14];
    const float* g2  = (const float*)d_in[15];
    const float* be2 = (const float*)d_in[16];
    const float* rm2 = (const float*)d_in[17];
    const float* rv2 = (const float*)d_in[18];
    float* out = (float*)d_out;

    const int Nn = in_sizes[0] / 128;
    const int E  = in_sizes[1] / 2;
    const int E2 = E + Nn;
    const int B  = out_size / 128;

    char* p = (char*)d_ws;
    size_t off = 0;
    auto alloc = [&](size_t bytes) -> void* {
        void* r = p + off;
        off = (off + bytes + 255) & ~(size_t)255;
        return r;
    };
    unsigned short* xh    = (unsigned short*)alloc((size_t)Nn * 128 * 2);
    unsigned short* w1th  = (unsigned short*)alloc(256 * 128 * 2);
    unsigned short* w1tl  = (unsigned short*)alloc(256 * 128 * 2);
    unsigned short* w2th  = (unsigned short*)alloc(128 * 256 * 2);
    unsigned short* w2tl  = (unsigned short*)alloc(128 * 256 * 2);
    unsigned short* xth   = (unsigned short*)alloc((size_t)Nn * 256 * 2);
    unsigned short* x2h   = (unsigned short*)alloc((size_t)Nn * 256 * 2);
    float*          vsd   = (float*)alloc(4 * 128 * 4);
    float*          asrc1 = (float*)alloc((size_t)Nn * 2 * 4);
    float*          adst1 = (float*)alloc((size_t)Nn * 2 * 4);
    float*          attnv = (float*)alloc((size_t)Nn * 2 * 4);   // asrc2, adst2
    float*          asrc2 = attnv;
    float*          adst2 = attnv + Nn;
    int*            counts= (int*)alloc((size_t)NREP * Nn * 4);  // 8 replicas -> repoff
    int*            erank = (int*)alloc((size_t)E2 * 4);
    int*            offs  = (int*)alloc((size_t)(Nn + 1) * 4);
    int*            bsum  = (int*)alloc(256 * 4);
    int*            esrc  = (int*)alloc((size_t)E2 * 4);
    // aliases (proven pattern): xth dead after gemm_bn_split -> x3b;
    // xh dead after spmm_x -> h2b target for layer-2 GEMM
    unsigned short* x3b   = xth;
    unsigned short* h2b   = xh;

    const int nb = (Nn + 255) / 256;
    const int nwB = (Nn + 3) / 4;
    const int countB = (E2 + 255) / 256;
    const int gmB = (Nn + 127) / 128;

    hipMemsetAsync(counts, 0, (size_t)NREP * Nn * 4, stream);
    hipMemsetAsync(attnv, 0, (size_t)Nn * 2 * 4, stream);

    // ---- prep: vsd, then fused {count_edges(8-rep) | split_x+attn | split_w}
    precompute_v<<<2, 256, 0, stream>>>(W1, as1, ad1, vsd);
    prep<<<countB + nwB + 256, 256, 0, stream>>>(
        x, vsd, W1, W2, ei, xh, asrc1, adst1,
        w1th, w1tl, w2th, w2tl, counts, erank, Nn, E, nwB, countB);

    // ---- CSR scan + fill
    scan_block<<<nb, 256, 0, stream>>>(counts, offs, bsum, Nn);
    finalize_offsets<<<nb, 256, 0, stream>>>(bsum, offs, Nn, E2);
    fill_edges<<<(E2 + 255) / 256, 256, 0, stream>>>(ei, E, Nn, offs, counts, erank, esrc);

    // ---- layer 1: aggregate x (dual-head) then project + BN + ReLU
    spmm_x<<<nwB, 256, 0, stream>>>(xh, asrc1, adst1, offs, esrc, xth, Nn);
    gemm_bn_split<<<dim3(gmB, 2), 256, 0, stream>>>(
        xth, w1th, w1tl, b1, g1, be1, rm1, rv1, x2h, Nn);

    // ---- layer 2: GEMM (+attn coef) then SpMM (bf16 out)
    gemm_bf16_attn<<<gmB, 256, 0, stream>>>(
        x2h, w2th, w2tl, h2b, as2, ad2, asrc2, adst2, Nn);
    spmm2<<<nwB, 256, 0, stream>>>(h2b, asrc2, adst2, offs, esrc,
                                   b2, g2, be2, rm2, rv2, x3b, Nn);

    // ---- global max pool (bf16 in, f32 out)
    pool_max_graph<<<B, 128, 0, stream>>>(x3b, bat, out, Nn);
}